// Round 6
// baseline (419.285 us; speedup 1.0000x reference)
//
#include <hip/hip_runtime.h>
#include <stdint.h>

#define NSEQ 512
#define CH   128
#define NN   (NSEQ*NSEQ)   // 262144

typedef unsigned short u16;
typedef __attribute__((ext_vector_type(8))) short bf16x8;  // 8 bf16 = 4 VGPRs
typedef __attribute__((ext_vector_type(4))) float f32x4;

__device__ __forceinline__ u16 f2bf(float x){          // RNE
  uint32_t u = __float_as_uint(x);
  u += 0x7fffu + ((u >> 16) & 1u);
  return (u16)(u >> 16);
}
__device__ __forceinline__ float bf2f(u16 h){
  return __uint_as_float(((uint32_t)h) << 16);
}
__device__ __forceinline__ uint32_t cvtpk(float lo, float hi){  // bf16(lo)|bf16(hi)<<16
  uint32_t r;
  asm volatile("v_cvt_pk_bf16_f32 %0, %1, %2" : "=v"(r) : "v"(lo), "v"(hi));
  return r;
}
__device__ __forceinline__ float sigm(float x){
  return __builtin_amdgcn_rcpf(1.0f + __expf(-x));
}

// left/right tensor layout: [i (512)][kblk (8)][c (128)][kin (64)] u16
// offset = i*65536 + kblk*8192 + c*64 + kin   (flat row n = i*512 + kblk*64 + kin)

// ------------- k0: cast 6 weight matrices fp32 -> bf16 -------------
// slot order: 0=W_left 1=W_lgate 2=W_right 3=W_rgate 4=W_ogate 5=W_out
__global__ void k0_cvt(const float* __restrict__ w0, const float* __restrict__ w1,
                       const float* __restrict__ w2, const float* __restrict__ w3,
                       const float* __restrict__ w4, const float* __restrict__ w5,
                       u16* __restrict__ out)
{
  int mat = blockIdx.x >> 4;
  int blk = blockIdx.x & 15;
  const float* src = (mat==0)?w0:(mat==1)?w1:(mat==2)?w2:(mat==3)?w3:(mat==4)?w4:w5;
  int idx = (blk*256 + (int)threadIdx.x) * 4;
  float4 v = *(const float4*)(src + idx);
  uint2 pk;
  pk.x = cvtpk(v.x, v.y);
  pk.y = cvtpk(v.z, v.w);
  *(uint2*)(out + mat*16384 + idx) = pk;
}

// ------------- k1a: LN(z) -> znS bf16 [row][c], pure streaming ------------
__global__ __launch_bounds__(256) void k1a_ln(
    const float* __restrict__ z, const float* __restrict__ lnw,
    const float* __restrict__ lnb, u16* __restrict__ znS)
{
  __shared__ float lnw_s[128], lnb_s[128];
  const int t = threadIdx.x;
  const int row0 = blockIdx.x * 64;
  if (t < 32)      ((float4*)lnw_s)[t]    = ((const float4*)lnw)[t];
  else if (t < 64) ((float4*)lnb_s)[t-32] = ((const float4*)lnb)[t-32];
  __syncthreads();

  int r = t >> 2, q = t & 3;
  const float* zp = z + (size_t)(row0 + r) * CH + q * 32;
  float4 v[8];
  #pragma unroll
  for (int e=0;e<8;e++) v[e] = ((const float4*)zp)[e];
  float s = 0.f, sq = 0.f;
  #pragma unroll
  for (int e=0;e<8;e++){
    s  += v[e].x + v[e].y + v[e].z + v[e].w;
    sq += v[e].x*v[e].x + v[e].y*v[e].y + v[e].z*v[e].z + v[e].w*v[e].w;
  }
  s += __shfl_xor(s,1); sq += __shfl_xor(sq,1);
  s += __shfl_xor(s,2); sq += __shfl_xor(sq,2);
  float mu = s * (1.f/128.f);
  float rstd = __builtin_amdgcn_rsqf(sq * (1.f/128.f) - mu*mu + 1e-5f);
  uint32_t pk[16];
  #pragma unroll
  for (int e=0;e<8;e++){
    int c = q*32 + e*4;
    float a0 = (v[e].x - mu)*rstd*lnw_s[c+0] + lnb_s[c+0];
    float a1 = (v[e].y - mu)*rstd*lnw_s[c+1] + lnb_s[c+1];
    float a2 = (v[e].z - mu)*rstd*lnw_s[c+2] + lnb_s[c+2];
    float a3 = (v[e].w - mu)*rstd*lnw_s[c+3] + lnb_s[c+3];
    pk[e*2+0] = cvtpk(a0, a1);
    pk[e*2+1] = cvtpk(a2, a3);
  }
  uint4* dst = (uint4*)(znS + (size_t)(row0 + r)*CH + q*32);
  #pragma unroll
  for (int e=0;e<4;e++) dst[e] = make_uint4(pk[e*4], pk[e*4+1], pk[e*4+2], pk[e*4+3]);
}

// ------------- k1b: 2 gated projections ---------------------------------
// weight loads issued BEFORE the barrier; stores coalesced via per-wave LDS
// stage (same-wave ds_write->ds_read, no extra barrier).
__global__ __launch_bounds__(256) void k1b_proj(
    const u16* __restrict__ znS, const float* __restrict__ pmask,
    const float* __restrict__ b_lg, const float* __restrict__ b_rg,
    const u16* __restrict__ wts,
    u16* __restrict__ left_t, u16* __restrict__ right_t)
{
  __shared__ __align__(16) u16 zn[64][136];
  __shared__ __align__(16) u16 stg[4][2048];   // 4KB per wave
  __shared__ float mask_s[64];
  const int t = threadIdx.x;
  const int row0 = blockIdx.x * 64;
  const size_t tile_off = (size_t)(row0 >> 9)*65536 + (size_t)((row0 >> 6) & 7)*8192;

  const int lane = t & 63;
  const int w = t >> 6;
  const int lr = lane & 15;
  const int lg = lane >> 4;
  const int ow = w*32;

  // pass-A weights: no dependency on zn -> issue before staging/barrier
  bf16x8 wl[8], wg[8];
  #pragma unroll
  for (int kk=0;kk<4;kk++)
    #pragma unroll
    for (int n=0;n<2;n++){
      int o = ow + n*16 + lr;
      wl[kk*2+n] = *(const bf16x8*)&wts[0*16384 + o*128 + kk*32 + lg*8];
      wg[kk*2+n] = *(const bf16x8*)&wts[1*16384 + o*128 + kk*32 + lg*8];
    }

  // stage znorm tile (16KB) reg->LDS
  #pragma unroll
  for (int k=0;k<4;k++){
    uint4 v = *(const uint4*)(znS + (size_t)row0*CH + k*2048 + t*8);
    int r = k*16 + (t>>4), g = t & 15;
    *(uint4*)&zn[r][g*8] = v;
  }
  if (t < 16) ((float4*)mask_s)[t] = ((const float4*)(pmask + row0))[t];
  __syncthreads();   // the ONLY barrier

  f32x4 acc1[4][2], acc2[4][2];
  const f32x4 zero4 = {0.f,0.f,0.f,0.f};

  // ===== pass A MFMAs =====
  #pragma unroll
  for (int mi=0;mi<4;mi++){ acc1[mi][0]=zero4; acc1[mi][1]=zero4; acc2[mi][0]=zero4; acc2[mi][1]=zero4; }
  #pragma unroll
  for (int kk=0;kk<4;kk++){
    bf16x8 a[4];
    #pragma unroll
    for (int mi=0;mi<4;mi++)
      a[mi] = *(const bf16x8*)&zn[mi*16 + lr][kk*32 + lg*8];
    #pragma unroll
    for (int n=0;n<2;n++)
      #pragma unroll
      for (int mi=0;mi<4;mi++){
        acc1[mi][n] = __builtin_amdgcn_mfma_f32_16x16x32_bf16(a[mi], wl[kk*2+n], acc1[mi][n], 0,0,0);
        acc2[mi][n] = __builtin_amdgcn_mfma_f32_16x16x32_bf16(a[mi], wg[kk*2+n], acc2[mi][n], 0,0,0);
      }
  }
  // prefetch pass-B weights (hide under epilogue-A VALU)
  bf16x8 wl2[8], wg2[8];
  #pragma unroll
  for (int kk=0;kk<4;kk++)
    #pragma unroll
    for (int n=0;n<2;n++){
      int o = ow + n*16 + lr;
      wl2[kk*2+n] = *(const bf16x8*)&wts[2*16384 + o*128 + kk*32 + lg*8];
      wg2[kk*2+n] = *(const bf16x8*)&wts[3*16384 + o*128 + kk*32 + lg*8];
    }

  // ===== epilogue A: sigmoid*mask -> per-wave LDS stage -> coalesced store
  #pragma unroll
  for (int n=0;n<2;n++){
    int ol = n*16 + lr;          // 0..31 within wave's o-range
    float bgv = b_lg[ow + ol];
    #pragma unroll
    for (int mi=0;mi<4;mi++){
      int r0 = mi*16 + lg*4;
      float v0 = acc1[mi][n][0] * sigm(acc2[mi][n][0] + bgv) * mask_s[r0+0];
      float v1 = acc1[mi][n][1] * sigm(acc2[mi][n][1] + bgv) * mask_s[r0+1];
      float v2 = acc1[mi][n][2] * sigm(acc2[mi][n][2] + bgv) * mask_s[r0+2];
      float v3 = acc1[mi][n][3] * sigm(acc2[mi][n][3] + bgv) * mask_s[r0+3];
      int chunk = (mi*2 + (lg>>1)) ^ (ol & 7);     // 8-u16-chunk XOR swizzle
      *(uint2*)&stg[w][ol*64 + (chunk<<3) + (lg&1)*4] = make_uint2(cvtpk(v0,v1), cvtpk(v2,v3));
    }
  }
  { // readback (same wave; lgkmcnt ordering only) + contiguous 4KB/wave store
    int ol = lane >> 1, rh = lane & 1;
    uint4 pf[4];
    #pragma unroll
    for (int q=0;q<4;q++){
      int m = (rh*4 + q) ^ (ol & 7);
      pf[q] = *(const uint4*)&stg[w][ol*64 + (m<<3)];
    }
    uint4* dst = (uint4*)(left_t + tile_off + (ow + ol)*64 + rh*32);
    #pragma unroll
    for (int q=0;q<4;q++) dst[q] = pf[q];
  }

  // ===== pass B MFMAs =====
  #pragma unroll
  for (int mi=0;mi<4;mi++){ acc1[mi][0]=zero4; acc1[mi][1]=zero4; acc2[mi][0]=zero4; acc2[mi][1]=zero4; }
  #pragma unroll
  for (int kk=0;kk<4;kk++){
    bf16x8 a[4];
    #pragma unroll
    for (int mi=0;mi<4;mi++)
      a[mi] = *(const bf16x8*)&zn[mi*16 + lr][kk*32 + lg*8];
    #pragma unroll
    for (int n=0;n<2;n++)
      #pragma unroll
      for (int mi=0;mi<4;mi++){
        acc1[mi][n] = __builtin_amdgcn_mfma_f32_16x16x32_bf16(a[mi], wl2[kk*2+n], acc1[mi][n], 0,0,0);
        acc2[mi][n] = __builtin_amdgcn_mfma_f32_16x16x32_bf16(a[mi], wg2[kk*2+n], acc2[mi][n], 0,0,0);
      }
  }
  // ===== epilogue B =====
  #pragma unroll
  for (int n=0;n<2;n++){
    int ol = n*16 + lr;
    float bgv = b_rg[ow + ol];
    #pragma unroll
    for (int mi=0;mi<4;mi++){
      int r0 = mi*16 + lg*4;
      float v0 = acc1[mi][n][0] * sigm(acc2[mi][n][0] + bgv) * mask_s[r0+0];
      float v1 = acc1[mi][n][1] * sigm(acc2[mi][n][1] + bgv) * mask_s[r0+1];
      float v2 = acc1[mi][n][2] * sigm(acc2[mi][n][2] + bgv) * mask_s[r0+2];
      float v3 = acc1[mi][n][3] * sigm(acc2[mi][n][3] + bgv) * mask_s[r0+3];
      int chunk = (mi*2 + (lg>>1)) ^ (ol & 7);
      *(uint2*)&stg[w][ol*64 + (chunk<<3) + (lg&1)*4] = make_uint2(cvtpk(v0,v1), cvtpk(v2,v3));
    }
  }
  {
    int ol = lane >> 1, rh = lane & 1;
    uint4 pf[4];
    #pragma unroll
    for (int q=0;q<4;q++){
      int m = (rh*4 + q) ^ (ol & 7);
      pf[q] = *(const uint4*)&stg[w][ol*64 + (m<<3)];
    }
    uint4* dst = (uint4*)(right_t + tile_off + (ow + ol)*64 + rh*32);
    #pragma unroll
    for (int q=0;q<4;q++) dst[q] = pf[q];
  }
}

// ------------- k2: per-channel 128x128x512 GEMM, bf16 output --------------
// 128^2 tile: 2x staging reuse vs 64^2; 4 waves in 2x2, each 64x64.
__global__ __launch_bounds__(256) void k2_einsum(
    const u16* __restrict__ left_t, const u16* __restrict__ right_t,
    u16* __restrict__ upd16)
{
  __shared__ __align__(16) u16 lds_raw[32768];   // 64KB: A dbuf | B dbuf; reused as stage
  const int t = threadIdx.x;
  const int lane = t & 63, w = t >> 6;
  const int wi = w >> 1, wj = w & 1;
  const int lr = lane & 15, lg = lane >> 4;
  const int i0 = blockIdx.x * 128, j0 = blockIdx.y * 128;
  const int c  = blockIdx.z;

  // staging: thread -> tensor (t>>7), row (t&127), 128B per K-step
  const int ts = t >> 7, srow = t & 127;
  const u16* gsrc = (ts ? right_t : left_t)
                  + (size_t)((ts ? j0 : i0) + srow)*65536 + (size_t)c*64;

  f32x4 acc[4][4];
  const f32x4 zero4 = {0.f,0.f,0.f,0.f};
  #pragma unroll
  for (int mi=0;mi<4;mi++)
    #pragma unroll
    for (int nj=0;nj<4;nj++) acc[mi][nj] = zero4;

  { // stage K-step 0 into buf0
    u16* d = lds_raw + ts*16384 + srow*64;
    #pragma unroll
    for (int s=0;s<8;s++){
      uint4 v = *(const uint4*)(gsrc + s*8);
      *(uint4*)&d[(s ^ (srow&7))*8] = v;
    }
  }
  __syncthreads();

  for (int kt=0; kt<8; kt++){
    const int buf = kt & 1;
    uint4 pf[8];
    if (kt < 7){
      const u16* g = gsrc + (size_t)(kt+1)*8192;
      #pragma unroll
      for (int s=0;s<8;s++) pf[s] = *(const uint4*)(g + s*8);
    }
    const u16* ldsA = lds_raw + buf*8192;
    const u16* ldsB = lds_raw + 16384 + buf*8192;
    #pragma unroll
    for (int kk=0;kk<2;kk++){
      bf16x8 af[4], bfr[4];
      #pragma unroll
      for (int mi=0;mi<4;mi++){
        int row = wi*64 + mi*16 + lr;
        af[mi] = *(const bf16x8*)&ldsA[row*64 + (((kk*4+lg) ^ (row&7)))*8];
      }
      #pragma unroll
      for (int nj=0;nj<4;nj++){
        int row = wj*64 + nj*16 + lr;
        bfr[nj] = *(const bf16x8*)&ldsB[row*64 + (((kk*4+lg) ^ (row&7)))*8];
      }
      #pragma unroll
      for (int mi=0;mi<4;mi++)
        #pragma unroll
        for (int nj=0;nj<4;nj++)
          acc[mi][nj] = __builtin_amdgcn_mfma_f32_16x16x32_bf16(af[mi], bfr[nj], acc[mi][nj], 0,0,0);
    }
    if (kt < 7){
      u16* d = lds_raw + ts*16384 + (buf^1)*8192 + srow*64;
      #pragma unroll
      for (int s=0;s<8;s++) *(uint4*)&d[(s ^ (srow&7))*8] = pf[s];
    }
    __syncthreads();
  }

  // epilogue: bf16 via LDS transpose stage st[128][136]
  const float scale = 0.044194173824159216f;   // 1/sqrt(512)
  u16* st = lds_raw;
  #pragma unroll
  for (int mi=0;mi<4;mi++){
    #pragma unroll
    for (int nj=0;nj<4;nj++){
      int cj = wj*64 + nj*16 + lr;
      #pragma unroll
      for (int g2=0;g2<4;g2++){
        int ri = wi*64 + mi*16 + lg*4 + g2;
        st[ri*136 + cj] = f2bf(acc[mi][nj][g2] * scale);
      }
    }
  }
  __syncthreads();
  {
    int ri = t >> 1, half = t & 1;
    const uint4* src = (const uint4*)&st[ri*136 + half*64];
    uint4* dst = (uint4*)(upd16 + (size_t)c*NN + (size_t)(i0+ri)*NSEQ + j0 + half*64);
    #pragma unroll
    for (int e=0;e<8;e++) dst[e] = src[e];
  }
}

// ------------- k3a: LN over c of upd16 [c][i*512+j] -> znu [row][c] bf16 --
__global__ __launch_bounds__(256) void k3a_ln(
    const u16* __restrict__ upd16, const float* __restrict__ onw,
    const float* __restrict__ onb, u16* __restrict__ znu)
{
  __shared__ float u[128*129];
  __shared__ float onw_s[128], onb_s[128];
  const int t = threadIdx.x;
  const int i = blockIdx.x;
  const int j0 = blockIdx.y * 128;

  if (t < 32)      ((float4*)onw_s)[t]    = ((const float4*)onw)[t];
  else if (t < 64) ((float4*)onb_s)[t-32] = ((const float4*)onb)[t-32];

  {
    int cr = t >> 1, h = t & 1;
    const uint4* src = (const uint4*)(upd16 + (size_t)cr*NN + (size_t)i*NSEQ + j0 + h*64);
    float* dst = &u[cr*129 + h*64];
    #pragma unroll
    for (int e=0;e<8;e++){
      uint4 v = src[e];
      const u16* hp = (const u16*)&v;
      #pragma unroll
      for (int p=0;p<8;p++) dst[e*8+p] = bf2f(hp[p]);
    }
  }
  __syncthreads();

  int j = t >> 1, h = t & 1;
  float s = 0.f, sq = 0.f;
  #pragma unroll
  for (int e=0;e<64;e++){
    float v = u[(h*64+e)*129 + j];
    s += v; sq += v*v;
  }
  s += __shfl_xor(s,1); sq += __shfl_xor(sq,1);
  float mu = s * (1.f/128.f);
  float rstd = __builtin_amdgcn_rsqf(sq * (1.f/128.f) - mu*mu + 1e-5f);

  uint32_t pk[32];
  #pragma unroll
  for (int e=0;e<64;e+=2){
    int c0 = h*64 + e;
    float v0 = (u[c0*129 + j]     - mu)*rstd*onw_s[c0]   + onb_s[c0];
    float v1 = (u[(c0+1)*129 + j] - mu)*rstd*onw_s[c0+1] + onb_s[c0+1];
    pk[e>>1] = cvtpk(v0, v1);
  }
  uint4* dst = (uint4*)(znu + ((size_t)i*NSEQ + j0 + j)*CH + h*64);
  #pragma unroll
  for (int e=0;e<8;e++) dst[e] = make_uint4(pk[e*4], pk[e*4+1], pk[e*4+2], pk[e*4+3]);
}

// ------------- k3b: out = (LN'd-update @ W_out^T) * sigm(zn@W_og^T+b) * mask
__global__ __launch_bounds__(256) void k3b_out(
    const u16* __restrict__ znu, const u16* __restrict__ znS,
    const float* __restrict__ pmask, const float* __restrict__ b_og,
    const u16* __restrict__ wts, float* __restrict__ out)
{
  __shared__ __align__(16) u16 uL[64][136];
  __shared__ __align__(16) u16 zL[64][136];
  __shared__ float mask_s[64];
  const int t = threadIdx.x;
  const int row0 = blockIdx.x * 64;

  #pragma unroll
  for (int k=0;k<4;k++){
    uint4 vu = *(const uint4*)(znu + (size_t)row0*CH + k*2048 + t*8);
    uint4 vz = *(const uint4*)(znS + (size_t)row0*CH + k*2048 + t*8);
    int r = k*16 + (t>>4), g = t & 15;
    *(uint4*)&uL[r][g*8] = vu;
    *(uint4*)&zL[r][g*8] = vz;
  }
  if (t < 16) ((float4*)mask_s)[t] = ((const float4*)(pmask + row0))[t];
  __syncthreads();

  const int lane = t & 63, w = t >> 6;
  const int lr = lane & 15, lg = lane >> 4;

  f32x4 acc_o[4][2], acc_g[4][2];
  const f32x4 zero4 = {0.f,0.f,0.f,0.f};
  #pragma unroll
  for (int mi=0;mi<4;mi++){ acc_o[mi][0]=zero4; acc_o[mi][1]=zero4; acc_g[mi][0]=zero4; acc_g[mi][1]=zero4; }

  // GEMM1: znu @ W_out^T
  #pragma unroll
  for (int kk=0;kk<4;kk++){
    bf16x8 a[4];
    #pragma unroll
    for (int mi=0;mi<4;mi++)
      a[mi] = *(const bf16x8*)&uL[mi*16 + lr][kk*32 + lg*8];
    #pragma unroll
    for (int n=0;n<2;n++){
      int o = w*32 + n*16 + lr;
      bf16x8 b = *(const bf16x8*)&wts[5*16384 + o*128 + kk*32 + lg*8];
      #pragma unroll
      for (int mi=0;mi<4;mi++)
        acc_o[mi][n] = __builtin_amdgcn_mfma_f32_16x16x32_bf16(a[mi], b, acc_o[mi][n], 0,0,0);
    }
  }
  // GEMM2: znS @ W_ogate^T
  #pragma unroll
  for (int kk=0;kk<4;kk++){
    bf16x8 a[4];
    #pragma unroll
    for (int mi=0;mi<4;mi++)
      a[mi] = *(const bf16x8*)&zL[mi*16 + lr][kk*32 + lg*8];
    #pragma unroll
    for (int n=0;n<2;n++){
      int o = w*32 + n*16 + lr;
      bf16x8 b = *(const bf16x8*)&wts[4*16384 + o*128 + kk*32 + lg*8];
      #pragma unroll
      for (int mi=0;mi<4;mi++)
        acc_g[mi][n] = __builtin_amdgcn_mfma_f32_16x16x32_bf16(a[mi], b, acc_g[mi][n], 0,0,0);
    }
  }

  // combine in-register (identical C-layouts) + direct fp32 stores
  #pragma unroll
  for (int n=0;n<2;n++){
    int o = w*32 + n*16 + lr;
    float bgv = b_og[o];
    #pragma unroll
    for (int mi=0;mi<4;mi++){
      #pragma unroll
      for (int g2=0;g2<4;g2++){
        int r = mi*16 + lg*4 + g2;
        float val = acc_o[mi][n][g2] * sigm(acc_g[mi][n][g2] + bgv) * mask_s[r];
        out[(size_t)(row0 + r)*CH + o] = val;
      }
    }
  }
}

// --------------------------- launcher ------------------------------------
extern "C" void kernel_launch(void* const* d_in, const int* in_sizes, int n_in,
                              void* d_out, int out_size, void* d_ws, size_t ws_size,
                              hipStream_t stream)
{
  const float* z       = (const float*)d_in[0];
  const float* pmask   = (const float*)d_in[1];
  const float* lnw     = (const float*)d_in[2];
  const float* lnb     = (const float*)d_in[3];
  const float* W_left  = (const float*)d_in[4];
  const float* W_right = (const float*)d_in[5];
  const float* W_lgate = (const float*)d_in[6];
  const float* b_lgate = (const float*)d_in[7];
  const float* W_rgate = (const float*)d_in[8];
  const float* b_rgate = (const float*)d_in[9];
  const float* onw     = (const float*)d_in[10];
  const float* onb     = (const float*)d_in[11];
  const float* W_out   = (const float*)d_in[12];
  const float* W_ogate = (const float*)d_in[13];
  const float* b_ogate = (const float*)d_in[14];

  const size_t SLOT = 67108864;   // 64 MiB
  uint8_t* ws = (uint8_t*)d_ws;
  u16* left_t  = (u16*)(ws);               // [i][kb][c][kin]; reused as znu after k2
  u16* right_t = (u16*)(ws + SLOT);
  u16* znS     = (u16*)(ws + 2*SLOT);      // LN(z) bf16 [row][c]
  u16* wts     = (u16*)(ws + 3*SLOT);
  u16* upd16   = (u16*)d_out;              // d_out doubles as bf16 update scratch

  k0_cvt<<<96, 256, 0, stream>>>(W_left, W_lgate, W_right, W_rgate, W_ogate, W_out, wts);
  k1a_ln<<<4096, 256, 0, stream>>>(z, lnw, lnb, znS);
  k1b_proj<<<4096, 256, 0, stream>>>(znS, pmask, b_lgate, b_rgate, wts, left_t, right_t);
  k2_einsum<<<dim3(4,4,128), 256, 0, stream>>>(left_t, right_t, upd16);
  k3a_ln<<<dim3(512,4), 256, 0, stream>>>(upd16, onw, onb, left_t /*znu*/);
  k3b_out<<<4096, 256, 0, stream>>>(left_t /*znu*/, znS, pmask, b_ogate, wts, (float*)d_out);
}

// Round 7
// 358.669 us; speedup vs baseline: 1.1690x; 1.1690x over previous
//
#include <hip/hip_runtime.h>
#include <stdint.h>

#define NSEQ 512
#define CH   128
#define NN   (NSEQ*NSEQ)   // 262144

typedef unsigned short u16;
typedef __attribute__((ext_vector_type(8))) short bf16x8;  // 8 bf16 = 4 VGPRs
typedef __attribute__((ext_vector_type(4))) float f32x4;

__device__ __forceinline__ u16 f2bf(float x){          // RNE
  uint32_t u = __float_as_uint(x);
  u += 0x7fffu + ((u >> 16) & 1u);
  return (u16)(u >> 16);
}
__device__ __forceinline__ float bf2f(u16 h){
  return __uint_as_float(((uint32_t)h) << 16);
}
__device__ __forceinline__ uint32_t cvtpk(float lo, float hi){  // bf16(lo)|bf16(hi)<<16
  uint32_t r;
  asm volatile("v_cvt_pk_bf16_f32 %0, %1, %2" : "=v"(r) : "v"(lo), "v"(hi));
  return r;
}
__device__ __forceinline__ float sigm(float x){
  return __builtin_amdgcn_rcpf(1.0f + __expf(-x));
}

// left/right tensor layout: [i (512)][kblk (8)][c (128)][kin (64)] u16
// offset = i*65536 + kblk*8192 + c*64 + kin   (flat row n = i*512 + kblk*64 + kin)

// ------------- k0: cast 6 weight matrices fp32 -> bf16 -------------
// slot order: 0=W_left 1=W_lgate 2=W_right 3=W_rgate 4=W_ogate 5=W_out
__global__ void k0_cvt(const float* __restrict__ w0, const float* __restrict__ w1,
                       const float* __restrict__ w2, const float* __restrict__ w3,
                       const float* __restrict__ w4, const float* __restrict__ w5,
                       u16* __restrict__ out)
{
  int mat = blockIdx.x >> 4;
  int blk = blockIdx.x & 15;
  const float* src = (mat==0)?w0:(mat==1)?w1:(mat==2)?w2:(mat==3)?w3:(mat==4)?w4:w5;
  int idx = (blk*256 + (int)threadIdx.x) * 4;
  float4 v = *(const float4*)(src + idx);
  uint2 pk;
  pk.x = cvtpk(v.x, v.y);
  pk.y = cvtpk(v.z, v.w);
  *(uint2*)(out + mat*16384 + idx) = pk;
}

// ------------- k1a: LN(z) -> znS bf16 [row][c], pure streaming ------------
__global__ __launch_bounds__(256) void k1a_ln(
    const float* __restrict__ z, const float* __restrict__ lnw,
    const float* __restrict__ lnb, u16* __restrict__ znS)
{
  __shared__ float lnw_s[128], lnb_s[128];
  const int t = threadIdx.x;
  const int row0 = blockIdx.x * 64;
  if (t < 32)      ((float4*)lnw_s)[t]    = ((const float4*)lnw)[t];
  else if (t < 64) ((float4*)lnb_s)[t-32] = ((const float4*)lnb)[t-32];
  __syncthreads();

  int r = t >> 2, q = t & 3;
  const float* zp = z + (size_t)(row0 + r) * CH + q * 32;
  float4 v[8];
  #pragma unroll
  for (int e=0;e<8;e++) v[e] = ((const float4*)zp)[e];
  float s = 0.f, sq = 0.f;
  #pragma unroll
  for (int e=0;e<8;e++){
    s  += v[e].x + v[e].y + v[e].z + v[e].w;
    sq += v[e].x*v[e].x + v[e].y*v[e].y + v[e].z*v[e].z + v[e].w*v[e].w;
  }
  s += __shfl_xor(s,1); sq += __shfl_xor(sq,1);
  s += __shfl_xor(s,2); sq += __shfl_xor(sq,2);
  float mu = s * (1.f/128.f);
  float rstd = __builtin_amdgcn_rsqf(sq * (1.f/128.f) - mu*mu + 1e-5f);
  uint32_t pk[16];
  #pragma unroll
  for (int e=0;e<8;e++){
    int c = q*32 + e*4;
    float a0 = (v[e].x - mu)*rstd*lnw_s[c+0] + lnb_s[c+0];
    float a1 = (v[e].y - mu)*rstd*lnw_s[c+1] + lnb_s[c+1];
    float a2 = (v[e].z - mu)*rstd*lnw_s[c+2] + lnb_s[c+2];
    float a3 = (v[e].w - mu)*rstd*lnw_s[c+3] + lnb_s[c+3];
    pk[e*2+0] = cvtpk(a0, a1);
    pk[e*2+1] = cvtpk(a2, a3);
  }
  uint4* dst = (uint4*)(znS + (size_t)(row0 + r)*CH + q*32);
  #pragma unroll
  for (int e=0;e<4;e++) dst[e] = make_uint4(pk[e*4], pk[e*4+1], pk[e*4+2], pk[e*4+3]);
}

// ------------- k1b: 2 gated projections, 2 row-tiles per block ------------
// Both tiles' znS loads issued up front (32KB in flight), ONE barrier, then
// tile0 + tile1 compute back-to-back; tile0's stores drain under tile1's MFMA.
__global__ __launch_bounds__(256) void k1b_proj(
    const u16* __restrict__ znS, const float* __restrict__ pmask,
    const float* __restrict__ b_lg, const float* __restrict__ b_rg,
    const u16* __restrict__ wts,
    u16* __restrict__ left_t, u16* __restrict__ right_t)
{
  __shared__ __align__(16) u16 zn[2][64][136];  // 34 KB
  __shared__ __align__(16) u16 stg[4][2048];    // 16 KB (per-wave stage)
  __shared__ float mask_s[128];
  const int t = threadIdx.x;
  const int row0 = blockIdx.x * 128;

  const int lane = t & 63;
  const int w = t >> 6;
  const int lr = lane & 15;
  const int lg = lane >> 4;
  const int ow = w*32;

  // both tiles' znorm loads issued first (deep MLP), then LDS writes
  uint4 za[4], zb[4];
  #pragma unroll
  for (int k=0;k<4;k++) za[k] = *(const uint4*)(znS + (size_t)row0*CH + k*2048 + t*8);
  #pragma unroll
  for (int k=0;k<4;k++) zb[k] = *(const uint4*)(znS + (size_t)(row0+64)*CH + k*2048 + t*8);
  if (t < 32) ((float4*)mask_s)[t] = ((const float4*)(pmask + row0))[t];
  #pragma unroll
  for (int k=0;k<4;k++){
    int r = k*16 + (t>>4), g = t & 15;
    *(uint4*)&zn[0][r][g*8] = za[k];
  }
  #pragma unroll
  for (int k=0;k<4;k++){
    int r = k*16 + (t>>4), g = t & 15;
    *(uint4*)&zn[1][r][g*8] = zb[k];
  }
  __syncthreads();   // the ONLY barrier

  const f32x4 zero4 = {0.f,0.f,0.f,0.f};

  #pragma unroll
  for (int tt=0; tt<2; tt++){
    const int r0t = row0 + tt*64;
    const size_t tile_off = (size_t)(r0t >> 9)*65536 + (size_t)((r0t >> 6) & 7)*8192;
    const float* msk = mask_s + tt*64;

    // pass-A weights
    bf16x8 wl[8], wg[8];
    #pragma unroll
    for (int kk=0;kk<4;kk++)
      #pragma unroll
      for (int n=0;n<2;n++){
        int o = ow + n*16 + lr;
        wl[kk*2+n] = *(const bf16x8*)&wts[0*16384 + o*128 + kk*32 + lg*8];
        wg[kk*2+n] = *(const bf16x8*)&wts[1*16384 + o*128 + kk*32 + lg*8];
      }

    f32x4 acc1[4][2], acc2[4][2];
    #pragma unroll
    for (int mi=0;mi<4;mi++){ acc1[mi][0]=zero4; acc1[mi][1]=zero4; acc2[mi][0]=zero4; acc2[mi][1]=zero4; }
    #pragma unroll
    for (int kk=0;kk<4;kk++){
      bf16x8 a[4];
      #pragma unroll
      for (int mi=0;mi<4;mi++)
        a[mi] = *(const bf16x8*)&zn[tt][mi*16 + lr][kk*32 + lg*8];
      #pragma unroll
      for (int n=0;n<2;n++)
        #pragma unroll
        for (int mi=0;mi<4;mi++){
          acc1[mi][n] = __builtin_amdgcn_mfma_f32_16x16x32_bf16(a[mi], wl[kk*2+n], acc1[mi][n], 0,0,0);
          acc2[mi][n] = __builtin_amdgcn_mfma_f32_16x16x32_bf16(a[mi], wg[kk*2+n], acc2[mi][n], 0,0,0);
        }
    }
    // prefetch pass-B weights
    bf16x8 wl2[8], wg2[8];
    #pragma unroll
    for (int kk=0;kk<4;kk++)
      #pragma unroll
      for (int n=0;n<2;n++){
        int o = ow + n*16 + lr;
        wl2[kk*2+n] = *(const bf16x8*)&wts[2*16384 + o*128 + kk*32 + lg*8];
        wg2[kk*2+n] = *(const bf16x8*)&wts[3*16384 + o*128 + kk*32 + lg*8];
      }

    // epilogue A: sigmoid*mask -> per-wave LDS stage -> coalesced store
    #pragma unroll
    for (int n=0;n<2;n++){
      int ol = n*16 + lr;
      float bgv = b_lg[ow + ol];
      #pragma unroll
      for (int mi=0;mi<4;mi++){
        int r0 = mi*16 + lg*4;
        float v0 = acc1[mi][n][0] * sigm(acc2[mi][n][0] + bgv) * msk[r0+0];
        float v1 = acc1[mi][n][1] * sigm(acc2[mi][n][1] + bgv) * msk[r0+1];
        float v2 = acc1[mi][n][2] * sigm(acc2[mi][n][2] + bgv) * msk[r0+2];
        float v3 = acc1[mi][n][3] * sigm(acc2[mi][n][3] + bgv) * msk[r0+3];
        int chunk = (mi*2 + (lg>>1)) ^ (ol & 7);
        *(uint2*)&stg[w][ol*64 + (chunk<<3) + (lg&1)*4] = make_uint2(cvtpk(v0,v1), cvtpk(v2,v3));
      }
    }
    {
      int ol = lane >> 1, rh = lane & 1;
      uint4 pf[4];
      #pragma unroll
      for (int q=0;q<4;q++){
        int m = (rh*4 + q) ^ (ol & 7);
        pf[q] = *(const uint4*)&stg[w][ol*64 + (m<<3)];
      }
      uint4* dst = (uint4*)(left_t + tile_off + (ow + ol)*64 + rh*32);
      #pragma unroll
      for (int q=0;q<4;q++) dst[q] = pf[q];
    }

    // pass B
    #pragma unroll
    for (int mi=0;mi<4;mi++){ acc1[mi][0]=zero4; acc1[mi][1]=zero4; acc2[mi][0]=zero4; acc2[mi][1]=zero4; }
    #pragma unroll
    for (int kk=0;kk<4;kk++){
      bf16x8 a[4];
      #pragma unroll
      for (int mi=0;mi<4;mi++)
        a[mi] = *(const bf16x8*)&zn[tt][mi*16 + lr][kk*32 + lg*8];
      #pragma unroll
      for (int n=0;n<2;n++)
        #pragma unroll
        for (int mi=0;mi<4;mi++){
          acc1[mi][n] = __builtin_amdgcn_mfma_f32_16x16x32_bf16(a[mi], wl2[kk*2+n], acc1[mi][n], 0,0,0);
          acc2[mi][n] = __builtin_amdgcn_mfma_f32_16x16x32_bf16(a[mi], wg2[kk*2+n], acc2[mi][n], 0,0,0);
        }
    }
    // epilogue B
    #pragma unroll
    for (int n=0;n<2;n++){
      int ol = n*16 + lr;
      float bgv = b_rg[ow + ol];
      #pragma unroll
      for (int mi=0;mi<4;mi++){
        int r0 = mi*16 + lg*4;
        float v0 = acc1[mi][n][0] * sigm(acc2[mi][n][0] + bgv) * msk[r0+0];
        float v1 = acc1[mi][n][1] * sigm(acc2[mi][n][1] + bgv) * msk[r0+1];
        float v2 = acc1[mi][n][2] * sigm(acc2[mi][n][2] + bgv) * msk[r0+2];
        float v3 = acc1[mi][n][3] * sigm(acc2[mi][n][3] + bgv) * msk[r0+3];
        int chunk = (mi*2 + (lg>>1)) ^ (ol & 7);
        *(uint2*)&stg[w][ol*64 + (chunk<<3) + (lg&1)*4] = make_uint2(cvtpk(v0,v1), cvtpk(v2,v3));
      }
    }
    {
      int ol = lane >> 1, rh = lane & 1;
      uint4 pf[4];
      #pragma unroll
      for (int q=0;q<4;q++){
        int m = (rh*4 + q) ^ (ol & 7);
        pf[q] = *(const uint4*)&stg[w][ol*64 + (m<<3)];
      }
      uint4* dst = (uint4*)(right_t + tile_off + (ow + ol)*64 + rh*32);
      #pragma unroll
      for (int q=0;q<4;q++) dst[q] = pf[q];
    }
  }
}

// ------------- k2: per-channel 64x64x512 GEMM, bf16 output (R5 proven) ----
__global__ __launch_bounds__(256) void k2_einsum(
    const u16* __restrict__ left_t, const u16* __restrict__ right_t,
    u16* __restrict__ upd16)
{
  __shared__ __align__(16) u16 lds_raw[16384];
  const int t = threadIdx.x;
  const int lane = t & 63, w = t >> 6;
  const int wi = w >> 1, wj = w & 1;
  const int lr = lane & 15, lg = lane >> 4;
  const int i0 = blockIdx.x * 64, j0 = blockIdx.y * 64;
  const int c  = blockIdx.z;

  const int srow = t >> 3;
  const int ssl  = t & 7;
  const size_t cofs = (size_t)c*64 + ssl*8;

  f32x4 acc[2][2];
  const f32x4 zero4 = {0.f,0.f,0.f,0.f};
  acc[0][0]=zero4; acc[0][1]=zero4; acc[1][0]=zero4; acc[1][1]=zero4;

  u16* ldsL = lds_raw;
  u16* ldsR = lds_raw + 8192;

  {
    #pragma unroll
    for (int q=0;q<2;q++){
      int row = q*32 + srow;
      int sw = ssl ^ (row & 7);
      uint4 vL = *(const uint4*)&left_t [(size_t)(i0+row)*65536 + cofs];
      uint4 vR = *(const uint4*)&right_t[(size_t)(j0+row)*65536 + cofs];
      *(uint4*)&ldsL[row*64 + sw*8] = vL;
      *(uint4*)&ldsR[row*64 + sw*8] = vR;
    }
  }
  __syncthreads();

  for (int kt=0; kt<8; kt++){
    const int buf = kt & 1;
    uint4 pL[2], pR[2];
    if (kt < 7){
      size_t ko = (size_t)(kt+1)*8192 + cofs;
      #pragma unroll
      for (int q=0;q<2;q++){
        int row = q*32 + srow;
        pL[q] = *(const uint4*)&left_t [(size_t)(i0+row)*65536 + ko];
        pR[q] = *(const uint4*)&right_t[(size_t)(j0+row)*65536 + ko];
      }
    }
    #pragma unroll
    for (int kk=0;kk<2;kk++){
      bf16x8 af[2], bfr[2];
      #pragma unroll
      for (int mi=0;mi<2;mi++){
        int row = wi*32 + mi*16 + lr;
        af[mi] = *(const bf16x8*)&ldsL[buf*4096 + row*64 + (((kk*4+lg) ^ (row&7)))*8];
      }
      #pragma unroll
      for (int nj=0;nj<2;nj++){
        int row = wj*32 + nj*16 + lr;
        bfr[nj] = *(const bf16x8*)&ldsR[buf*4096 + row*64 + (((kk*4+lg) ^ (row&7)))*8];
      }
      #pragma unroll
      for (int mi=0;mi<2;mi++)
        #pragma unroll
        for (int nj=0;nj<2;nj++)
          acc[mi][nj] = __builtin_amdgcn_mfma_f32_16x16x32_bf16(af[mi], bfr[nj], acc[mi][nj], 0,0,0);
    }
    if (kt < 7){
      #pragma unroll
      for (int q=0;q<2;q++){
        int row = q*32 + srow;
        int sw = ssl ^ (row & 7);
        *(uint4*)&ldsL[(buf^1)*4096 + row*64 + sw*8] = pL[q];
        *(uint4*)&ldsR[(buf^1)*4096 + row*64 + sw*8] = pR[q];
      }
    }
    __syncthreads();
  }

  const float scale = 0.044194173824159216f;   // 1/sqrt(512)
  u16* st = lds_raw;
  #pragma unroll
  for (int mi=0;mi<2;mi++){
    #pragma unroll
    for (int nj=0;nj<2;nj++){
      int cj = wj*32 + nj*16 + lr;
      #pragma unroll
      for (int g2=0;g2<4;g2++){
        int ri = wi*32 + mi*16 + lg*4 + g2;
        st[ri*72 + cj] = f2bf(acc[mi][nj][g2] * scale);
      }
    }
  }
  __syncthreads();
  {
    int ri = t >> 2, q = t & 3;
    const uint4* src = (const uint4*)&st[ri*72 + q*16];
    uint4* dst = (uint4*)(upd16 + (size_t)c*NN + (size_t)(i0+ri)*NSEQ + j0 + q*16);
    dst[0] = src[0];
    dst[1] = src[1];
  }
}

// ------------- k3a: LN over c of upd16 [c][i*512+j] -> znu [row][c] bf16 --
__global__ __launch_bounds__(256) void k3a_ln(
    const u16* __restrict__ upd16, const float* __restrict__ onw,
    const float* __restrict__ onb, u16* __restrict__ znu)
{
  __shared__ float u[128*129];
  __shared__ float onw_s[128], onb_s[128];
  const int t = threadIdx.x;
  const int i = blockIdx.x;
  const int j0 = blockIdx.y * 128;

  if (t < 32)      ((float4*)onw_s)[t]    = ((const float4*)onw)[t];
  else if (t < 64) ((float4*)onb_s)[t-32] = ((const float4*)onb)[t-32];

  {
    int cr = t >> 1, h = t & 1;
    const uint4* src = (const uint4*)(upd16 + (size_t)cr*NN + (size_t)i*NSEQ + j0 + h*64);
    float* dst = &u[cr*129 + h*64];
    #pragma unroll
    for (int e=0;e<8;e++){
      uint4 v = src[e];
      const u16* hp = (const u16*)&v;
      #pragma unroll
      for (int p=0;p<8;p++) dst[e*8+p] = bf2f(hp[p]);
    }
  }
  __syncthreads();

  int j = t >> 1, h = t & 1;
  float s = 0.f, sq = 0.f;
  #pragma unroll
  for (int e=0;e<64;e++){
    float v = u[(h*64+e)*129 + j];
    s += v; sq += v*v;
  }
  s += __shfl_xor(s,1); sq += __shfl_xor(sq,1);
  float mu = s * (1.f/128.f);
  float rstd = __builtin_amdgcn_rsqf(sq * (1.f/128.f) - mu*mu + 1e-5f);

  uint32_t pk[32];
  #pragma unroll
  for (int e=0;e<64;e+=2){
    int c0 = h*64 + e;
    float v0 = (u[c0*129 + j]     - mu)*rstd*onw_s[c0]   + onb_s[c0];
    float v1 = (u[(c0+1)*129 + j] - mu)*rstd*onw_s[c0+1] + onb_s[c0+1];
    pk[e>>1] = cvtpk(v0, v1);
  }
  uint4* dst = (uint4*)(znu + ((size_t)i*NSEQ + j0 + j)*CH + h*64);
  #pragma unroll
  for (int e=0;e<8;e++) dst[e] = make_uint4(pk[e*4], pk[e*4+1], pk[e*4+2], pk[e*4+3]);
}

// ------------- k3b: out = (LN'd-update @ W_out^T) * sigm(zn@W_og^T+b) * mask
__global__ __launch_bounds__(256) void k3b_out(
    const u16* __restrict__ znu, const u16* __restrict__ znS,
    const float* __restrict__ pmask, const float* __restrict__ b_og,
    const u16* __restrict__ wts, float* __restrict__ out)
{
  __shared__ __align__(16) u16 uL[64][136];
  __shared__ __align__(16) u16 zL[64][136];
  __shared__ float mask_s[64];
  const int t = threadIdx.x;
  const int row0 = blockIdx.x * 64;

  #pragma unroll
  for (int k=0;k<4;k++){
    uint4 vu = *(const uint4*)(znu + (size_t)row0*CH + k*2048 + t*8);
    uint4 vz = *(const uint4*)(znS + (size_t)row0*CH + k*2048 + t*8);
    int r = k*16 + (t>>4), g = t & 15;
    *(uint4*)&uL[r][g*8] = vu;
    *(uint4*)&zL[r][g*8] = vz;
  }
  if (t < 16) ((float4*)mask_s)[t] = ((const float4*)(pmask + row0))[t];
  __syncthreads();

  const int lane = t & 63, w = t >> 6;
  const int lr = lane & 15, lg = lane >> 4;

  f32x4 acc_o[4][2], acc_g[4][2];
  const f32x4 zero4 = {0.f,0.f,0.f,0.f};
  #pragma unroll
  for (int mi=0;mi<4;mi++){ acc_o[mi][0]=zero4; acc_o[mi][1]=zero4; acc_g[mi][0]=zero4; acc_g[mi][1]=zero4; }

  // GEMM1: znu @ W_out^T
  #pragma unroll
  for (int kk=0;kk<4;kk++){
    bf16x8 a[4];
    #pragma unroll
    for (int mi=0;mi<4;mi++)
      a[mi] = *(const bf16x8*)&uL[mi*16 + lr][kk*32 + lg*8];
    #pragma unroll
    for (int n=0;n<2;n++){
      int o = w*32 + n*16 + lr;
      bf16x8 b = *(const bf16x8*)&wts[5*16384 + o*128 + kk*32 + lg*8];
      #pragma unroll
      for (int mi=0;mi<4;mi++)
        acc_o[mi][n] = __builtin_amdgcn_mfma_f32_16x16x32_bf16(a[mi], b, acc_o[mi][n], 0,0,0);
    }
  }
  // GEMM2: znS @ W_ogate^T
  #pragma unroll
  for (int kk=0;kk<4;kk++){
    bf16x8 a[4];
    #pragma unroll
    for (int mi=0;mi<4;mi++)
      a[mi] = *(const bf16x8*)&zL[mi*16 + lr][kk*32 + lg*8];
    #pragma unroll
    for (int n=0;n<2;n++){
      int o = w*32 + n*16 + lr;
      bf16x8 b = *(const bf16x8*)&wts[4*16384 + o*128 + kk*32 + lg*8];
      #pragma unroll
      for (int mi=0;mi<4;mi++)
        acc_g[mi][n] = __builtin_amdgcn_mfma_f32_16x16x32_bf16(a[mi], b, acc_g[mi][n], 0,0,0);
    }
  }

  // combine in-register (identical C-layouts) + direct fp32 stores
  #pragma unroll
  for (int n=0;n<2;n++){
    int o = w*32 + n*16 + lr;
    float bgv = b_og[o];
    #pragma unroll
    for (int mi=0;mi<4;mi++){
      #pragma unroll
      for (int g2=0;g2<4;g2++){
        int r = mi*16 + lg*4 + g2;
        float val = acc_o[mi][n][g2] * sigm(acc_g[mi][n][g2] + bgv) * mask_s[r];
        out[(size_t)(row0 + r)*CH + o] = val;
      }
    }
  }
}

// --------------------------- launcher ------------------------------------
extern "C" void kernel_launch(void* const* d_in, const int* in_sizes, int n_in,
                              void* d_out, int out_size, void* d_ws, size_t ws_size,
                              hipStream_t stream)
{
  const float* z       = (const float*)d_in[0];
  const float* pmask   = (const float*)d_in[1];
  const float* lnw     = (const float*)d_in[2];
  const float* lnb     = (const float*)d_in[3];
  const float* W_left  = (const float*)d_in[4];
  const float* W_right = (const float*)d_in[5];
  const float* W_lgate = (const float*)d_in[6];
  const float* b_lgate = (const float*)d_in[7];
  const float* W_rgate = (const float*)d_in[8];
  const float* b_rgate = (const float*)d_in[9];
  const float* onw     = (const float*)d_in[10];
  const float* onb     = (const float*)d_in[11];
  const float* W_out   = (const float*)d_in[12];
  const float* W_ogate = (const float*)d_in[13];
  const float* b_ogate = (const float*)d_in[14];

  const size_t SLOT = 67108864;   // 64 MiB
  uint8_t* ws = (uint8_t*)d_ws;
  u16* left_t  = (u16*)(ws);               // [i][kb][c][kin]; reused as znu after k2
  u16* right_t = (u16*)(ws + SLOT);
  u16* znS     = (u16*)(ws + 2*SLOT);      // LN(z) bf16 [row][c]
  u16* wts     = (u16*)(ws + 3*SLOT);
  u16* upd16   = (u16*)d_out;              // d_out doubles as bf16 update scratch

  k0_cvt<<<96, 256, 0, stream>>>(W_left, W_lgate, W_right, W_rgate, W_ogate, W_out, wts);
  k1a_ln<<<4096, 256, 0, stream>>>(z, lnw, lnb, znS);
  k1b_proj<<<2048, 256, 0, stream>>>(znS, pmask, b_lgate, b_rgate, wts, left_t, right_t);
  k2_einsum<<<dim3(8,8,128), 256, 0, stream>>>(left_t, right_t, upd16);
  k3a_ln<<<dim3(512,4), 256, 0, stream>>>(upd16, onw, onb, left_t /*znu*/);
  k3b_out<<<4096, 256, 0, stream>>>(left_t /*znu*/, znS, pmask, b_ogate, wts, (float*)d_out);
}

// Round 8
// 318.000 us; speedup vs baseline: 1.3185x; 1.1279x over previous
//
#include <hip/hip_runtime.h>
#include <stdint.h>

#define NSEQ 512
#define CH   128
#define NN   (NSEQ*NSEQ)   // 262144

typedef unsigned short u16;
typedef __attribute__((ext_vector_type(8))) short bf16x8;  // 8 bf16 = 4 VGPRs
typedef __attribute__((ext_vector_type(4))) float f32x4;

__device__ __forceinline__ u16 f2bf(float x){          // RNE
  uint32_t u = __float_as_uint(x);
  u += 0x7fffu + ((u >> 16) & 1u);
  return (u16)(u >> 16);
}
__device__ __forceinline__ float bf2f(u16 h){
  return __uint_as_float(((uint32_t)h) << 16);
}
__device__ __forceinline__ uint32_t cvtpk(float lo, float hi){  // bf16(lo)|bf16(hi)<<16
  uint32_t r;
  asm volatile("v_cvt_pk_bf16_f32 %0, %1, %2" : "=v"(r) : "v"(lo), "v"(hi));
  return r;
}
__device__ __forceinline__ float sigm(float x){
  return __builtin_amdgcn_rcpf(1.0f + __expf(-x));
}

// left/right tensor layout: [i (512)][kblk (8)][c (128)][kin (64)] u16
// offset = i*65536 + kblk*8192 + c*64 + kin   (flat row n = i*512 + kblk*64 + kin)

// ------------- k0: cast 6 weight matrices fp32 -> bf16 -------------
// slot order: 0=W_left 1=W_lgate 2=W_right 3=W_rgate 4=W_ogate 5=W_out
__global__ void k0_cvt(const float* __restrict__ w0, const float* __restrict__ w1,
                       const float* __restrict__ w2, const float* __restrict__ w3,
                       const float* __restrict__ w4, const float* __restrict__ w5,
                       u16* __restrict__ out)
{
  int mat = blockIdx.x >> 4;
  int blk = blockIdx.x & 15;
  const float* src = (mat==0)?w0:(mat==1)?w1:(mat==2)?w2:(mat==3)?w3:(mat==4)?w4:w5;
  int idx = (blk*256 + (int)threadIdx.x) * 4;
  float4 v = *(const float4*)(src + idx);
  uint2 pk;
  pk.x = cvtpk(v.x, v.y);
  pk.y = cvtpk(v.z, v.w);
  *(uint2*)(out + mat*16384 + idx) = pk;
}

// ------------- k1a: LN(z) -> znS bf16 [row][c], pure streaming ------------
__global__ __launch_bounds__(256) void k1a_ln(
    const float* __restrict__ z, const float* __restrict__ lnw,
    const float* __restrict__ lnb, u16* __restrict__ znS)
{
  __shared__ float lnw_s[128], lnb_s[128];
  const int t = threadIdx.x;
  const int row0 = blockIdx.x * 64;
  if (t < 32)      ((float4*)lnw_s)[t]    = ((const float4*)lnw)[t];
  else if (t < 64) ((float4*)lnb_s)[t-32] = ((const float4*)lnb)[t-32];
  __syncthreads();

  int r = t >> 2, q = t & 3;
  const float* zp = z + (size_t)(row0 + r) * CH + q * 32;
  float4 v[8];
  #pragma unroll
  for (int e=0;e<8;e++) v[e] = ((const float4*)zp)[e];
  float s = 0.f, sq = 0.f;
  #pragma unroll
  for (int e=0;e<8;e++){
    s  += v[e].x + v[e].y + v[e].z + v[e].w;
    sq += v[e].x*v[e].x + v[e].y*v[e].y + v[e].z*v[e].z + v[e].w*v[e].w;
  }
  s += __shfl_xor(s,1); sq += __shfl_xor(sq,1);
  s += __shfl_xor(s,2); sq += __shfl_xor(sq,2);
  float mu = s * (1.f/128.f);
  float rstd = __builtin_amdgcn_rsqf(sq * (1.f/128.f) - mu*mu + 1e-5f);
  uint32_t pk[16];
  #pragma unroll
  for (int e=0;e<8;e++){
    int c = q*32 + e*4;
    float a0 = (v[e].x - mu)*rstd*lnw_s[c+0] + lnb_s[c+0];
    float a1 = (v[e].y - mu)*rstd*lnw_s[c+1] + lnb_s[c+1];
    float a2 = (v[e].z - mu)*rstd*lnw_s[c+2] + lnb_s[c+2];
    float a3 = (v[e].w - mu)*rstd*lnw_s[c+3] + lnb_s[c+3];
    pk[e*2+0] = cvtpk(a0, a1);
    pk[e*2+1] = cvtpk(a2, a3);
  }
  uint4* dst = (uint4*)(znS + (size_t)(row0 + r)*CH + q*32);
  #pragma unroll
  for (int e=0;e<4;e++) dst[e] = make_uint4(pk[e*4], pk[e*4+1], pk[e*4+2], pk[e*4+3]);
}

// ------------- k1b: 2 gated projections, 2 row-tiles per block ------------
__global__ __launch_bounds__(256) void k1b_proj(
    const u16* __restrict__ znS, const float* __restrict__ pmask,
    const float* __restrict__ b_lg, const float* __restrict__ b_rg,
    const u16* __restrict__ wts,
    u16* __restrict__ left_t, u16* __restrict__ right_t)
{
  __shared__ __align__(16) u16 zn[2][64][136];  // 34 KB
  __shared__ __align__(16) u16 stg[4][2048];    // 16 KB (per-wave stage)
  __shared__ float mask_s[128];
  const int t = threadIdx.x;
  const int row0 = blockIdx.x * 128;

  const int lane = t & 63;
  const int w = t >> 6;
  const int lr = lane & 15;
  const int lg = lane >> 4;
  const int ow = w*32;

  uint4 za[4], zb[4];
  #pragma unroll
  for (int k=0;k<4;k++) za[k] = *(const uint4*)(znS + (size_t)row0*CH + k*2048 + t*8);
  #pragma unroll
  for (int k=0;k<4;k++) zb[k] = *(const uint4*)(znS + (size_t)(row0+64)*CH + k*2048 + t*8);
  if (t < 32) ((float4*)mask_s)[t] = ((const float4*)(pmask + row0))[t];
  #pragma unroll
  for (int k=0;k<4;k++){
    int r = k*16 + (t>>4), g = t & 15;
    *(uint4*)&zn[0][r][g*8] = za[k];
  }
  #pragma unroll
  for (int k=0;k<4;k++){
    int r = k*16 + (t>>4), g = t & 15;
    *(uint4*)&zn[1][r][g*8] = zb[k];
  }
  __syncthreads();   // the ONLY barrier

  const f32x4 zero4 = {0.f,0.f,0.f,0.f};

  #pragma unroll
  for (int tt=0; tt<2; tt++){
    const int r0t = row0 + tt*64;
    const size_t tile_off = (size_t)(r0t >> 9)*65536 + (size_t)((r0t >> 6) & 7)*8192;
    const float* msk = mask_s + tt*64;

    bf16x8 wl[8], wg[8];
    #pragma unroll
    for (int kk=0;kk<4;kk++)
      #pragma unroll
      for (int n=0;n<2;n++){
        int o = ow + n*16 + lr;
        wl[kk*2+n] = *(const bf16x8*)&wts[0*16384 + o*128 + kk*32 + lg*8];
        wg[kk*2+n] = *(const bf16x8*)&wts[1*16384 + o*128 + kk*32 + lg*8];
      }

    f32x4 acc1[4][2], acc2[4][2];
    #pragma unroll
    for (int mi=0;mi<4;mi++){ acc1[mi][0]=zero4; acc1[mi][1]=zero4; acc2[mi][0]=zero4; acc2[mi][1]=zero4; }
    #pragma unroll
    for (int kk=0;kk<4;kk++){
      bf16x8 a[4];
      #pragma unroll
      for (int mi=0;mi<4;mi++)
        a[mi] = *(const bf16x8*)&zn[tt][mi*16 + lr][kk*32 + lg*8];
      #pragma unroll
      for (int n=0;n<2;n++)
        #pragma unroll
        for (int mi=0;mi<4;mi++){
          acc1[mi][n] = __builtin_amdgcn_mfma_f32_16x16x32_bf16(a[mi], wl[kk*2+n], acc1[mi][n], 0,0,0);
          acc2[mi][n] = __builtin_amdgcn_mfma_f32_16x16x32_bf16(a[mi], wg[kk*2+n], acc2[mi][n], 0,0,0);
        }
    }
    bf16x8 wl2[8], wg2[8];
    #pragma unroll
    for (int kk=0;kk<4;kk++)
      #pragma unroll
      for (int n=0;n<2;n++){
        int o = ow + n*16 + lr;
        wl2[kk*2+n] = *(const bf16x8*)&wts[2*16384 + o*128 + kk*32 + lg*8];
        wg2[kk*2+n] = *(const bf16x8*)&wts[3*16384 + o*128 + kk*32 + lg*8];
      }

    #pragma unroll
    for (int n=0;n<2;n++){
      int ol = n*16 + lr;
      float bgv = b_lg[ow + ol];
      #pragma unroll
      for (int mi=0;mi<4;mi++){
        int r0 = mi*16 + lg*4;
        float v0 = acc1[mi][n][0] * sigm(acc2[mi][n][0] + bgv) * msk[r0+0];
        float v1 = acc1[mi][n][1] * sigm(acc2[mi][n][1] + bgv) * msk[r0+1];
        float v2 = acc1[mi][n][2] * sigm(acc2[mi][n][2] + bgv) * msk[r0+2];
        float v3 = acc1[mi][n][3] * sigm(acc2[mi][n][3] + bgv) * msk[r0+3];
        int chunk = (mi*2 + (lg>>1)) ^ (ol & 7);
        *(uint2*)&stg[w][ol*64 + (chunk<<3) + (lg&1)*4] = make_uint2(cvtpk(v0,v1), cvtpk(v2,v3));
      }
    }
    {
      int ol = lane >> 1, rh = lane & 1;
      uint4 pf[4];
      #pragma unroll
      for (int q=0;q<4;q++){
        int m = (rh*4 + q) ^ (ol & 7);
        pf[q] = *(const uint4*)&stg[w][ol*64 + (m<<3)];
      }
      uint4* dst = (uint4*)(left_t + tile_off + (ow + ol)*64 + rh*32);
      #pragma unroll
      for (int q=0;q<4;q++) dst[q] = pf[q];
    }

    #pragma unroll
    for (int mi=0;mi<4;mi++){ acc1[mi][0]=zero4; acc1[mi][1]=zero4; acc2[mi][0]=zero4; acc2[mi][1]=zero4; }
    #pragma unroll
    for (int kk=0;kk<4;kk++){
      bf16x8 a[4];
      #pragma unroll
      for (int mi=0;mi<4;mi++)
        a[mi] = *(const bf16x8*)&zn[tt][mi*16 + lr][kk*32 + lg*8];
      #pragma unroll
      for (int n=0;n<2;n++)
        #pragma unroll
        for (int mi=0;mi<4;mi++){
          acc1[mi][n] = __builtin_amdgcn_mfma_f32_16x16x32_bf16(a[mi], wl2[kk*2+n], acc1[mi][n], 0,0,0);
          acc2[mi][n] = __builtin_amdgcn_mfma_f32_16x16x32_bf16(a[mi], wg2[kk*2+n], acc2[mi][n], 0,0,0);
        }
    }
    #pragma unroll
    for (int n=0;n<2;n++){
      int ol = n*16 + lr;
      float bgv = b_rg[ow + ol];
      #pragma unroll
      for (int mi=0;mi<4;mi++){
        int r0 = mi*16 + lg*4;
        float v0 = acc1[mi][n][0] * sigm(acc2[mi][n][0] + bgv) * msk[r0+0];
        float v1 = acc1[mi][n][1] * sigm(acc2[mi][n][1] + bgv) * msk[r0+1];
        float v2 = acc1[mi][n][2] * sigm(acc2[mi][n][2] + bgv) * msk[r0+2];
        float v3 = acc1[mi][n][3] * sigm(acc2[mi][n][3] + bgv) * msk[r0+3];
        int chunk = (mi*2 + (lg>>1)) ^ (ol & 7);
        *(uint2*)&stg[w][ol*64 + (chunk<<3) + (lg&1)*4] = make_uint2(cvtpk(v0,v1), cvtpk(v2,v3));
      }
    }
    {
      int ol = lane >> 1, rh = lane & 1;
      uint4 pf[4];
      #pragma unroll
      for (int q=0;q<4;q++){
        int m = (rh*4 + q) ^ (ol & 7);
        pf[q] = *(const uint4*)&stg[w][ol*64 + (m<<3)];
      }
      uint4* dst = (uint4*)(right_t + tile_off + (ow + ol)*64 + rh*32);
      #pragma unroll
      for (int q=0;q<4;q++) dst[q] = pf[q];
    }
  }
}

// ------------- k2: per-channel 64x64x512 GEMM, bf16 output ----------------
__global__ __launch_bounds__(256) void k2_einsum(
    const u16* __restrict__ left_t, const u16* __restrict__ right_t,
    u16* __restrict__ upd16)
{
  __shared__ __align__(16) u16 lds_raw[16384];
  const int t = threadIdx.x;
  const int lane = t & 63, w = t >> 6;
  const int wi = w >> 1, wj = w & 1;
  const int lr = lane & 15, lg = lane >> 4;
  const int i0 = blockIdx.x * 64, j0 = blockIdx.y * 64;
  const int c  = blockIdx.z;

  const int srow = t >> 3;
  const int ssl  = t & 7;
  const size_t cofs = (size_t)c*64 + ssl*8;

  f32x4 acc[2][2];
  const f32x4 zero4 = {0.f,0.f,0.f,0.f};
  acc[0][0]=zero4; acc[0][1]=zero4; acc[1][0]=zero4; acc[1][1]=zero4;

  u16* ldsL = lds_raw;
  u16* ldsR = lds_raw + 8192;

  {
    #pragma unroll
    for (int q=0;q<2;q++){
      int row = q*32 + srow;
      int sw = ssl ^ (row & 7);
      uint4 vL = *(const uint4*)&left_t [(size_t)(i0+row)*65536 + cofs];
      uint4 vR = *(const uint4*)&right_t[(size_t)(j0+row)*65536 + cofs];
      *(uint4*)&ldsL[row*64 + sw*8] = vL;
      *(uint4*)&ldsR[row*64 + sw*8] = vR;
    }
  }
  __syncthreads();

  for (int kt=0; kt<8; kt++){
    const int buf = kt & 1;
    uint4 pL[2], pR[2];
    if (kt < 7){
      size_t ko = (size_t)(kt+1)*8192 + cofs;
      #pragma unroll
      for (int q=0;q<2;q++){
        int row = q*32 + srow;
        pL[q] = *(const uint4*)&left_t [(size_t)(i0+row)*65536 + ko];
        pR[q] = *(const uint4*)&right_t[(size_t)(j0+row)*65536 + ko];
      }
    }
    #pragma unroll
    for (int kk=0;kk<2;kk++){
      bf16x8 af[2], bfr[2];
      #pragma unroll
      for (int mi=0;mi<2;mi++){
        int row = wi*32 + mi*16 + lr;
        af[mi] = *(const bf16x8*)&ldsL[buf*4096 + row*64 + (((kk*4+lg) ^ (row&7)))*8];
      }
      #pragma unroll
      for (int nj=0;nj<2;nj++){
        int row = wj*32 + nj*16 + lr;
        bfr[nj] = *(const bf16x8*)&ldsR[buf*4096 + row*64 + (((kk*4+lg) ^ (row&7)))*8];
      }
      #pragma unroll
      for (int mi=0;mi<2;mi++)
        #pragma unroll
        for (int nj=0;nj<2;nj++)
          acc[mi][nj] = __builtin_amdgcn_mfma_f32_16x16x32_bf16(af[mi], bfr[nj], acc[mi][nj], 0,0,0);
    }
    if (kt < 7){
      #pragma unroll
      for (int q=0;q<2;q++){
        int row = q*32 + srow;
        int sw = ssl ^ (row & 7);
        *(uint4*)&ldsL[(buf^1)*4096 + row*64 + sw*8] = pL[q];
        *(uint4*)&ldsR[(buf^1)*4096 + row*64 + sw*8] = pR[q];
      }
    }
    __syncthreads();
  }

  const float scale = 0.044194173824159216f;   // 1/sqrt(512)
  u16* st = lds_raw;
  #pragma unroll
  for (int mi=0;mi<2;mi++){
    #pragma unroll
    for (int nj=0;nj<2;nj++){
      int cj = wj*32 + nj*16 + lr;
      #pragma unroll
      for (int g2=0;g2<4;g2++){
        int ri = wi*32 + mi*16 + lg*4 + g2;
        st[ri*72 + cj] = f2bf(acc[mi][nj][g2] * scale);
      }
    }
  }
  __syncthreads();
  {
    int ri = t >> 2, q = t & 3;
    const uint4* src = (const uint4*)&st[ri*72 + q*16];
    uint4* dst = (uint4*)(upd16 + (size_t)c*NN + (size_t)(i0+ri)*NSEQ + j0 + q*16);
    dst[0] = src[0];
    dst[1] = src[1];
  }
}

// ------------- k3a: LN over c of upd16 [c][i*512+j] -> znu [row][c] bf16 --
__global__ __launch_bounds__(256) void k3a_ln(
    const u16* __restrict__ upd16, const float* __restrict__ onw,
    const float* __restrict__ onb, u16* __restrict__ znu)
{
  __shared__ float u[128*129];
  __shared__ float onw_s[128], onb_s[128];
  const int t = threadIdx.x;
  const int i = blockIdx.x;
  const int j0 = blockIdx.y * 128;

  if (t < 32)      ((float4*)onw_s)[t]    = ((const float4*)onw)[t];
  else if (t < 64) ((float4*)onb_s)[t-32] = ((const float4*)onb)[t-32];

  {
    int cr = t >> 1, h = t & 1;
    const uint4* src = (const uint4*)(upd16 + (size_t)cr*NN + (size_t)i*NSEQ + j0 + h*64);
    float* dst = &u[cr*129 + h*64];
    #pragma unroll
    for (int e=0;e<8;e++){
      uint4 v = src[e];
      const u16* hp = (const u16*)&v;
      #pragma unroll
      for (int p=0;p<8;p++) dst[e*8+p] = bf2f(hp[p]);
    }
  }
  __syncthreads();

  int j = t >> 1, h = t & 1;
  float s = 0.f, sq = 0.f;
  #pragma unroll
  for (int e=0;e<64;e++){
    float v = u[(h*64+e)*129 + j];
    s += v; sq += v*v;
  }
  s += __shfl_xor(s,1); sq += __shfl_xor(sq,1);
  float mu = s * (1.f/128.f);
  float rstd = __builtin_amdgcn_rsqf(sq * (1.f/128.f) - mu*mu + 1e-5f);

  uint32_t pk[32];
  #pragma unroll
  for (int e=0;e<64;e+=2){
    int c0 = h*64 + e;
    float v0 = (u[c0*129 + j]     - mu)*rstd*onw_s[c0]   + onb_s[c0];
    float v1 = (u[(c0+1)*129 + j] - mu)*rstd*onw_s[c0+1] + onb_s[c0+1];
    pk[e>>1] = cvtpk(v0, v1);
  }
  uint4* dst = (uint4*)(znu + ((size_t)i*NSEQ + j0 + j)*CH + h*64);
  #pragma unroll
  for (int e=0;e<8;e++) dst[e] = make_uint4(pk[e*4], pk[e*4+1], pk[e*4+2], pk[e*4+3]);
}

// ------------- k3b: out = (LN'd-update @ W_out^T) * sigm(zn@W_og^T+b) * mask
__global__ __launch_bounds__(256) void k3b_out(
    const u16* __restrict__ znu, const u16* __restrict__ znS,
    const float* __restrict__ pmask, const float* __restrict__ b_og,
    const u16* __restrict__ wts, float* __restrict__ out)
{
  __shared__ __align__(16) u16 uL[64][136];
  __shared__ __align__(16) u16 zL[64][136];
  __shared__ float mask_s[64];
  const int t = threadIdx.x;
  const int row0 = blockIdx.x * 64;

  #pragma unroll
  for (int k=0;k<4;k++){
    uint4 vu = *(const uint4*)(znu + (size_t)row0*CH + k*2048 + t*8);
    uint4 vz = *(const uint4*)(znS + (size_t)row0*CH + k*2048 + t*8);
    int r = k*16 + (t>>4), g = t & 15;
    *(uint4*)&uL[r][g*8] = vu;
    *(uint4*)&zL[r][g*8] = vz;
  }
  if (t < 16) ((float4*)mask_s)[t] = ((const float4*)(pmask + row0))[t];
  __syncthreads();

  const int lane = t & 63, w = t >> 6;
  const int lr = lane & 15, lg = lane >> 4;

  f32x4 acc_o[4][2], acc_g[4][2];
  const f32x4 zero4 = {0.f,0.f,0.f,0.f};
  #pragma unroll
  for (int mi=0;mi<4;mi++){ acc_o[mi][0]=zero4; acc_o[mi][1]=zero4; acc_g[mi][0]=zero4; acc_g[mi][1]=zero4; }

  #pragma unroll
  for (int kk=0;kk<4;kk++){
    bf16x8 a[4];
    #pragma unroll
    for (int mi=0;mi<4;mi++)
      a[mi] = *(const bf16x8*)&uL[mi*16 + lr][kk*32 + lg*8];
    #pragma unroll
    for (int n=0;n<2;n++){
      int o = w*32 + n*16 + lr;
      bf16x8 b = *(const bf16x8*)&wts[5*16384 + o*128 + kk*32 + lg*8];
      #pragma unroll
      for (int mi=0;mi<4;mi++)
        acc_o[mi][n] = __builtin_amdgcn_mfma_f32_16x16x32_bf16(a[mi], b, acc_o[mi][n], 0,0,0);
    }
  }
  #pragma unroll
  for (int kk=0;kk<4;kk++){
    bf16x8 a[4];
    #pragma unroll
    for (int mi=0;mi<4;mi++)
      a[mi] = *(const bf16x8*)&zL[mi*16 + lr][kk*32 + lg*8];
    #pragma unroll
    for (int n=0;n<2;n++){
      int o = w*32 + n*16 + lr;
      bf16x8 b = *(const bf16x8*)&wts[4*16384 + o*128 + kk*32 + lg*8];
      #pragma unroll
      for (int mi=0;mi<4;mi++)
        acc_g[mi][n] = __builtin_amdgcn_mfma_f32_16x16x32_bf16(a[mi], b, acc_g[mi][n], 0,0,0);
    }
  }

  #pragma unroll
  for (int n=0;n<2;n++){
    int o = w*32 + n*16 + lr;
    float bgv = b_og[o];
    #pragma unroll
    for (int mi=0;mi<4;mi++){
      #pragma unroll
      for (int g2=0;g2<4;g2++){
        int r = mi*16 + lg*4 + g2;
        float val = acc_o[mi][n][g2] * sigm(acc_g[mi][n][g2] + bgv) * mask_s[r];
        out[(size_t)(row0 + r)*CH + o] = val;
      }
    }
  }
}

// ------------- k3bf: FUSED LN(update) + dual GEMM + gate + store ----------
// Per 64-row block: upd16 columns -> regs (coalesced 128B lines), LN over c,
// normalized bf16 into proven zn[64][136], then exact k3b GEMM body.
__global__ __launch_bounds__(256) void k3bf_out(
    const u16* __restrict__ upd16, const u16* __restrict__ znS,
    const float* __restrict__ pmask, const float* __restrict__ onw,
    const float* __restrict__ onb, const float* __restrict__ b_og,
    const u16* __restrict__ wts, float* __restrict__ out)
{
  __shared__ __align__(16) u16 zn[64][136];   // LN'd update (GEMM1 A operand)
  __shared__ __align__(16) u16 zL[64][136];   // znS tile   (GEMM2 A operand)
  __shared__ float ps[4][64], pq[4][64];
  __shared__ float st2[64][2];
  __shared__ float onw_s[128], onb_s[128], mask_s[64];

  const int t = threadIdx.x;
  const int row0 = blockIdx.x * 64;
  const int j  = t & 63;     // row within tile (lane-contiguous)
  const int h2 = t >> 6;     // channel quarter: c in [h2*32, h2*32+32)

  // znS tile loads (proven k3b pattern)
  uint4 vz[4];
  #pragma unroll
  for (int k=0;k<4;k++) vz[k] = *(const uint4*)(znS + (size_t)row0*CH + k*2048 + t*8);

  // upd16 column loads: v[e] = upd[c=h2*32+e][row0+j]; lanes j-consecutive
  // -> each instruction reads one coalesced 128B line.
  float v[32];
  #pragma unroll
  for (int e=0;e<32;e++){
    int c = h2*32 + e;
    v[e] = bf2f(upd16[(size_t)c*NN + row0 + j]);
  }

  if (t < 32)      ((float4*)onw_s)[t]     = ((const float4*)onw)[t];
  else if (t < 64) ((float4*)onb_s)[t-32]  = ((const float4*)onb)[t-32];
  else if (t < 80) ((float4*)mask_s)[t-64] = ((const float4*)(pmask + row0))[t-64];

  #pragma unroll
  for (int k=0;k<4;k++){
    int r = k*16 + (t>>4), g = t & 15;
    *(uint4*)&zL[r][g*8] = vz[k];
  }

  { // LN partial sums over this thread's 32 channels
    float s = 0.f, sq = 0.f;
    #pragma unroll
    for (int e=0;e<32;e++){ s += v[e]; sq += v[e]*v[e]; }
    ps[h2][j] = s; pq[h2][j] = sq;
  }
  __syncthreads();
  if (t < 64){
    float s  = ps[0][t]+ps[1][t]+ps[2][t]+ps[3][t];
    float sq = pq[0][t]+pq[1][t]+pq[2][t]+pq[3][t];
    float mu = s * (1.f/128.f);
    float rstd = __builtin_amdgcn_rsqf(sq * (1.f/128.f) - mu*mu + 1e-5f);
    st2[t][0] = mu; st2[t][1] = rstd;
  }
  __syncthreads();

  { // normalized bf16 into zn[j][h2*32 .. +31] (plain padded layout, no swizzle)
    float mu = st2[j][0], rstd = st2[j][1];
    #pragma unroll
    for (int q=0;q<4;q++){
      uint32_t pk[4];
      #pragma unroll
      for (int p=0;p<4;p++){
        int e = q*8 + p*2;
        int c = h2*32 + e;
        float y0 = (v[e]   - mu)*rstd*onw_s[c]   + onb_s[c];
        float y1 = (v[e+1] - mu)*rstd*onw_s[c+1] + onb_s[c+1];
        pk[p] = cvtpk(y0, y1);
      }
      *(uint4*)&zn[j][h2*32 + q*8] = make_uint4(pk[0],pk[1],pk[2],pk[3]);
    }
  }
  __syncthreads();

  // ===== exact k3b GEMM body (uL -> zn) =====
  const int lane = t & 63, w = t >> 6;
  const int lr = lane & 15, lg = lane >> 4;

  f32x4 acc_o[4][2], acc_g[4][2];
  const f32x4 zero4 = {0.f,0.f,0.f,0.f};
  #pragma unroll
  for (int mi=0;mi<4;mi++){ acc_o[mi][0]=zero4; acc_o[mi][1]=zero4; acc_g[mi][0]=zero4; acc_g[mi][1]=zero4; }

  #pragma unroll
  for (int kk=0;kk<4;kk++){
    bf16x8 a[4];
    #pragma unroll
    for (int mi=0;mi<4;mi++)
      a[mi] = *(const bf16x8*)&zn[mi*16 + lr][kk*32 + lg*8];
    #pragma unroll
    for (int n=0;n<2;n++){
      int o = w*32 + n*16 + lr;
      bf16x8 b = *(const bf16x8*)&wts[5*16384 + o*128 + kk*32 + lg*8];
      #pragma unroll
      for (int mi=0;mi<4;mi++)
        acc_o[mi][n] = __builtin_amdgcn_mfma_f32_16x16x32_bf16(a[mi], b, acc_o[mi][n], 0,0,0);
    }
  }
  #pragma unroll
  for (int kk=0;kk<4;kk++){
    bf16x8 a[4];
    #pragma unroll
    for (int mi=0;mi<4;mi++)
      a[mi] = *(const bf16x8*)&zL[mi*16 + lr][kk*32 + lg*8];
    #pragma unroll
    for (int n=0;n<2;n++){
      int o = w*32 + n*16 + lr;
      bf16x8 b = *(const bf16x8*)&wts[4*16384 + o*128 + kk*32 + lg*8];
      #pragma unroll
      for (int mi=0;mi<4;mi++)
        acc_g[mi][n] = __builtin_amdgcn_mfma_f32_16x16x32_bf16(a[mi], b, acc_g[mi][n], 0,0,0);
    }
  }

  #pragma unroll
  for (int n=0;n<2;n++){
    int o = w*32 + n*16 + lr;
    float bgv = b_og[o];
    #pragma unroll
    for (int mi=0;mi<4;mi++){
      #pragma unroll
      for (int g2=0;g2<4;g2++){
        int r = mi*16 + lg*4 + g2;
        float val = acc_o[mi][n][g2] * sigm(acc_g[mi][n][g2] + bgv) * mask_s[r];
        out[(size_t)(row0 + r)*CH + o] = val;
      }
    }
  }
}

// --------------------------- launcher ------------------------------------
extern "C" void kernel_launch(void* const* d_in, const int* in_sizes, int n_in,
                              void* d_out, int out_size, void* d_ws, size_t ws_size,
                              hipStream_t stream)
{
  const float* z       = (const float*)d_in[0];
  const float* pmask   = (const float*)d_in[1];
  const float* lnw     = (const float*)d_in[2];
  const float* lnb     = (const float*)d_in[3];
  const float* W_left  = (const float*)d_in[4];
  const float* W_right = (const float*)d_in[5];
  const float* W_lgate = (const float*)d_in[6];
  const float* b_lgate = (const float*)d_in[7];
  const float* W_rgate = (const float*)d_in[8];
  const float* b_rgate = (const float*)d_in[9];
  const float* onw     = (const float*)d_in[10];
  const float* onb     = (const float*)d_in[11];
  const float* W_out   = (const float*)d_in[12];
  const float* W_ogate = (const float*)d_in[13];
  const float* b_ogate = (const float*)d_in[14];

  const size_t SLOT = 67108864;   // 64 MiB
  uint8_t* ws = (uint8_t*)d_ws;
  u16* left_t  = (u16*)(ws);
  u16* right_t = (u16*)(ws + SLOT);
  u16* znS     = (u16*)(ws + 2*SLOT);

  const bool fused = (ws_size >= 4*SLOT + 196608);
  u16* wts   = (u16*)(ws + (fused ? 4*SLOT : 3*SLOT));
  u16* upd16 = fused ? (u16*)(ws + 3*SLOT) : (u16*)d_out;

  k0_cvt<<<96, 256, 0, stream>>>(W_left, W_lgate, W_right, W_rgate, W_ogate, W_out, wts);
  k1a_ln<<<4096, 256, 0, stream>>>(z, lnw, lnb, znS);
  k1b_proj<<<2048, 256, 0, stream>>>(znS, pmask, b_lgate, b_rgate, wts, left_t, right_t);
  k2_einsum<<<dim3(8,8,128), 256, 0, stream>>>(left_t, right_t, upd16);

  if (fused){
    k3bf_out<<<4096, 256, 0, stream>>>(upd16, znS, pmask, onw, onb, b_ogate, wts,
                                       (float*)d_out);
  } else {
    k3a_ln<<<dim3(512,4), 256, 0, stream>>>(upd16, onw, onb, left_t /*znu*/);
    k3b_out<<<4096, 256, 0, stream>>>(left_t /*znu*/, znS, pmask, b_ogate, wts,
                                      (float*)d_out);
  }
}

// Round 9
// 316.506 us; speedup vs baseline: 1.3247x; 1.0047x over previous
//
#include <hip/hip_runtime.h>
#include <stdint.h>

#define NSEQ 512
#define CH   128
#define NN   (NSEQ*NSEQ)   // 262144

typedef unsigned short u16;
typedef __attribute__((ext_vector_type(8))) short bf16x8;  // 8 bf16 = 4 VGPRs
typedef __attribute__((ext_vector_type(4))) float f32x4;

__device__ __forceinline__ u16 f2bf(float x){          // RNE
  uint32_t u = __float_as_uint(x);
  u += 0x7fffu + ((u >> 16) & 1u);
  return (u16)(u >> 16);
}
__device__ __forceinline__ float bf2f(u16 h){
  return __uint_as_float(((uint32_t)h) << 16);
}
__device__ __forceinline__ uint32_t cvtpk(float lo, float hi){  // bf16(lo)|bf16(hi)<<16
  uint32_t r;
  asm volatile("v_cvt_pk_bf16_f32 %0, %1, %2" : "=v"(r) : "v"(lo), "v"(hi));
  return r;
}
__device__ __forceinline__ float sigm(float x){
  return __builtin_amdgcn_rcpf(1.0f + __expf(-x));
}

// left/right tensor layout: [i (512)][kblk (8)][c (128)][kin (64)] u16
// offset = i*65536 + kblk*8192 + c*64 + kin   (flat row n = i*512 + kblk*64 + kin)

// ------------- k0: cast 6 weight matrices fp32 -> bf16 -------------
// slot order: 0=W_left 1=W_lgate 2=W_right 3=W_rgate 4=W_ogate 5=W_out
__global__ void k0_cvt(const float* __restrict__ w0, const float* __restrict__ w1,
                       const float* __restrict__ w2, const float* __restrict__ w3,
                       const float* __restrict__ w4, const float* __restrict__ w5,
                       u16* __restrict__ out)
{
  int mat = blockIdx.x >> 4;
  int blk = blockIdx.x & 15;
  const float* src = (mat==0)?w0:(mat==1)?w1:(mat==2)?w2:(mat==3)?w3:(mat==4)?w4:w5;
  int idx = (blk*256 + (int)threadIdx.x) * 4;
  float4 v = *(const float4*)(src + idx);
  uint2 pk;
  pk.x = cvtpk(v.x, v.y);
  pk.y = cvtpk(v.z, v.w);
  *(uint2*)(out + mat*16384 + idx) = pk;
}

// ------------- k1ab: FUSED LN(z) + 2 gated projections, 128 rows/block ----
// LN computed in-block (k1a's exact per-64-row code, run twice); znS written
// once for k3bf's ogate GEMM; then the proven 2-tile projection body.
__global__ __launch_bounds__(256) void k1ab_proj(
    const float* __restrict__ z, const float* __restrict__ pmask,
    const float* __restrict__ lnw, const float* __restrict__ lnb,
    const float* __restrict__ b_lg, const float* __restrict__ b_rg,
    const u16* __restrict__ wts, u16* __restrict__ znS,
    u16* __restrict__ left_t, u16* __restrict__ right_t)
{
  __shared__ __align__(16) u16 zn[2][64][136];  // 34 KB
  __shared__ __align__(16) u16 stg[4][2048];    // 16 KB (per-wave stage)
  __shared__ float lnw_s[128], lnb_s[128], mask_s[128];
  const int t = threadIdx.x;
  const int row0 = blockIdx.x * 128;

  // param loads + both tiles' z loads issued up-front (256B/thread in flight)
  if (t < 32)      ((float4*)lnw_s)[t]     = ((const float4*)lnw)[t];
  else if (t < 64) ((float4*)lnb_s)[t-32]  = ((const float4*)lnb)[t-32];
  else if (t < 96) ((float4*)mask_s)[t-64] = ((const float4*)(pmask + row0))[t-64];

  const int r = t >> 2, q = t & 3;
  float4 v0[8], v1[8];
  {
    const float* zp0 = z + (size_t)(row0 + r) * CH + q * 32;
    const float* zp1 = z + (size_t)(row0 + 64 + r) * CH + q * 32;
    #pragma unroll
    for (int e=0;e<8;e++) v0[e] = ((const float4*)zp0)[e];
    #pragma unroll
    for (int e=0;e<8;e++) v1[e] = ((const float4*)zp1)[e];
  }
  __syncthreads();   // lnw_s/lnb_s/mask_s visible

  // ----- LN tile 0 (k1a's exact math) -----
  {
    float s = 0.f, sq = 0.f;
    #pragma unroll
    for (int e=0;e<8;e++){
      s  += v0[e].x + v0[e].y + v0[e].z + v0[e].w;
      sq += v0[e].x*v0[e].x + v0[e].y*v0[e].y + v0[e].z*v0[e].z + v0[e].w*v0[e].w;
    }
    s += __shfl_xor(s,1); sq += __shfl_xor(sq,1);
    s += __shfl_xor(s,2); sq += __shfl_xor(sq,2);
    float mu = s * (1.f/128.f);
    float rstd = __builtin_amdgcn_rsqf(sq * (1.f/128.f) - mu*mu + 1e-5f);
    uint32_t pk[16];
    #pragma unroll
    for (int e=0;e<8;e++){
      int c = q*32 + e*4;
      float a0 = (v0[e].x - mu)*rstd*lnw_s[c+0] + lnb_s[c+0];
      float a1 = (v0[e].y - mu)*rstd*lnw_s[c+1] + lnb_s[c+1];
      float a2 = (v0[e].z - mu)*rstd*lnw_s[c+2] + lnb_s[c+2];
      float a3 = (v0[e].w - mu)*rstd*lnw_s[c+3] + lnb_s[c+3];
      pk[e*2+0] = cvtpk(a0, a1);
      pk[e*2+1] = cvtpk(a2, a3);
    }
    uint4* gd = (uint4*)(znS + (size_t)(row0 + r)*CH + q*32);
    uint4* ld = (uint4*)&zn[0][r][q*32];
    #pragma unroll
    for (int e=0;e<4;e++){
      uint4 w4 = make_uint4(pk[e*4], pk[e*4+1], pk[e*4+2], pk[e*4+3]);
      gd[e] = w4; ld[e] = w4;
    }
  }
  // ----- LN tile 1 -----
  {
    float s = 0.f, sq = 0.f;
    #pragma unroll
    for (int e=0;e<8;e++){
      s  += v1[e].x + v1[e].y + v1[e].z + v1[e].w;
      sq += v1[e].x*v1[e].x + v1[e].y*v1[e].y + v1[e].z*v1[e].z + v1[e].w*v1[e].w;
    }
    s += __shfl_xor(s,1); sq += __shfl_xor(sq,1);
    s += __shfl_xor(s,2); sq += __shfl_xor(sq,2);
    float mu = s * (1.f/128.f);
    float rstd = __builtin_amdgcn_rsqf(sq * (1.f/128.f) - mu*mu + 1e-5f);
    uint32_t pk[16];
    #pragma unroll
    for (int e=0;e<8;e++){
      int c = q*32 + e*4;
      float a0 = (v1[e].x - mu)*rstd*lnw_s[c+0] + lnb_s[c+0];
      float a1 = (v1[e].y - mu)*rstd*lnw_s[c+1] + lnb_s[c+1];
      float a2 = (v1[e].z - mu)*rstd*lnw_s[c+2] + lnb_s[c+2];
      float a3 = (v1[e].w - mu)*rstd*lnw_s[c+3] + lnb_s[c+3];
      pk[e*2+0] = cvtpk(a0, a1);
      pk[e*2+1] = cvtpk(a2, a3);
    }
    uint4* gd = (uint4*)(znS + (size_t)(row0 + 64 + r)*CH + q*32);
    uint4* ld = (uint4*)&zn[1][r][q*32];
    #pragma unroll
    for (int e=0;e<4;e++){
      uint4 w4 = make_uint4(pk[e*4], pk[e*4+1], pk[e*4+2], pk[e*4+3]);
      gd[e] = w4; ld[e] = w4;
    }
  }
  __syncthreads();   // zn ready

  const int lane = t & 63;
  const int w = t >> 6;
  const int lr = lane & 15;
  const int lg = lane >> 4;
  const int ow = w*32;
  const f32x4 zero4 = {0.f,0.f,0.f,0.f};

  #pragma unroll
  for (int tt=0; tt<2; tt++){
    const int r0t = row0 + tt*64;
    const size_t tile_off = (size_t)(r0t >> 9)*65536 + (size_t)((r0t >> 6) & 7)*8192;
    const float* msk = mask_s + tt*64;

    bf16x8 wl[8], wg[8];
    #pragma unroll
    for (int kk=0;kk<4;kk++)
      #pragma unroll
      for (int n=0;n<2;n++){
        int o = ow + n*16 + lr;
        wl[kk*2+n] = *(const bf16x8*)&wts[0*16384 + o*128 + kk*32 + lg*8];
        wg[kk*2+n] = *(const bf16x8*)&wts[1*16384 + o*128 + kk*32 + lg*8];
      }

    f32x4 acc1[4][2], acc2[4][2];
    #pragma unroll
    for (int mi=0;mi<4;mi++){ acc1[mi][0]=zero4; acc1[mi][1]=zero4; acc2[mi][0]=zero4; acc2[mi][1]=zero4; }
    #pragma unroll
    for (int kk=0;kk<4;kk++){
      bf16x8 a[4];
      #pragma unroll
      for (int mi=0;mi<4;mi++)
        a[mi] = *(const bf16x8*)&zn[tt][mi*16 + lr][kk*32 + lg*8];
      #pragma unroll
      for (int n=0;n<2;n++)
        #pragma unroll
        for (int mi=0;mi<4;mi++){
          acc1[mi][n] = __builtin_amdgcn_mfma_f32_16x16x32_bf16(a[mi], wl[kk*2+n], acc1[mi][n], 0,0,0);
          acc2[mi][n] = __builtin_amdgcn_mfma_f32_16x16x32_bf16(a[mi], wg[kk*2+n], acc2[mi][n], 0,0,0);
        }
    }
    bf16x8 wl2[8], wg2[8];
    #pragma unroll
    for (int kk=0;kk<4;kk++)
      #pragma unroll
      for (int n=0;n<2;n++){
        int o = ow + n*16 + lr;
        wl2[kk*2+n] = *(const bf16x8*)&wts[2*16384 + o*128 + kk*32 + lg*8];
        wg2[kk*2+n] = *(const bf16x8*)&wts[3*16384 + o*128 + kk*32 + lg*8];
      }

    #pragma unroll
    for (int n=0;n<2;n++){
      int ol = n*16 + lr;
      float bgv = b_lg[ow + ol];
      #pragma unroll
      for (int mi=0;mi<4;mi++){
        int r0 = mi*16 + lg*4;
        float u0 = acc1[mi][n][0] * sigm(acc2[mi][n][0] + bgv) * msk[r0+0];
        float u1 = acc1[mi][n][1] * sigm(acc2[mi][n][1] + bgv) * msk[r0+1];
        float u2 = acc1[mi][n][2] * sigm(acc2[mi][n][2] + bgv) * msk[r0+2];
        float u3 = acc1[mi][n][3] * sigm(acc2[mi][n][3] + bgv) * msk[r0+3];
        int chunk = (mi*2 + (lg>>1)) ^ (ol & 7);
        *(uint2*)&stg[w][ol*64 + (chunk<<3) + (lg&1)*4] = make_uint2(cvtpk(u0,u1), cvtpk(u2,u3));
      }
    }
    {
      int ol = lane >> 1, rh = lane & 1;
      uint4 pf[4];
      #pragma unroll
      for (int qq=0;qq<4;qq++){
        int m = (rh*4 + qq) ^ (ol & 7);
        pf[qq] = *(const uint4*)&stg[w][ol*64 + (m<<3)];
      }
      uint4* dst = (uint4*)(left_t + tile_off + (ow + ol)*64 + rh*32);
      #pragma unroll
      for (int qq=0;qq<4;qq++) dst[qq] = pf[qq];
    }

    #pragma unroll
    for (int mi=0;mi<4;mi++){ acc1[mi][0]=zero4; acc1[mi][1]=zero4; acc2[mi][0]=zero4; acc2[mi][1]=zero4; }
    #pragma unroll
    for (int kk=0;kk<4;kk++){
      bf16x8 a[4];
      #pragma unroll
      for (int mi=0;mi<4;mi++)
        a[mi] = *(const bf16x8*)&zn[tt][mi*16 + lr][kk*32 + lg*8];
      #pragma unroll
      for (int n=0;n<2;n++)
        #pragma unroll
        for (int mi=0;mi<4;mi++){
          acc1[mi][n] = __builtin_amdgcn_mfma_f32_16x16x32_bf16(a[mi], wl2[kk*2+n], acc1[mi][n], 0,0,0);
          acc2[mi][n] = __builtin_amdgcn_mfma_f32_16x16x32_bf16(a[mi], wg2[kk*2+n], acc2[mi][n], 0,0,0);
        }
    }
    #pragma unroll
    for (int n=0;n<2;n++){
      int ol = n*16 + lr;
      float bgv = b_rg[ow + ol];
      #pragma unroll
      for (int mi=0;mi<4;mi++){
        int r0 = mi*16 + lg*4;
        float u0 = acc1[mi][n][0] * sigm(acc2[mi][n][0] + bgv) * msk[r0+0];
        float u1 = acc1[mi][n][1] * sigm(acc2[mi][n][1] + bgv) * msk[r0+1];
        float u2 = acc1[mi][n][2] * sigm(acc2[mi][n][2] + bgv) * msk[r0+2];
        float u3 = acc1[mi][n][3] * sigm(acc2[mi][n][3] + bgv) * msk[r0+3];
        int chunk = (mi*2 + (lg>>1)) ^ (ol & 7);
        *(uint2*)&stg[w][ol*64 + (chunk<<3) + (lg&1)*4] = make_uint2(cvtpk(u0,u1), cvtpk(u2,u3));
      }
    }
    {
      int ol = lane >> 1, rh = lane & 1;
      uint4 pf[4];
      #pragma unroll
      for (int qq=0;qq<4;qq++){
        int m = (rh*4 + qq) ^ (ol & 7);
        pf[qq] = *(const uint4*)&stg[w][ol*64 + (m<<3)];
      }
      uint4* dst = (uint4*)(right_t + tile_off + (ow + ol)*64 + rh*32);
      #pragma unroll
      for (int qq=0;qq<4;qq++) dst[qq] = pf[qq];
    }
  }
}

// ------------- k2: per-channel 64x64x512 GEMM, bf16 output ----------------
__global__ __launch_bounds__(256) void k2_einsum(
    const u16* __restrict__ left_t, const u16* __restrict__ right_t,
    u16* __restrict__ upd16)
{
  __shared__ __align__(16) u16 lds_raw[16384];
  const int t = threadIdx.x;
  const int lane = t & 63, w = t >> 6;
  const int wi = w >> 1, wj = w & 1;
  const int lr = lane & 15, lg = lane >> 4;
  const int i0 = blockIdx.x * 64, j0 = blockIdx.y * 64;
  const int c  = blockIdx.z;

  const int srow = t >> 3;
  const int ssl  = t & 7;
  const size_t cofs = (size_t)c*64 + ssl*8;

  f32x4 acc[2][2];
  const f32x4 zero4 = {0.f,0.f,0.f,0.f};
  acc[0][0]=zero4; acc[0][1]=zero4; acc[1][0]=zero4; acc[1][1]=zero4;

  u16* ldsL = lds_raw;
  u16* ldsR = lds_raw + 8192;

  {
    #pragma unroll
    for (int q=0;q<2;q++){
      int row = q*32 + srow;
      int sw = ssl ^ (row & 7);
      uint4 vL = *(const uint4*)&left_t [(size_t)(i0+row)*65536 + cofs];
      uint4 vR = *(const uint4*)&right_t[(size_t)(j0+row)*65536 + cofs];
      *(uint4*)&ldsL[row*64 + sw*8] = vL;
      *(uint4*)&ldsR[row*64 + sw*8] = vR;
    }
  }
  __syncthreads();

  for (int kt=0; kt<8; kt++){
    const int buf = kt & 1;
    uint4 pL[2], pR[2];
    if (kt < 7){
      size_t ko = (size_t)(kt+1)*8192 + cofs;
      #pragma unroll
      for (int q=0;q<2;q++){
        int row = q*32 + srow;
        pL[q] = *(const uint4*)&left_t [(size_t)(i0+row)*65536 + ko];
        pR[q] = *(const uint4*)&right_t[(size_t)(j0+row)*65536 + ko];
      }
    }
    #pragma unroll
    for (int kk=0;kk<2;kk++){
      bf16x8 af[2], bfr[2];
      #pragma unroll
      for (int mi=0;mi<2;mi++){
        int row = wi*32 + mi*16 + lr;
        af[mi] = *(const bf16x8*)&ldsL[buf*4096 + row*64 + (((kk*4+lg) ^ (row&7)))*8];
      }
      #pragma unroll
      for (int nj=0;nj<2;nj++){
        int row = wj*32 + nj*16 + lr;
        bfr[nj] = *(const bf16x8*)&ldsR[buf*4096 + row*64 + (((kk*4+lg) ^ (row&7)))*8];
      }
      #pragma unroll
      for (int mi=0;mi<2;mi++)
        #pragma unroll
        for (int nj=0;nj<2;nj++)
          acc[mi][nj] = __builtin_amdgcn_mfma_f32_16x16x32_bf16(af[mi], bfr[nj], acc[mi][nj], 0,0,0);
    }
    if (kt < 7){
      #pragma unroll
      for (int q=0;q<2;q++){
        int row = q*32 + srow;
        int sw = ssl ^ (row & 7);
        *(uint4*)&ldsL[(buf^1)*4096 + row*64 + sw*8] = pL[q];
        *(uint4*)&ldsR[(buf^1)*4096 + row*64 + sw*8] = pR[q];
      }
    }
    __syncthreads();
  }

  const float scale = 0.044194173824159216f;   // 1/sqrt(512)
  u16* st = lds_raw;
  #pragma unroll
  for (int mi=0;mi<2;mi++){
    #pragma unroll
    for (int nj=0;nj<2;nj++){
      int cj = wj*32 + nj*16 + lr;
      #pragma unroll
      for (int g2=0;g2<4;g2++){
        int ri = wi*32 + mi*16 + lg*4 + g2;
        st[ri*72 + cj] = f2bf(acc[mi][nj][g2] * scale);
      }
    }
  }
  __syncthreads();
  {
    int ri = t >> 2, q = t & 3;
    const uint4* src = (const uint4*)&st[ri*72 + q*16];
    uint4* dst = (uint4*)(upd16 + (size_t)c*NN + (size_t)(i0+ri)*NSEQ + j0 + q*16);
    dst[0] = src[0];
    dst[1] = src[1];
  }
}

// ------------- k3a: LN over c of upd16 [c][i*512+j] -> znu [row][c] bf16 --
__global__ __launch_bounds__(256) void k3a_ln(
    const u16* __restrict__ upd16, const float* __restrict__ onw,
    const float* __restrict__ onb, u16* __restrict__ znu)
{
  __shared__ float u[128*129];
  __shared__ float onw_s[128], onb_s[128];
  const int t = threadIdx.x;
  const int i = blockIdx.x;
  const int j0 = blockIdx.y * 128;

  if (t < 32)      ((float4*)onw_s)[t]    = ((const float4*)onw)[t];
  else if (t < 64) ((float4*)onb_s)[t-32] = ((const float4*)onb)[t-32];

  {
    int cr = t >> 1, h = t & 1;
    const uint4* src = (const uint4*)(upd16 + (size_t)cr*NN + (size_t)i*NSEQ + j0 + h*64);
    float* dst = &u[cr*129 + h*64];
    #pragma unroll
    for (int e=0;e<8;e++){
      uint4 v = src[e];
      const u16* hp = (const u16*)&v;
      #pragma unroll
      for (int p=0;p<8;p++) dst[e*8+p] = bf2f(hp[p]);
    }
  }
  __syncthreads();

  int j = t >> 1, h = t & 1;
  float s = 0.f, sq = 0.f;
  #pragma unroll
  for (int e=0;e<64;e++){
    float v = u[(h*64+e)*129 + j];
    s += v; sq += v*v;
  }
  s += __shfl_xor(s,1); sq += __shfl_xor(sq,1);
  float mu = s * (1.f/128.f);
  float rstd = __builtin_amdgcn_rsqf(sq * (1.f/128.f) - mu*mu + 1e-5f);

  uint32_t pk[32];
  #pragma unroll
  for (int e=0;e<64;e+=2){
    int c0 = h*64 + e;
    float v0 = (u[c0*129 + j]     - mu)*rstd*onw_s[c0]   + onb_s[c0];
    float v1 = (u[(c0+1)*129 + j] - mu)*rstd*onw_s[c0+1] + onb_s[c0+1];
    pk[e>>1] = cvtpk(v0, v1);
  }
  uint4* dst = (uint4*)(znu + ((size_t)i*NSEQ + j0 + j)*CH + h*64);
  #pragma unroll
  for (int e=0;e<8;e++) dst[e] = make_uint4(pk[e*4], pk[e*4+1], pk[e*4+2], pk[e*4+3]);
}

// ------------- k3b: out = (LN'd-update @ W_out^T) * sigm(zn@W_og^T+b) * mask
__global__ __launch_bounds__(256) void k3b_out(
    const u16* __restrict__ znu, const u16* __restrict__ znS,
    const float* __restrict__ pmask, const float* __restrict__ b_og,
    const u16* __restrict__ wts, float* __restrict__ out)
{
  __shared__ __align__(16) u16 uL[64][136];
  __shared__ __align__(16) u16 zL[64][136];
  __shared__ float mask_s[64];
  const int t = threadIdx.x;
  const int row0 = blockIdx.x * 64;

  #pragma unroll
  for (int k=0;k<4;k++){
    uint4 vu = *(const uint4*)(znu + (size_t)row0*CH + k*2048 + t*8);
    uint4 vz = *(const uint4*)(znS + (size_t)row0*CH + k*2048 + t*8);
    int r = k*16 + (t>>4), g = t & 15;
    *(uint4*)&uL[r][g*8] = vu;
    *(uint4*)&zL[r][g*8] = vz;
  }
  if (t < 16) ((float4*)mask_s)[t] = ((const float4*)(pmask + row0))[t];
  __syncthreads();

  const int lane = t & 63, w = t >> 6;
  const int lr = lane & 15, lg = lane >> 4;

  f32x4 acc_o[4][2], acc_g[4][2];
  const f32x4 zero4 = {0.f,0.f,0.f,0.f};
  #pragma unroll
  for (int mi=0;mi<4;mi++){ acc_o[mi][0]=zero4; acc_o[mi][1]=zero4; acc_g[mi][0]=zero4; acc_g[mi][1]=zero4; }

  #pragma unroll
  for (int kk=0;kk<4;kk++){
    bf16x8 a[4];
    #pragma unroll
    for (int mi=0;mi<4;mi++)
      a[mi] = *(const bf16x8*)&uL[mi*16 + lr][kk*32 + lg*8];
    #pragma unroll
    for (int n=0;n<2;n++){
      int o = w*32 + n*16 + lr;
      bf16x8 b = *(const bf16x8*)&wts[5*16384 + o*128 + kk*32 + lg*8];
      #pragma unroll
      for (int mi=0;mi<4;mi++)
        acc_o[mi][n] = __builtin_amdgcn_mfma_f32_16x16x32_bf16(a[mi], b, acc_o[mi][n], 0,0,0);
    }
  }
  #pragma unroll
  for (int kk=0;kk<4;kk++){
    bf16x8 a[4];
    #pragma unroll
    for (int mi=0;mi<4;mi++)
      a[mi] = *(const bf16x8*)&zL[mi*16 + lr][kk*32 + lg*8];
    #pragma unroll
    for (int n=0;n<2;n++){
      int o = w*32 + n*16 + lr;
      bf16x8 b = *(const bf16x8*)&wts[4*16384 + o*128 + kk*32 + lg*8];
      #pragma unroll
      for (int mi=0;mi<4;mi++)
        acc_g[mi][n] = __builtin_amdgcn_mfma_f32_16x16x32_bf16(a[mi], b, acc_g[mi][n], 0,0,0);
    }
  }

  #pragma unroll
  for (int n=0;n<2;n++){
    int o = w*32 + n*16 + lr;
    float bgv = b_og[o];
    #pragma unroll
    for (int mi=0;mi<4;mi++){
      #pragma unroll
      for (int g2=0;g2<4;g2++){
        int r = mi*16 + lg*4 + g2;
        float val = acc_o[mi][n][g2] * sigm(acc_g[mi][n][g2] + bgv) * mask_s[r];
        out[(size_t)(row0 + r)*CH + o] = val;
      }
    }
  }
}

// ------------- k3bf: FUSED LN(update) + dual GEMM + gate + store ----------
__global__ __launch_bounds__(256) void k3bf_out(
    const u16* __restrict__ upd16, const u16* __restrict__ znS,
    const float* __restrict__ pmask, const float* __restrict__ onw,
    const float* __restrict__ onb, const float* __restrict__ b_og,
    const u16* __restrict__ wts, float* __restrict__ out)
{
  __shared__ __align__(16) u16 zn[64][136];   // LN'd update (GEMM1 A operand)
  __shared__ __align__(16) u16 zL[64][136];   // znS tile   (GEMM2 A operand)
  __shared__ float ps[4][64], pq[4][64];
  __shared__ float st2[64][2];
  __shared__ float onw_s[128], onb_s[128], mask_s[64];

  const int t = threadIdx.x;
  const int row0 = blockIdx.x * 64;
  const int j  = t & 63;
  const int h2 = t >> 6;

  uint4 vz[4];
  #pragma unroll
  for (int k=0;k<4;k++) vz[k] = *(const uint4*)(znS + (size_t)row0*CH + k*2048 + t*8);

  float v[32];
  #pragma unroll
  for (int e=0;e<32;e++){
    int c = h2*32 + e;
    v[e] = bf2f(upd16[(size_t)c*NN + row0 + j]);
  }

  if (t < 32)      ((float4*)onw_s)[t]     = ((const float4*)onw)[t];
  else if (t < 64) ((float4*)onb_s)[t-32]  = ((const float4*)onb)[t-32];
  else if (t < 80) ((float4*)mask_s)[t-64] = ((const float4*)(pmask + row0))[t-64];

  #pragma unroll
  for (int k=0;k<4;k++){
    int r = k*16 + (t>>4), g = t & 15;
    *(uint4*)&zL[r][g*8] = vz[k];
  }

  {
    float s = 0.f, sq = 0.f;
    #pragma unroll
    for (int e=0;e<32;e++){ s += v[e]; sq += v[e]*v[e]; }
    ps[h2][j] = s; pq[h2][j] = sq;
  }
  __syncthreads();
  if (t < 64){
    float s  = ps[0][t]+ps[1][t]+ps[2][t]+ps[3][t];
    float sq = pq[0][t]+pq[1][t]+pq[2][t]+pq[3][t];
    float mu = s * (1.f/128.f);
    float rstd = __builtin_amdgcn_rsqf(sq * (1.f/128.f) - mu*mu + 1e-5f);
    st2[t][0] = mu; st2[t][1] = rstd;
  }
  __syncthreads();

  {
    float mu = st2[j][0], rstd = st2[j][1];
    #pragma unroll
    for (int q=0;q<4;q++){
      uint32_t pk[4];
      #pragma unroll
      for (int p=0;p<4;p++){
        int e = q*8 + p*2;
        int c = h2*32 + e;
        float y0 = (v[e]   - mu)*rstd*onw_s[c]   + onb_s[c];
        float y1 = (v[e+1] - mu)*rstd*onw_s[c+1] + onb_s[c+1];
        pk[p] = cvtpk(y0, y1);
      }
      *(uint4*)&zn[j][h2*32 + q*8] = make_uint4(pk[0],pk[1],pk[2],pk[3]);
    }
  }
  __syncthreads();

  const int lane = t & 63, w = t >> 6;
  const int lr = lane & 15, lg = lane >> 4;

  f32x4 acc_o[4][2], acc_g[4][2];
  const f32x4 zero4 = {0.f,0.f,0.f,0.f};
  #pragma unroll
  for (int mi=0;mi<4;mi++){ acc_o[mi][0]=zero4; acc_o[mi][1]=zero4; acc_g[mi][0]=zero4; acc_g[mi][1]=zero4; }

  #pragma unroll
  for (int kk=0;kk<4;kk++){
    bf16x8 a[4];
    #pragma unroll
    for (int mi=0;mi<4;mi++)
      a[mi] = *(const bf16x8*)&zn[mi*16 + lr][kk*32 + lg*8];
    #pragma unroll
    for (int n=0;n<2;n++){
      int o = w*32 + n*16 + lr;
      bf16x8 b = *(const bf16x8*)&wts[5*16384 + o*128 + kk*32 + lg*8];
      #pragma unroll
      for (int mi=0;mi<4;mi++)
        acc_o[mi][n] = __builtin_amdgcn_mfma_f32_16x16x32_bf16(a[mi], b, acc_o[mi][n], 0,0,0);
    }
  }
  #pragma unroll
  for (int kk=0;kk<4;kk++){
    bf16x8 a[4];
    #pragma unroll
    for (int mi=0;mi<4;mi++)
      a[mi] = *(const bf16x8*)&zL[mi*16 + lr][kk*32 + lg*8];
    #pragma unroll
    for (int n=0;n<2;n++){
      int o = w*32 + n*16 + lr;
      bf16x8 b = *(const bf16x8*)&wts[4*16384 + o*128 + kk*32 + lg*8];
      #pragma unroll
      for (int mi=0;mi<4;mi++)
        acc_g[mi][n] = __builtin_amdgcn_mfma_f32_16x16x32_bf16(a[mi], b, acc_g[mi][n], 0,0,0);
    }
  }

  #pragma unroll
  for (int n=0;n<2;n++){
    int o = w*32 + n*16 + lr;
    float bgv = b_og[o];
    #pragma unroll
    for (int mi=0;mi<4;mi++){
      #pragma unroll
      for (int g2=0;g2<4;g2++){
        int r = mi*16 + lg*4 + g2;
        float val = acc_o[mi][n][g2] * sigm(acc_g[mi][n][g2] + bgv) * mask_s[r];
        out[(size_t)(row0 + r)*CH + o] = val;
      }
    }
  }
}

// --------------------------- launcher ------------------------------------
extern "C" void kernel_launch(void* const* d_in, const int* in_sizes, int n_in,
                              void* d_out, int out_size, void* d_ws, size_t ws_size,
                              hipStream_t stream)
{
  const float* z       = (const float*)d_in[0];
  const float* pmask   = (const float*)d_in[1];
  const float* lnw     = (const float*)d_in[2];
  const float* lnb     = (const float*)d_in[3];
  const float* W_left  = (const float*)d_in[4];
  const float* W_right = (const float*)d_in[5];
  const float* W_lgate = (const float*)d_in[6];
  const float* b_lgate = (const float*)d_in[7];
  const float* W_rgate = (const float*)d_in[8];
  const float* b_rgate = (const float*)d_in[9];
  const float* onw     = (const float*)d_in[10];
  const float* onb     = (const float*)d_in[11];
  const float* W_out   = (const float*)d_in[12];
  const float* W_ogate = (const float*)d_in[13];
  const float* b_ogate = (const float*)d_in[14];

  const size_t SLOT = 67108864;   // 64 MiB
  uint8_t* ws = (uint8_t*)d_ws;
  u16* left_t  = (u16*)(ws);
  u16* right_t = (u16*)(ws + SLOT);
  u16* znS     = (u16*)(ws + 2*SLOT);

  const bool fused = (ws_size >= 4*SLOT + 196608);
  u16* wts   = (u16*)(ws + (fused ? 4*SLOT : 3*SLOT));
  u16* upd16 = fused ? (u16*)(ws + 3*SLOT) : (u16*)d_out;

  k0_cvt<<<96, 256, 0, stream>>>(W_left, W_lgate, W_right, W_rgate, W_ogate, W_out, wts);
  k1ab_proj<<<2048, 256, 0, stream>>>(z, pmask, lnw, lnb, b_lgate, b_rgate, wts,
                                      znS, left_t, right_t);
  k2_einsum<<<dim3(8,8,128), 256, 0, stream>>>(left_t, right_t, upd16);

  if (fused){
    k3bf_out<<<4096, 256, 0, stream>>>(upd16, znS, pmask, onw, onb, b_ogate, wts,
                                       (float*)d_out);
  } else {
    k3a_ln<<<dim3(512,4), 256, 0, stream>>>(upd16, onw, onb, left_t /*znu*/);
    k3b_out<<<4096, 256, 0, stream>>>(left_t /*znu*/, znS, pmask, b_ogate, wts,
                                      (float*)d_out);
  }
}

// Round 10
// 316.243 us; speedup vs baseline: 1.3258x; 1.0008x over previous
//
#include <hip/hip_runtime.h>
#include <stdint.h>

#define NSEQ 512
#define CH   128
#define NN   (NSEQ*NSEQ)   // 262144

typedef unsigned short u16;
typedef __attribute__((ext_vector_type(8))) short bf16x8;  // 8 bf16 = 4 VGPRs
typedef __attribute__((ext_vector_type(4))) float f32x4;

__device__ __forceinline__ u16 f2bf(float x){          // RNE
  uint32_t u = __float_as_uint(x);
  u += 0x7fffu + ((u >> 16) & 1u);
  return (u16)(u >> 16);
}
__device__ __forceinline__ float bf2f(u16 h){
  return __uint_as_float(((uint32_t)h) << 16);
}
__device__ __forceinline__ uint32_t cvtpk(float lo, float hi){  // bf16(lo)|bf16(hi)<<16
  uint32_t r;
  asm volatile("v_cvt_pk_bf16_f32 %0, %1, %2" : "=v"(r) : "v"(lo), "v"(hi));
  return r;
}
__device__ __forceinline__ float sigm(float x){
  return __builtin_amdgcn_rcpf(1.0f + __expf(-x));
}
__device__ __forceinline__ void gll16(const void* g, void* l){  // 16B global->LDS DMA
  __builtin_amdgcn_global_load_lds((const __attribute__((address_space(1))) void*)g,
                                   (__attribute__((address_space(3))) void*)l, 16, 0, 0);
}

// left/right tensor layout: [i (512)][kblk (8)][c (128)][kin (64)] u16
// offset = i*65536 + kblk*8192 + c*64 + kin   (flat row n = i*512 + kblk*64 + kin)

// ------------- k0: cast 6 weight matrices fp32 -> bf16 -------------
// slot order: 0=W_left 1=W_lgate 2=W_right 3=W_rgate 4=W_ogate 5=W_out
__global__ void k0_cvt(const float* __restrict__ w0, const float* __restrict__ w1,
                       const float* __restrict__ w2, const float* __restrict__ w3,
                       const float* __restrict__ w4, const float* __restrict__ w5,
                       u16* __restrict__ out)
{
  int mat = blockIdx.x >> 4;
  int blk = blockIdx.x & 15;
  const float* src = (mat==0)?w0:(mat==1)?w1:(mat==2)?w2:(mat==3)?w3:(mat==4)?w4:w5;
  int idx = (blk*256 + (int)threadIdx.x) * 4;
  float4 v = *(const float4*)(src + idx);
  uint2 pk;
  pk.x = cvtpk(v.x, v.y);
  pk.y = cvtpk(v.z, v.w);
  *(uint2*)(out + mat*16384 + idx) = pk;
}

// ------------- k1ab: FUSED LN(z) + 2 gated projections, 128 rows/block ----
__global__ __launch_bounds__(256) void k1ab_proj(
    const float* __restrict__ z, const float* __restrict__ pmask,
    const float* __restrict__ lnw, const float* __restrict__ lnb,
    const float* __restrict__ b_lg, const float* __restrict__ b_rg,
    const u16* __restrict__ wts, u16* __restrict__ znS,
    u16* __restrict__ left_t, u16* __restrict__ right_t)
{
  __shared__ __align__(16) u16 zn[2][64][136];  // 34 KB
  __shared__ __align__(16) u16 stg[4][2048];    // 16 KB (per-wave stage)
  __shared__ float lnw_s[128], lnb_s[128], mask_s[128];
  const int t = threadIdx.x;
  const int row0 = blockIdx.x * 128;

  if (t < 32)      ((float4*)lnw_s)[t]     = ((const float4*)lnw)[t];
  else if (t < 64) ((float4*)lnb_s)[t-32]  = ((const float4*)lnb)[t-32];
  else if (t < 96) ((float4*)mask_s)[t-64] = ((const float4*)(pmask + row0))[t-64];

  const int r = t >> 2, q = t & 3;
  float4 v0[8], v1[8];
  {
    const float* zp0 = z + (size_t)(row0 + r) * CH + q * 32;
    const float* zp1 = z + (size_t)(row0 + 64 + r) * CH + q * 32;
    #pragma unroll
    for (int e=0;e<8;e++) v0[e] = ((const float4*)zp0)[e];
    #pragma unroll
    for (int e=0;e<8;e++) v1[e] = ((const float4*)zp1)[e];
  }
  __syncthreads();

  // ----- LN tile 0 -----
  {
    float s = 0.f, sq = 0.f;
    #pragma unroll
    for (int e=0;e<8;e++){
      s  += v0[e].x + v0[e].y + v0[e].z + v0[e].w;
      sq += v0[e].x*v0[e].x + v0[e].y*v0[e].y + v0[e].z*v0[e].z + v0[e].w*v0[e].w;
    }
    s += __shfl_xor(s,1); sq += __shfl_xor(sq,1);
    s += __shfl_xor(s,2); sq += __shfl_xor(sq,2);
    float mu = s * (1.f/128.f);
    float rstd = __builtin_amdgcn_rsqf(sq * (1.f/128.f) - mu*mu + 1e-5f);
    uint32_t pk[16];
    #pragma unroll
    for (int e=0;e<8;e++){
      int c = q*32 + e*4;
      float a0 = (v0[e].x - mu)*rstd*lnw_s[c+0] + lnb_s[c+0];
      float a1 = (v0[e].y - mu)*rstd*lnw_s[c+1] + lnb_s[c+1];
      float a2 = (v0[e].z - mu)*rstd*lnw_s[c+2] + lnb_s[c+2];
      float a3 = (v0[e].w - mu)*rstd*lnw_s[c+3] + lnb_s[c+3];
      pk[e*2+0] = cvtpk(a0, a1);
      pk[e*2+1] = cvtpk(a2, a3);
    }
    uint4* gd = (uint4*)(znS + (size_t)(row0 + r)*CH + q*32);
    uint4* ld = (uint4*)&zn[0][r][q*32];
    #pragma unroll
    for (int e=0;e<4;e++){
      uint4 w4 = make_uint4(pk[e*4], pk[e*4+1], pk[e*4+2], pk[e*4+3]);
      gd[e] = w4; ld[e] = w4;
    }
  }
  // ----- LN tile 1 -----
  {
    float s = 0.f, sq = 0.f;
    #pragma unroll
    for (int e=0;e<8;e++){
      s  += v1[e].x + v1[e].y + v1[e].z + v1[e].w;
      sq += v1[e].x*v1[e].x + v1[e].y*v1[e].y + v1[e].z*v1[e].z + v1[e].w*v1[e].w;
    }
    s += __shfl_xor(s,1); sq += __shfl_xor(sq,1);
    s += __shfl_xor(s,2); sq += __shfl_xor(sq,2);
    float mu = s * (1.f/128.f);
    float rstd = __builtin_amdgcn_rsqf(sq * (1.f/128.f) - mu*mu + 1e-5f);
    uint32_t pk[16];
    #pragma unroll
    for (int e=0;e<8;e++){
      int c = q*32 + e*4;
      float a0 = (v1[e].x - mu)*rstd*lnw_s[c+0] + lnb_s[c+0];
      float a1 = (v1[e].y - mu)*rstd*lnw_s[c+1] + lnb_s[c+1];
      float a2 = (v1[e].z - mu)*rstd*lnw_s[c+2] + lnb_s[c+2];
      float a3 = (v1[e].w - mu)*rstd*lnw_s[c+3] + lnb_s[c+3];
      pk[e*2+0] = cvtpk(a0, a1);
      pk[e*2+1] = cvtpk(a2, a3);
    }
    uint4* gd = (uint4*)(znS + (size_t)(row0 + 64 + r)*CH + q*32);
    uint4* ld = (uint4*)&zn[1][r][q*32];
    #pragma unroll
    for (int e=0;e<4;e++){
      uint4 w4 = make_uint4(pk[e*4], pk[e*4+1], pk[e*4+2], pk[e*4+3]);
      gd[e] = w4; ld[e] = w4;
    }
  }
  __syncthreads();

  const int lane = t & 63;
  const int w = t >> 6;
  const int lr = lane & 15;
  const int lg = lane >> 4;
  const int ow = w*32;
  const f32x4 zero4 = {0.f,0.f,0.f,0.f};

  #pragma unroll
  for (int tt=0; tt<2; tt++){
    const int r0t = row0 + tt*64;
    const size_t tile_off = (size_t)(r0t >> 9)*65536 + (size_t)((r0t >> 6) & 7)*8192;
    const float* msk = mask_s + tt*64;

    bf16x8 wl[8], wg[8];
    #pragma unroll
    for (int kk=0;kk<4;kk++)
      #pragma unroll
      for (int n=0;n<2;n++){
        int o = ow + n*16 + lr;
        wl[kk*2+n] = *(const bf16x8*)&wts[0*16384 + o*128 + kk*32 + lg*8];
        wg[kk*2+n] = *(const bf16x8*)&wts[1*16384 + o*128 + kk*32 + lg*8];
      }

    f32x4 acc1[4][2], acc2[4][2];
    #pragma unroll
    for (int mi=0;mi<4;mi++){ acc1[mi][0]=zero4; acc1[mi][1]=zero4; acc2[mi][0]=zero4; acc2[mi][1]=zero4; }
    #pragma unroll
    for (int kk=0;kk<4;kk++){
      bf16x8 a[4];
      #pragma unroll
      for (int mi=0;mi<4;mi++)
        a[mi] = *(const bf16x8*)&zn[tt][mi*16 + lr][kk*32 + lg*8];
      #pragma unroll
      for (int n=0;n<2;n++)
        #pragma unroll
        for (int mi=0;mi<4;mi++){
          acc1[mi][n] = __builtin_amdgcn_mfma_f32_16x16x32_bf16(a[mi], wl[kk*2+n], acc1[mi][n], 0,0,0);
          acc2[mi][n] = __builtin_amdgcn_mfma_f32_16x16x32_bf16(a[mi], wg[kk*2+n], acc2[mi][n], 0,0,0);
        }
    }
    bf16x8 wl2[8], wg2[8];
    #pragma unroll
    for (int kk=0;kk<4;kk++)
      #pragma unroll
      for (int n=0;n<2;n++){
        int o = ow + n*16 + lr;
        wl2[kk*2+n] = *(const bf16x8*)&wts[2*16384 + o*128 + kk*32 + lg*8];
        wg2[kk*2+n] = *(const bf16x8*)&wts[3*16384 + o*128 + kk*32 + lg*8];
      }

    #pragma unroll
    for (int n=0;n<2;n++){
      int ol = n*16 + lr;
      float bgv = b_lg[ow + ol];
      #pragma unroll
      for (int mi=0;mi<4;mi++){
        int r0 = mi*16 + lg*4;
        float u0 = acc1[mi][n][0] * sigm(acc2[mi][n][0] + bgv) * msk[r0+0];
        float u1 = acc1[mi][n][1] * sigm(acc2[mi][n][1] + bgv) * msk[r0+1];
        float u2 = acc1[mi][n][2] * sigm(acc2[mi][n][2] + bgv) * msk[r0+2];
        float u3 = acc1[mi][n][3] * sigm(acc2[mi][n][3] + bgv) * msk[r0+3];
        int chunk = (mi*2 + (lg>>1)) ^ (ol & 7);
        *(uint2*)&stg[w][ol*64 + (chunk<<3) + (lg&1)*4] = make_uint2(cvtpk(u0,u1), cvtpk(u2,u3));
      }
    }
    {
      int ol = lane >> 1, rh = lane & 1;
      uint4 pf[4];
      #pragma unroll
      for (int qq=0;qq<4;qq++){
        int m = (rh*4 + qq) ^ (ol & 7);
        pf[qq] = *(const uint4*)&stg[w][ol*64 + (m<<3)];
      }
      uint4* dst = (uint4*)(left_t + tile_off + (ow + ol)*64 + rh*32);
      #pragma unroll
      for (int qq=0;qq<4;qq++) dst[qq] = pf[qq];
    }

    #pragma unroll
    for (int mi=0;mi<4;mi++){ acc1[mi][0]=zero4; acc1[mi][1]=zero4; acc2[mi][0]=zero4; acc2[mi][1]=zero4; }
    #pragma unroll
    for (int kk=0;kk<4;kk++){
      bf16x8 a[4];
      #pragma unroll
      for (int mi=0;mi<4;mi++)
        a[mi] = *(const bf16x8*)&zn[tt][mi*16 + lr][kk*32 + lg*8];
      #pragma unroll
      for (int n=0;n<2;n++)
        #pragma unroll
        for (int mi=0;mi<4;mi++){
          acc1[mi][n] = __builtin_amdgcn_mfma_f32_16x16x32_bf16(a[mi], wl2[kk*2+n], acc1[mi][n], 0,0,0);
          acc2[mi][n] = __builtin_amdgcn_mfma_f32_16x16x32_bf16(a[mi], wg2[kk*2+n], acc2[mi][n], 0,0,0);
        }
    }
    #pragma unroll
    for (int n=0;n<2;n++){
      int ol = n*16 + lr;
      float bgv = b_rg[ow + ol];
      #pragma unroll
      for (int mi=0;mi<4;mi++){
        int r0 = mi*16 + lg*4;
        float u0 = acc1[mi][n][0] * sigm(acc2[mi][n][0] + bgv) * msk[r0+0];
        float u1 = acc1[mi][n][1] * sigm(acc2[mi][n][1] + bgv) * msk[r0+1];
        float u2 = acc1[mi][n][2] * sigm(acc2[mi][n][2] + bgv) * msk[r0+2];
        float u3 = acc1[mi][n][3] * sigm(acc2[mi][n][3] + bgv) * msk[r0+3];
        int chunk = (mi*2 + (lg>>1)) ^ (ol & 7);
        *(uint2*)&stg[w][ol*64 + (chunk<<3) + (lg&1)*4] = make_uint2(cvtpk(u0,u1), cvtpk(u2,u3));
      }
    }
    {
      int ol = lane >> 1, rh = lane & 1;
      uint4 pf[4];
      #pragma unroll
      for (int qq=0;qq<4;qq++){
        int m = (rh*4 + qq) ^ (ol & 7);
        pf[qq] = *(const uint4*)&stg[w][ol*64 + (m<<3)];
      }
      uint4* dst = (uint4*)(right_t + tile_off + (ow + ol)*64 + rh*32);
      #pragma unroll
      for (int qq=0;qq<4;qq++) dst[qq] = pf[qq];
    }
  }
}

// ------------- k2: per-channel 64x64x512 GEMM, global_load_lds staging ----
// LDS dest is LINEAR (base + lane*16B); the XOR swizzle is applied to the
// GLOBAL source slot (gslot = ssl ^ (row&7)), so LDS slot s holds k-chunk
// s^(row&7) — identical contents to the proven reg-staged version; MFMA-side
// reads unchanged. (rule #21: linear dest + inverse-swz source + swz read)
__global__ __launch_bounds__(256) void k2_einsum(
    const u16* __restrict__ left_t, const u16* __restrict__ right_t,
    u16* __restrict__ upd16)
{
  __shared__ __align__(16) u16 lds_raw[16384];  // L bufs @0,4096 | R bufs @8192,12288
  const int t = threadIdx.x;
  const int lane = t & 63, w = t >> 6;
  const int wi = w >> 1, wj = w & 1;
  const int lr = lane & 15, lg = lane >> 4;
  const int i0 = blockIdx.x * 64, j0 = blockIdx.y * 64;
  const int c  = blockIdx.z;

  const int srow = t >> 3;   // 0..31
  const int ssl  = t & 7;

  f32x4 acc[2][2];
  const f32x4 zero4 = {0.f,0.f,0.f,0.f};
  acc[0][0]=zero4; acc[0][1]=zero4; acc[1][0]=zero4; acc[1][1]=zero4;

  // stage k-tile kt into buffer buf via 16B global->LDS DMA (4 per thread)
  auto stage = [&](int buf, int kt){
    #pragma unroll
    for (int q=0;q<2;q++){
      int row = q*32 + srow;
      int gs  = ssl ^ (row & 7);
      size_t gofs = (size_t)kt*8192 + (size_t)c*64 + gs*8;
      const u16* gl = &left_t [(size_t)(i0+row)*65536 + gofs];
      const u16* gr = &right_t[(size_t)(j0+row)*65536 + gofs];
      u16* dl = lds_raw +        buf*4096 + q*2048 + w*512 + lane*8;  // linear in lane
      u16* dr = lds_raw + 8192 + buf*4096 + q*2048 + w*512 + lane*8;
      gll16(gl, dl);
      gll16(gr, dr);
    }
  };

  stage(0, 0);
  __syncthreads();   // vmcnt(0) drain before barrier -> tile 0 landed

  for (int kt=0; kt<8; kt++){
    const int buf = kt & 1;
    if (kt < 7) stage(buf^1, kt+1);   // DMA in flight across the MFMA phase
    #pragma unroll
    for (int kk=0;kk<2;kk++){
      bf16x8 af[2], bfr[2];
      #pragma unroll
      for (int mi=0;mi<2;mi++){
        int row = wi*32 + mi*16 + lr;
        af[mi] = *(const bf16x8*)&lds_raw[buf*4096 + row*64 + (((kk*4+lg) ^ (row&7)))*8];
      }
      #pragma unroll
      for (int nj=0;nj<2;nj++){
        int row = wj*32 + nj*16 + lr;
        bfr[nj] = *(const bf16x8*)&lds_raw[8192 + buf*4096 + row*64 + (((kk*4+lg) ^ (row&7)))*8];
      }
      #pragma unroll
      for (int mi=0;mi<2;mi++)
        #pragma unroll
        for (int nj=0;nj<2;nj++)
          acc[mi][nj] = __builtin_amdgcn_mfma_f32_16x16x32_bf16(af[mi], bfr[nj], acc[mi][nj], 0,0,0);
    }
    __syncthreads();   // drains the prefetch DMA -> buf^1 ready
  }

  const float scale = 0.044194173824159216f;   // 1/sqrt(512)
  u16* st = lds_raw;
  #pragma unroll
  for (int mi=0;mi<2;mi++){
    #pragma unroll
    for (int nj=0;nj<2;nj++){
      int cj = wj*32 + nj*16 + lr;
      #pragma unroll
      for (int g2=0;g2<4;g2++){
        int ri = wi*32 + mi*16 + lg*4 + g2;
        st[ri*72 + cj] = f2bf(acc[mi][nj][g2] * scale);
      }
    }
  }
  __syncthreads();
  {
    int ri = t >> 2, q = t & 3;
    const uint4* src = (const uint4*)&st[ri*72 + q*16];
    uint4* dst = (uint4*)(upd16 + (size_t)c*NN + (size_t)(i0+ri)*NSEQ + j0 + q*16);
    dst[0] = src[0];
    dst[1] = src[1];
  }
}

// ------------- k3a: LN over c of upd16 [c][i*512+j] -> znu [row][c] bf16 --
__global__ __launch_bounds__(256) void k3a_ln(
    const u16* __restrict__ upd16, const float* __restrict__ onw,
    const float* __restrict__ onb, u16* __restrict__ znu)
{
  __shared__ float u[128*129];
  __shared__ float onw_s[128], onb_s[128];
  const int t = threadIdx.x;
  const int i = blockIdx.x;
  const int j0 = blockIdx.y * 128;

  if (t < 32)      ((float4*)onw_s)[t]    = ((const float4*)onw)[t];
  else if (t < 64) ((float4*)onb_s)[t-32] = ((const float4*)onb)[t-32];

  {
    int cr = t >> 1, h = t & 1;
    const uint4* src = (const uint4*)(upd16 + (size_t)cr*NN + (size_t)i*NSEQ + j0 + h*64);
    float* dst = &u[cr*129 + h*64];
    #pragma unroll
    for (int e=0;e<8;e++){
      uint4 v = src[e];
      const u16* hp = (const u16*)&v;
      #pragma unroll
      for (int p=0;p<8;p++) dst[e*8+p] = bf2f(hp[p]);
    }
  }
  __syncthreads();

  int j = t >> 1, h = t & 1;
  float s = 0.f, sq = 0.f;
  #pragma unroll
  for (int e=0;e<64;e++){
    float v = u[(h*64+e)*129 + j];
    s += v; sq += v*v;
  }
  s += __shfl_xor(s,1); sq += __shfl_xor(sq,1);
  float mu = s * (1.f/128.f);
  float rstd = __builtin_amdgcn_rsqf(sq * (1.f/128.f) - mu*mu + 1e-5f);

  uint32_t pk[32];
  #pragma unroll
  for (int e=0;e<64;e+=2){
    int c0 = h*64 + e;
    float v0 = (u[c0*129 + j]     - mu)*rstd*onw_s[c0]   + onb_s[c0];
    float v1 = (u[(c0+1)*129 + j] - mu)*rstd*onw_s[c0+1] + onb_s[c0+1];
    pk[e>>1] = cvtpk(v0, v1);
  }
  uint4* dst = (uint4*)(znu + ((size_t)i*NSEQ + j0 + j)*CH + h*64);
  #pragma unroll
  for (int e=0;e<8;e++) dst[e] = make_uint4(pk[e*4], pk[e*4+1], pk[e*4+2], pk[e*4+3]);
}

// ------------- k3b: out = (LN'd-update @ W_out^T) * sigm(zn@W_og^T+b) * mask
__global__ __launch_bounds__(256) void k3b_out(
    const u16* __restrict__ znu, const u16* __restrict__ znS,
    const float* __restrict__ pmask, const float* __restrict__ b_og,
    const u16* __restrict__ wts, float* __restrict__ out)
{
  __shared__ __align__(16) u16 uL[64][136];
  __shared__ __align__(16) u16 zL[64][136];
  __shared__ float mask_s[64];
  const int t = threadIdx.x;
  const int row0 = blockIdx.x * 64;

  #pragma unroll
  for (int k=0;k<4;k++){
    uint4 vu = *(const uint4*)(znu + (size_t)row0*CH + k*2048 + t*8);
    uint4 vz = *(const uint4*)(znS + (size_t)row0*CH + k*2048 + t*8);
    int r = k*16 + (t>>4), g = t & 15;
    *(uint4*)&uL[r][g*8] = vu;
    *(uint4*)&zL[r][g*8] = vz;
  }
  if (t < 16) ((float4*)mask_s)[t] = ((const float4*)(pmask + row0))[t];
  __syncthreads();

  const int lane = t & 63, w = t >> 6;
  const int lr = lane & 15, lg = lane >> 4;

  f32x4 acc_o[4][2], acc_g[4][2];
  const f32x4 zero4 = {0.f,0.f,0.f,0.f};
  #pragma unroll
  for (int mi=0;mi<4;mi++){ acc_o[mi][0]=zero4; acc_o[mi][1]=zero4; acc_g[mi][0]=zero4; acc_g[mi][1]=zero4; }

  #pragma unroll
  for (int kk=0;kk<4;kk++){
    bf16x8 a[4];
    #pragma unroll
    for (int mi=0;mi<4;mi++)
      a[mi] = *(const bf16x8*)&uL[mi*16 + lr][kk*32 + lg*8];
    #pragma unroll
    for (int n=0;n<2;n++){
      int o = w*32 + n*16 + lr;
      bf16x8 b = *(const bf16x8*)&wts[5*16384 + o*128 + kk*32 + lg*8];
      #pragma unroll
      for (int mi=0;mi<4;mi++)
        acc_o[mi][n] = __builtin_amdgcn_mfma_f32_16x16x32_bf16(a[mi], b, acc_o[mi][n], 0,0,0);
    }
  }
  #pragma unroll
  for (int kk=0;kk<4;kk++){
    bf16x8 a[4];
    #pragma unroll
    for (int mi=0;mi<4;mi++)
      a[mi] = *(const bf16x8*)&zL[mi*16 + lr][kk*32 + lg*8];
    #pragma unroll
    for (int n=0;n<2;n++){
      int o = w*32 + n*16 + lr;
      bf16x8 b = *(const bf16x8*)&wts[4*16384 + o*128 + kk*32 + lg*8];
      #pragma unroll
      for (int mi=0;mi<4;mi++)
        acc_g[mi][n] = __builtin_amdgcn_mfma_f32_16x16x32_bf16(a[mi], b, acc_g[mi][n], 0,0,0);
    }
  }

  #pragma unroll
  for (int n=0;n<2;n++){
    int o = w*32 + n*16 + lr;
    float bgv = b_og[o];
    #pragma unroll
    for (int mi=0;mi<4;mi++){
      #pragma unroll
      for (int g2=0;g2<4;g2++){
        int r = mi*16 + lg*4 + g2;
        float val = acc_o[mi][n][g2] * sigm(acc_g[mi][n][g2] + bgv) * mask_s[r];
        out[(size_t)(row0 + r)*CH + o] = val;
      }
    }
  }
}

// ------------- k3bf: FUSED LN(update) + dual GEMM + gate + store ----------
__global__ __launch_bounds__(256) void k3bf_out(
    const u16* __restrict__ upd16, const u16* __restrict__ znS,
    const float* __restrict__ pmask, const float* __restrict__ onw,
    const float* __restrict__ onb, const float* __restrict__ b_og,
    const u16* __restrict__ wts, float* __restrict__ out)
{
  __shared__ __align__(16) u16 zn[64][136];   // LN'd update (GEMM1 A operand)
  __shared__ __align__(16) u16 zL[64][136];   // znS tile   (GEMM2 A operand)
  __shared__ float ps[4][64], pq[4][64];
  __shared__ float st2[64][2];
  __shared__ float onw_s[128], onb_s[128], mask_s[64];

  const int t = threadIdx.x;
  const int row0 = blockIdx.x * 64;
  const int j  = t & 63;
  const int h2 = t >> 6;

  uint4 vz[4];
  #pragma unroll
  for (int k=0;k<4;k++) vz[k] = *(const uint4*)(znS + (size_t)row0*CH + k*2048 + t*8);

  float v[32];
  #pragma unroll
  for (int e=0;e<32;e++){
    int c = h2*32 + e;
    v[e] = bf2f(upd16[(size_t)c*NN + row0 + j]);
  }

  if (t < 32)      ((float4*)onw_s)[t]     = ((const float4*)onw)[t];
  else if (t < 64) ((float4*)onb_s)[t-32]  = ((const float4*)onb)[t-32];
  else if (t < 80) ((float4*)mask_s)[t-64] = ((const float4*)(pmask + row0))[t-64];

  #pragma unroll
  for (int k=0;k<4;k++){
    int r = k*16 + (t>>4), g = t & 15;
    *(uint4*)&zL[r][g*8] = vz[k];
  }

  {
    float s = 0.f, sq = 0.f;
    #pragma unroll
    for (int e=0;e<32;e++){ s += v[e]; sq += v[e]*v[e]; }
    ps[h2][j] = s; pq[h2][j] = sq;
  }
  __syncthreads();
  if (t < 64){
    float s  = ps[0][t]+ps[1][t]+ps[2][t]+ps[3][t];
    float sq = pq[0][t]+pq[1][t]+pq[2][t]+pq[3][t];
    float mu = s * (1.f/128.f);
    float rstd = __builtin_amdgcn_rsqf(sq * (1.f/128.f) - mu*mu + 1e-5f);
    st2[t][0] = mu; st2[t][1] = rstd;
  }
  __syncthreads();

  {
    float mu = st2[j][0], rstd = st2[j][1];
    #pragma unroll
    for (int q=0;q<4;q++){
      uint32_t pk[4];
      #pragma unroll
      for (int p=0;p<4;p++){
        int e = q*8 + p*2;
        int c = h2*32 + e;
        float y0 = (v[e]   - mu)*rstd*onw_s[c]   + onb_s[c];
        float y1 = (v[e+1] - mu)*rstd*onw_s[c+1] + onb_s[c+1];
        pk[p] = cvtpk(y0, y1);
      }
      *(uint4*)&zn[j][h2*32 + q*8] = make_uint4(pk[0],pk[1],pk[2],pk[3]);
    }
  }
  __syncthreads();

  const int lane = t & 63, w = t >> 6;
  const int lr = lane & 15, lg = lane >> 4;

  f32x4 acc_o[4][2], acc_g[4][2];
  const f32x4 zero4 = {0.f,0.f,0.f,0.f};
  #pragma unroll
  for (int mi=0;mi<4;mi++){ acc_o[mi][0]=zero4; acc_o[mi][1]=zero4; acc_g[mi][0]=zero4; acc_g[mi][1]=zero4; }

  #pragma unroll
  for (int kk=0;kk<4;kk++){
    bf16x8 a[4];
    #pragma unroll
    for (int mi=0;mi<4;mi++)
      a[mi] = *(const bf16x8*)&zn[mi*16 + lr][kk*32 + lg*8];
    #pragma unroll
    for (int n=0;n<2;n++){
      int o = w*32 + n*16 + lr;
      bf16x8 b = *(const bf16x8*)&wts[5*16384 + o*128 + kk*32 + lg*8];
      #pragma unroll
      for (int mi=0;mi<4;mi++)
        acc_o[mi][n] = __builtin_amdgcn_mfma_f32_16x16x32_bf16(a[mi], b, acc_o[mi][n], 0,0,0);
    }
  }
  #pragma unroll
  for (int kk=0;kk<4;kk++){
    bf16x8 a[4];
    #pragma unroll
    for (int mi=0;mi<4;mi++)
      a[mi] = *(const bf16x8*)&zL[mi*16 + lr][kk*32 + lg*8];
    #pragma unroll
    for (int n=0;n<2;n++){
      int o = w*32 + n*16 + lr;
      bf16x8 b = *(const bf16x8*)&wts[4*16384 + o*128 + kk*32 + lg*8];
      #pragma unroll
      for (int mi=0;mi<4;mi++)
        acc_g[mi][n] = __builtin_amdgcn_mfma_f32_16x16x32_bf16(a[mi], b, acc_g[mi][n], 0,0,0);
    }
  }

  #pragma unroll
  for (int n=0;n<2;n++){
    int o = w*32 + n*16 + lr;
    float bgv = b_og[o];
    #pragma unroll
    for (int mi=0;mi<4;mi++){
      #pragma unroll
      for (int g2=0;g2<4;g2++){
        int r = mi*16 + lg*4 + g2;
        float val = acc_o[mi][n][g2] * sigm(acc_g[mi][n][g2] + bgv) * mask_s[r];
        out[(size_t)(row0 + r)*CH + o] = val;
      }
    }
  }
}

// --------------------------- launcher ------------------------------------
extern "C" void kernel_launch(void* const* d_in, const int* in_sizes, int n_in,
                              void* d_out, int out_size, void* d_ws, size_t ws_size,
                              hipStream_t stream)
{
  const float* z       = (const float*)d_in[0];
  const float* pmask   = (const float*)d_in[1];
  const float* lnw     = (const float*)d_in[2];
  const float* lnb     = (const float*)d_in[3];
  const float* W_left  = (const float*)d_in[4];
  const float* W_right = (const float*)d_in[5];
  const float* W_lgate = (const float*)d_in[6];
  const float* b_lgate = (const float*)d_in[7];
  const float* W_rgate = (const float*)d_in[8];
  const float* b_rgate = (const float*)d_in[9];
  const float* onw     = (const float*)d_in[10];
  const float* onb     = (const float*)d_in[11];
  const float* W_out   = (const float*)d_in[12];
  const float* W_ogate = (const float*)d_in[13];
  const float* b_ogate = (const float*)d_in[14];

  const size_t SLOT = 67108864;   // 64 MiB
  uint8_t* ws = (uint8_t*)d_ws;
  u16* left_t  = (u16*)(ws);
  u16* right_t = (u16*)(ws + SLOT);
  u16* znS     = (u16*)(ws + 2*SLOT);

  const bool fused = (ws_size >= 4*SLOT + 196608);
  u16* wts   = (u16*)(ws + (fused ? 4*SLOT : 3*SLOT));
  u16* upd16 = fused ? (u16*)(ws + 3*SLOT) : (u16*)d_out;

  k0_cvt<<<96, 256, 0, stream>>>(W_left, W_lgate, W_right, W_rgate, W_ogate, W_out, wts);
  k1ab_proj<<<2048, 256, 0, stream>>>(z, pmask, lnw, lnb, b_lgate, b_rgate, wts,
                                      znS, left_t, right_t);
  k2_einsum<<<dim3(8,8,128), 256, 0, stream>>>(left_t, right_t, upd16);

  if (fused){
    k3bf_out<<<4096, 256, 0, stream>>>(upd16, znS, pmask, onw, onb, b_ogate, wts,
                                       (float*)d_out);
  } else {
    k3a_ln<<<dim3(512,4), 256, 0, stream>>>(upd16, onw, onb, left_t /*znu*/);
    k3b_out<<<4096, 256, 0, stream>>>(left_t /*znu*/, znS, pmask, b_ogate, wts,
                                      (float*)d_out);
  }
}

// Round 11
// 301.725 us; speedup vs baseline: 1.3896x; 1.0481x over previous
//
#include <hip/hip_runtime.h>
#include <stdint.h>

#define NSEQ 512
#define CH   128
#define NN   (NSEQ*NSEQ)   // 262144

typedef unsigned short u16;
typedef __attribute__((ext_vector_type(8))) short bf16x8;  // 8 bf16 = 4 VGPRs
typedef __attribute__((ext_vector_type(4))) float f32x4;

__device__ __forceinline__ u16 f2bf(float x){          // RNE
  uint32_t u = __float_as_uint(x);
  u += 0x7fffu + ((u >> 16) & 1u);
  return (u16)(u >> 16);
}
__device__ __forceinline__ float bf2f(u16 h){
  return __uint_as_float(((uint32_t)h) << 16);
}
__device__ __forceinline__ uint32_t cvtpk(float lo, float hi){  // bf16(lo)|bf16(hi)<<16
  uint32_t r;
  asm volatile("v_cvt_pk_bf16_f32 %0, %1, %2" : "=v"(r) : "v"(lo), "v"(hi));
  return r;
}
__device__ __forceinline__ float sigm(float x){
  return __builtin_amdgcn_rcpf(1.0f + __expf(-x));
}
__device__ __forceinline__ void gll16(const void* g, void* l){  // 16B global->LDS DMA
  __builtin_amdgcn_global_load_lds((const __attribute__((address_space(1))) void*)g,
                                   (__attribute__((address_space(3))) void*)l, 16, 0, 0);
}

// left/right tensor layout: [i (512)][kblk (8)][c (128)][kin (64)] u16
// offset = i*65536 + kblk*8192 + c*64 + kin   (flat row n = i*512 + kblk*64 + kin)

// ------------- k0: cast 6 weight matrices fp32 -> bf16 -------------
// slot order: 0=W_left 1=W_lgate 2=W_right 3=W_rgate 4=W_ogate 5=W_out
__global__ void k0_cvt(const float* __restrict__ w0, const float* __restrict__ w1,
                       const float* __restrict__ w2, const float* __restrict__ w3,
                       const float* __restrict__ w4, const float* __restrict__ w5,
                       u16* __restrict__ out)
{
  int mat = blockIdx.x >> 4;
  int blk = blockIdx.x & 15;
  const float* src = (mat==0)?w0:(mat==1)?w1:(mat==2)?w2:(mat==3)?w3:(mat==4)?w4:w5;
  int idx = (blk*256 + (int)threadIdx.x) * 4;
  float4 v = *(const float4*)(src + idx);
  uint2 pk;
  pk.x = cvtpk(v.x, v.y);
  pk.y = cvtpk(v.z, v.w);
  *(uint2*)(out + mat*16384 + idx) = pk;
}

// ------------- k1ab: FUSED LN(z) + 2 gated projections, 128 rows/block ----
__global__ __launch_bounds__(256) void k1ab_proj(
    const float* __restrict__ z, const float* __restrict__ pmask,
    const float* __restrict__ lnw, const float* __restrict__ lnb,
    const float* __restrict__ b_lg, const float* __restrict__ b_rg,
    const u16* __restrict__ wts, u16* __restrict__ znS,
    u16* __restrict__ left_t, u16* __restrict__ right_t)
{
  __shared__ __align__(16) u16 zn[2][64][136];  // 34 KB
  __shared__ __align__(16) u16 stg[4][2048];    // 16 KB (per-wave stage)
  __shared__ float lnw_s[128], lnb_s[128], mask_s[128];
  const int t = threadIdx.x;
  const int row0 = blockIdx.x * 128;

  if (t < 32)      ((float4*)lnw_s)[t]     = ((const float4*)lnw)[t];
  else if (t < 64) ((float4*)lnb_s)[t-32]  = ((const float4*)lnb)[t-32];
  else if (t < 96) ((float4*)mask_s)[t-64] = ((const float4*)(pmask + row0))[t-64];

  const int r = t >> 2, q = t & 3;
  float4 v0[8], v1[8];
  {
    const float* zp0 = z + (size_t)(row0 + r) * CH + q * 32;
    const float* zp1 = z + (size_t)(row0 + 64 + r) * CH + q * 32;
    #pragma unroll
    for (int e=0;e<8;e++) v0[e] = ((const float4*)zp0)[e];
    #pragma unroll
    for (int e=0;e<8;e++) v1[e] = ((const float4*)zp1)[e];
  }
  __syncthreads();

  // ----- LN tile 0 -----
  {
    float s = 0.f, sq = 0.f;
    #pragma unroll
    for (int e=0;e<8;e++){
      s  += v0[e].x + v0[e].y + v0[e].z + v0[e].w;
      sq += v0[e].x*v0[e].x + v0[e].y*v0[e].y + v0[e].z*v0[e].z + v0[e].w*v0[e].w;
    }
    s += __shfl_xor(s,1); sq += __shfl_xor(sq,1);
    s += __shfl_xor(s,2); sq += __shfl_xor(sq,2);
    float mu = s * (1.f/128.f);
    float rstd = __builtin_amdgcn_rsqf(sq * (1.f/128.f) - mu*mu + 1e-5f);
    uint32_t pk[16];
    #pragma unroll
    for (int e=0;e<8;e++){
      int c = q*32 + e*4;
      float a0 = (v0[e].x - mu)*rstd*lnw_s[c+0] + lnb_s[c+0];
      float a1 = (v0[e].y - mu)*rstd*lnw_s[c+1] + lnb_s[c+1];
      float a2 = (v0[e].z - mu)*rstd*lnw_s[c+2] + lnb_s[c+2];
      float a3 = (v0[e].w - mu)*rstd*lnw_s[c+3] + lnb_s[c+3];
      pk[e*2+0] = cvtpk(a0, a1);
      pk[e*2+1] = cvtpk(a2, a3);
    }
    uint4* gd = (uint4*)(znS + (size_t)(row0 + r)*CH + q*32);
    uint4* ld = (uint4*)&zn[0][r][q*32];
    #pragma unroll
    for (int e=0;e<4;e++){
      uint4 w4 = make_uint4(pk[e*4], pk[e*4+1], pk[e*4+2], pk[e*4+3]);
      gd[e] = w4; ld[e] = w4;
    }
  }
  // ----- LN tile 1 -----
  {
    float s = 0.f, sq = 0.f;
    #pragma unroll
    for (int e=0;e<8;e++){
      s  += v1[e].x + v1[e].y + v1[e].z + v1[e].w;
      sq += v1[e].x*v1[e].x + v1[e].y*v1[e].y + v1[e].z*v1[e].z + v1[e].w*v1[e].w;
    }
    s += __shfl_xor(s,1); sq += __shfl_xor(sq,1);
    s += __shfl_xor(s,2); sq += __shfl_xor(sq,2);
    float mu = s * (1.f/128.f);
    float rstd = __builtin_amdgcn_rsqf(sq * (1.f/128.f) - mu*mu + 1e-5f);
    uint32_t pk[16];
    #pragma unroll
    for (int e=0;e<8;e++){
      int c = q*32 + e*4;
      float a0 = (v1[e].x - mu)*rstd*lnw_s[c+0] + lnb_s[c+0];
      float a1 = (v1[e].y - mu)*rstd*lnw_s[c+1] + lnb_s[c+1];
      float a2 = (v1[e].z - mu)*rstd*lnw_s[c+2] + lnb_s[c+2];
      float a3 = (v1[e].w - mu)*rstd*lnw_s[c+3] + lnb_s[c+3];
      pk[e*2+0] = cvtpk(a0, a1);
      pk[e*2+1] = cvtpk(a2, a3);
    }
    uint4* gd = (uint4*)(znS + (size_t)(row0 + 64 + r)*CH + q*32);
    uint4* ld = (uint4*)&zn[1][r][q*32];
    #pragma unroll
    for (int e=0;e<4;e++){
      uint4 w4 = make_uint4(pk[e*4], pk[e*4+1], pk[e*4+2], pk[e*4+3]);
      gd[e] = w4; ld[e] = w4;
    }
  }
  __syncthreads();

  const int lane = t & 63;
  const int w = t >> 6;
  const int lr = lane & 15;
  const int lg = lane >> 4;
  const int ow = w*32;
  const f32x4 zero4 = {0.f,0.f,0.f,0.f};

  #pragma unroll
  for (int tt=0; tt<2; tt++){
    const int r0t = row0 + tt*64;
    const size_t tile_off = (size_t)(r0t >> 9)*65536 + (size_t)((r0t >> 6) & 7)*8192;
    const float* msk = mask_s + tt*64;

    bf16x8 wl[8], wg[8];
    #pragma unroll
    for (int kk=0;kk<4;kk++)
      #pragma unroll
      for (int n=0;n<2;n++){
        int o = ow + n*16 + lr;
        wl[kk*2+n] = *(const bf16x8*)&wts[0*16384 + o*128 + kk*32 + lg*8];
        wg[kk*2+n] = *(const bf16x8*)&wts[1*16384 + o*128 + kk*32 + lg*8];
      }

    f32x4 acc1[4][2], acc2[4][2];
    #pragma unroll
    for (int mi=0;mi<4;mi++){ acc1[mi][0]=zero4; acc1[mi][1]=zero4; acc2[mi][0]=zero4; acc2[mi][1]=zero4; }
    #pragma unroll
    for (int kk=0;kk<4;kk++){
      bf16x8 a[4];
      #pragma unroll
      for (int mi=0;mi<4;mi++)
        a[mi] = *(const bf16x8*)&zn[tt][mi*16 + lr][kk*32 + lg*8];
      #pragma unroll
      for (int n=0;n<2;n++)
        #pragma unroll
        for (int mi=0;mi<4;mi++){
          acc1[mi][n] = __builtin_amdgcn_mfma_f32_16x16x32_bf16(a[mi], wl[kk*2+n], acc1[mi][n], 0,0,0);
          acc2[mi][n] = __builtin_amdgcn_mfma_f32_16x16x32_bf16(a[mi], wg[kk*2+n], acc2[mi][n], 0,0,0);
        }
    }
    bf16x8 wl2[8], wg2[8];
    #pragma unroll
    for (int kk=0;kk<4;kk++)
      #pragma unroll
      for (int n=0;n<2;n++){
        int o = ow + n*16 + lr;
        wl2[kk*2+n] = *(const bf16x8*)&wts[2*16384 + o*128 + kk*32 + lg*8];
        wg2[kk*2+n] = *(const bf16x8*)&wts[3*16384 + o*128 + kk*32 + lg*8];
      }

    #pragma unroll
    for (int n=0;n<2;n++){
      int ol = n*16 + lr;
      float bgv = b_lg[ow + ol];
      #pragma unroll
      for (int mi=0;mi<4;mi++){
        int r0 = mi*16 + lg*4;
        float u0 = acc1[mi][n][0] * sigm(acc2[mi][n][0] + bgv) * msk[r0+0];
        float u1 = acc1[mi][n][1] * sigm(acc2[mi][n][1] + bgv) * msk[r0+1];
        float u2 = acc1[mi][n][2] * sigm(acc2[mi][n][2] + bgv) * msk[r0+2];
        float u3 = acc1[mi][n][3] * sigm(acc2[mi][n][3] + bgv) * msk[r0+3];
        int chunk = (mi*2 + (lg>>1)) ^ (ol & 7);
        *(uint2*)&stg[w][ol*64 + (chunk<<3) + (lg&1)*4] = make_uint2(cvtpk(u0,u1), cvtpk(u2,u3));
      }
    }
    {
      int ol = lane >> 1, rh = lane & 1;
      uint4 pf[4];
      #pragma unroll
      for (int qq=0;qq<4;qq++){
        int m = (rh*4 + qq) ^ (ol & 7);
        pf[qq] = *(const uint4*)&stg[w][ol*64 + (m<<3)];
      }
      uint4* dst = (uint4*)(left_t + tile_off + (ow + ol)*64 + rh*32);
      #pragma unroll
      for (int qq=0;qq<4;qq++) dst[qq] = pf[qq];
    }

    #pragma unroll
    for (int mi=0;mi<4;mi++){ acc1[mi][0]=zero4; acc1[mi][1]=zero4; acc2[mi][0]=zero4; acc2[mi][1]=zero4; }
    #pragma unroll
    for (int kk=0;kk<4;kk++){
      bf16x8 a[4];
      #pragma unroll
      for (int mi=0;mi<4;mi++)
        a[mi] = *(const bf16x8*)&zn[tt][mi*16 + lr][kk*32 + lg*8];
      #pragma unroll
      for (int n=0;n<2;n++)
        #pragma unroll
        for (int mi=0;mi<4;mi++){
          acc1[mi][n] = __builtin_amdgcn_mfma_f32_16x16x32_bf16(a[mi], wl2[kk*2+n], acc1[mi][n], 0,0,0);
          acc2[mi][n] = __builtin_amdgcn_mfma_f32_16x16x32_bf16(a[mi], wg2[kk*2+n], acc2[mi][n], 0,0,0);
        }
    }
    #pragma unroll
    for (int n=0;n<2;n++){
      int ol = n*16 + lr;
      float bgv = b_rg[ow + ol];
      #pragma unroll
      for (int mi=0;mi<4;mi++){
        int r0 = mi*16 + lg*4;
        float u0 = acc1[mi][n][0] * sigm(acc2[mi][n][0] + bgv) * msk[r0+0];
        float u1 = acc1[mi][n][1] * sigm(acc2[mi][n][1] + bgv) * msk[r0+1];
        float u2 = acc1[mi][n][2] * sigm(acc2[mi][n][2] + bgv) * msk[r0+2];
        float u3 = acc1[mi][n][3] * sigm(acc2[mi][n][3] + bgv) * msk[r0+3];
        int chunk = (mi*2 + (lg>>1)) ^ (ol & 7);
        *(uint2*)&stg[w][ol*64 + (chunk<<3) + (lg&1)*4] = make_uint2(cvtpk(u0,u1), cvtpk(u2,u3));
      }
    }
    {
      int ol = lane >> 1, rh = lane & 1;
      uint4 pf[4];
      #pragma unroll
      for (int qq=0;qq<4;qq++){
        int m = (rh*4 + qq) ^ (ol & 7);
        pf[qq] = *(const uint4*)&stg[w][ol*64 + (m<<3)];
      }
      uint4* dst = (uint4*)(right_t + tile_off + (ow + ol)*64 + rh*32);
      #pragma unroll
      for (int qq=0;qq<4;qq++) dst[qq] = pf[qq];
    }
  }
}

// ------------- k2: per-channel 64x64x512 GEMM, gll staging + XCD swizzle --
// T1: consecutive hardware linear IDs round-robin across the 8 XCDs; the
// bijective chunked transform gives XCD k logical ids [k*1024,(k+1)*1024)
// = 16 consecutive channels, so the 64 same-c blocks (sharing 1MB of L/R
// panels) run temporally adjacent on ONE XCD -> panels stay in its 4MB L2.
__global__ __launch_bounds__(256) void k2_einsum(
    const u16* __restrict__ left_t, const u16* __restrict__ right_t,
    u16* __restrict__ upd16)
{
  __shared__ __align__(16) u16 lds_raw[16384];  // L bufs @0,4096 | R bufs @8192,12288
  const int t = threadIdx.x;
  const int lane = t & 63, w = t >> 6;
  const int wi = w >> 1, wj = w & 1;
  const int lr = lane & 15, lg = lane >> 4;

  // XCD-aware bijective swizzle (nwg = 8192, 8192 % 8 == 0)
  const int lin = (int)(blockIdx.x + (blockIdx.y << 3) + (blockIdx.z << 6));
  const int logical = ((lin & 7) << 10) + (lin >> 3);
  const int c  = logical >> 6;
  const int tl = logical & 63;
  const int i0 = (tl & 7) * 64, j0 = (tl >> 3) * 64;

  const int srow = t >> 3;   // 0..31
  const int ssl  = t & 7;

  f32x4 acc[2][2];
  const f32x4 zero4 = {0.f,0.f,0.f,0.f};
  acc[0][0]=zero4; acc[0][1]=zero4; acc[1][0]=zero4; acc[1][1]=zero4;

  // stage k-tile kt into buffer buf via 16B global->LDS DMA (4 per thread)
  auto stage = [&](int buf, int kt){
    #pragma unroll
    for (int q=0;q<2;q++){
      int row = q*32 + srow;
      int gs  = ssl ^ (row & 7);
      size_t gofs = (size_t)kt*8192 + (size_t)c*64 + gs*8;
      const u16* gl = &left_t [(size_t)(i0+row)*65536 + gofs];
      const u16* gr = &right_t[(size_t)(j0+row)*65536 + gofs];
      u16* dl = lds_raw +        buf*4096 + q*2048 + w*512 + lane*8;  // linear in lane
      u16* dr = lds_raw + 8192 + buf*4096 + q*2048 + w*512 + lane*8;
      gll16(gl, dl);
      gll16(gr, dr);
    }
  };

  stage(0, 0);
  __syncthreads();   // vmcnt(0) drain before barrier -> tile 0 landed

  for (int kt=0; kt<8; kt++){
    const int buf = kt & 1;
    if (kt < 7) stage(buf^1, kt+1);   // DMA in flight across the MFMA phase
    #pragma unroll
    for (int kk=0;kk<2;kk++){
      bf16x8 af[2], bfr[2];
      #pragma unroll
      for (int mi=0;mi<2;mi++){
        int row = wi*32 + mi*16 + lr;
        af[mi] = *(const bf16x8*)&lds_raw[buf*4096 + row*64 + (((kk*4+lg) ^ (row&7)))*8];
      }
      #pragma unroll
      for (int nj=0;nj<2;nj++){
        int row = wj*32 + nj*16 + lr;
        bfr[nj] = *(const bf16x8*)&lds_raw[8192 + buf*4096 + row*64 + (((kk*4+lg) ^ (row&7)))*8];
      }
      #pragma unroll
      for (int mi=0;mi<2;mi++)
        #pragma unroll
        for (int nj=0;nj<2;nj++)
          acc[mi][nj] = __builtin_amdgcn_mfma_f32_16x16x32_bf16(af[mi], bfr[nj], acc[mi][nj], 0,0,0);
    }
    __syncthreads();   // drains the prefetch DMA -> buf^1 ready
  }

  const float scale = 0.044194173824159216f;   // 1/sqrt(512)
  u16* st = lds_raw;
  #pragma unroll
  for (int mi=0;mi<2;mi++){
    #pragma unroll
    for (int nj=0;nj<2;nj++){
      int cj = wj*32 + nj*16 + lr;
      #pragma unroll
      for (int g2=0;g2<4;g2++){
        int ri = wi*32 + mi*16 + lg*4 + g2;
        st[ri*72 + cj] = f2bf(acc[mi][nj][g2] * scale);
      }
    }
  }
  __syncthreads();
  {
    int ri = t >> 2, q = t & 3;
    const uint4* src = (const uint4*)&st[ri*72 + q*16];
    uint4* dst = (uint4*)(upd16 + (size_t)c*NN + (size_t)(i0+ri)*NSEQ + j0 + q*16);
    dst[0] = src[0];
    dst[1] = src[1];
  }
}

// ------------- k3a: LN over c of upd16 [c][i*512+j] -> znu [row][c] bf16 --
__global__ __launch_bounds__(256) void k3a_ln(
    const u16* __restrict__ upd16, const float* __restrict__ onw,
    const float* __restrict__ onb, u16* __restrict__ znu)
{
  __shared__ float u[128*129];
  __shared__ float onw_s[128], onb_s[128];
  const int t = threadIdx.x;
  const int i = blockIdx.x;
  const int j0 = blockIdx.y * 128;

  if (t < 32)      ((float4*)onw_s)[t]    = ((const float4*)onw)[t];
  else if (t < 64) ((float4*)onb_s)[t-32] = ((const float4*)onb)[t-32];

  {
    int cr = t >> 1, h = t & 1;
    const uint4* src = (const uint4*)(upd16 + (size_t)cr*NN + (size_t)i*NSEQ + j0 + h*64);
    float* dst = &u[cr*129 + h*64];
    #pragma unroll
    for (int e=0;e<8;e++){
      uint4 v = src[e];
      const u16* hp = (const u16*)&v;
      #pragma unroll
      for (int p=0;p<8;p++) dst[e*8+p] = bf2f(hp[p]);
    }
  }
  __syncthreads();

  int j = t >> 1, h = t & 1;
  float s = 0.f, sq = 0.f;
  #pragma unroll
  for (int e=0;e<64;e++){
    float v = u[(h*64+e)*129 + j];
    s += v; sq += v*v;
  }
  s += __shfl_xor(s,1); sq += __shfl_xor(sq,1);
  float mu = s * (1.f/128.f);
  float rstd = __builtin_amdgcn_rsqf(sq * (1.f/128.f) - mu*mu + 1e-5f);

  uint32_t pk[32];
  #pragma unroll
  for (int e=0;e<64;e+=2){
    int c0 = h*64 + e;
    float v0 = (u[c0*129 + j]     - mu)*rstd*onw_s[c0]   + onb_s[c0];
    float v1 = (u[(c0+1)*129 + j] - mu)*rstd*onw_s[c0+1] + onb_s[c0+1];
    pk[e>>1] = cvtpk(v0, v1);
  }
  uint4* dst = (uint4*)(znu + ((size_t)i*NSEQ + j0 + j)*CH + h*64);
  #pragma unroll
  for (int e=0;e<8;e++) dst[e] = make_uint4(pk[e*4], pk[e*4+1], pk[e*4+2], pk[e*4+3]);
}

// ------------- k3b: out = (LN'd-update @ W_out^T) * sigm(zn@W_og^T+b) * mask
__global__ __launch_bounds__(256) void k3b_out(
    const u16* __restrict__ znu, const u16* __restrict__ znS,
    const float* __restrict__ pmask, const float* __restrict__ b_og,
    const u16* __restrict__ wts, float* __restrict__ out)
{
  __shared__ __align__(16) u16 uL[64][136];
  __shared__ __align__(16) u16 zL[64][136];
  __shared__ float mask_s[64];
  const int t = threadIdx.x;
  const int row0 = blockIdx.x * 64;

  #pragma unroll
  for (int k=0;k<4;k++){
    uint4 vu = *(const uint4*)(znu + (size_t)row0*CH + k*2048 + t*8);
    uint4 vz = *(const uint4*)(znS + (size_t)row0*CH + k*2048 + t*8);
    int r = k*16 + (t>>4), g = t & 15;
    *(uint4*)&uL[r][g*8] = vu;
    *(uint4*)&zL[r][g*8] = vz;
  }
  if (t < 16) ((float4*)mask_s)[t] = ((const float4*)(pmask + row0))[t];
  __syncthreads();

  const int lane = t & 63, w = t >> 6;
  const int lr = lane & 15, lg = lane >> 4;

  f32x4 acc_o[4][2], acc_g[4][2];
  const f32x4 zero4 = {0.f,0.f,0.f,0.f};
  #pragma unroll
  for (int mi=0;mi<4;mi++){ acc_o[mi][0]=zero4; acc_o[mi][1]=zero4; acc_g[mi][0]=zero4; acc_g[mi][1]=zero4; }

  #pragma unroll
  for (int kk=0;kk<4;kk++){
    bf16x8 a[4];
    #pragma unroll
    for (int mi=0;mi<4;mi++)
      a[mi] = *(const bf16x8*)&uL[mi*16 + lr][kk*32 + lg*8];
    #pragma unroll
    for (int n=0;n<2;n++){
      int o = w*32 + n*16 + lr;
      bf16x8 b = *(const bf16x8*)&wts[5*16384 + o*128 + kk*32 + lg*8];
      #pragma unroll
      for (int mi=0;mi<4;mi++)
        acc_o[mi][n] = __builtin_amdgcn_mfma_f32_16x16x32_bf16(a[mi], b, acc_o[mi][n], 0,0,0);
    }
  }
  #pragma unroll
  for (int kk=0;kk<4;kk++){
    bf16x8 a[4];
    #pragma unroll
    for (int mi=0;mi<4;mi++)
      a[mi] = *(const bf16x8*)&zL[mi*16 + lr][kk*32 + lg*8];
    #pragma unroll
    for (int n=0;n<2;n++){
      int o = w*32 + n*16 + lr;
      bf16x8 b = *(const bf16x8*)&wts[4*16384 + o*128 + kk*32 + lg*8];
      #pragma unroll
      for (int mi=0;mi<4;mi++)
        acc_g[mi][n] = __builtin_amdgcn_mfma_f32_16x16x32_bf16(a[mi], b, acc_g[mi][n], 0,0,0);
    }
  }

  #pragma unroll
  for (int n=0;n<2;n++){
    int o = w*32 + n*16 + lr;
    float bgv = b_og[o];
    #pragma unroll
    for (int mi=0;mi<4;mi++){
      #pragma unroll
      for (int g2=0;g2<4;g2++){
        int r = mi*16 + lg*4 + g2;
        float val = acc_o[mi][n][g2] * sigm(acc_g[mi][n][g2] + bgv) * mask_s[r];
        out[(size_t)(row0 + r)*CH + o] = val;
      }
    }
  }
}

// ------------- k3bf: FUSED LN(update) + dual GEMM + gate + store ----------
__global__ __launch_bounds__(256) void k3bf_out(
    const u16* __restrict__ upd16, const u16* __restrict__ znS,
    const float* __restrict__ pmask, const float* __restrict__ onw,
    const float* __restrict__ onb, const float* __restrict__ b_og,
    const u16* __restrict__ wts, float* __restrict__ out)
{
  __shared__ __align__(16) u16 zn[64][136];   // LN'd update (GEMM1 A operand)
  __shared__ __align__(16) u16 zL[64][136];   // znS tile   (GEMM2 A operand)
  __shared__ float ps[4][64], pq[4][64];
  __shared__ float st2[64][2];
  __shared__ float onw_s[128], onb_s[128], mask_s[64];

  const int t = threadIdx.x;
  const int row0 = blockIdx.x * 64;
  const int j  = t & 63;
  const int h2 = t >> 6;

  uint4 vz[4];
  #pragma unroll
  for (int k=0;k<4;k++) vz[k] = *(const uint4*)(znS + (size_t)row0*CH + k*2048 + t*8);

  float v[32];
  #pragma unroll
  for (int e=0;e<32;e++){
    int c = h2*32 + e;
    v[e] = bf2f(upd16[(size_t)c*NN + row0 + j]);
  }

  if (t < 32)      ((float4*)onw_s)[t]     = ((const float4*)onw)[t];
  else if (t < 64) ((float4*)onb_s)[t-32]  = ((const float4*)onb)[t-32];
  else if (t < 80) ((float4*)mask_s)[t-64] = ((const float4*)(pmask + row0))[t-64];

  #pragma unroll
  for (int k=0;k<4;k++){
    int r = k*16 + (t>>4), g = t & 15;
    *(uint4*)&zL[r][g*8] = vz[k];
  }

  {
    float s = 0.f, sq = 0.f;
    #pragma unroll
    for (int e=0;e<32;e++){ s += v[e]; sq += v[e]*v[e]; }
    ps[h2][j] = s; pq[h2][j] = sq;
  }
  __syncthreads();
  if (t < 64){
    float s  = ps[0][t]+ps[1][t]+ps[2][t]+ps[3][t];
    float sq = pq[0][t]+pq[1][t]+pq[2][t]+pq[3][t];
    float mu = s * (1.f/128.f);
    float rstd = __builtin_amdgcn_rsqf(sq * (1.f/128.f) - mu*mu + 1e-5f);
    st2[t][0] = mu; st2[t][1] = rstd;
  }
  __syncthreads();

  {
    float mu = st2[j][0], rstd = st2[j][1];
    #pragma unroll
    for (int q=0;q<4;q++){
      uint32_t pk[4];
      #pragma unroll
      for (int p=0;p<4;p++){
        int e = q*8 + p*2;
        int c = h2*32 + e;
        float y0 = (v[e]   - mu)*rstd*onw_s[c]   + onb_s[c];
        float y1 = (v[e+1] - mu)*rstd*onw_s[c+1] + onb_s[c+1];
        pk[p] = cvtpk(y0, y1);
      }
      *(uint4*)&zn[j][h2*32 + q*8] = make_uint4(pk[0],pk[1],pk[2],pk[3]);
    }
  }
  __syncthreads();

  const int lane = t & 63, w = t >> 6;
  const int lr = lane & 15, lg = lane >> 4;

  f32x4 acc_o[4][2], acc_g[4][2];
  const f32x4 zero4 = {0.f,0.f,0.f,0.f};
  #pragma unroll
  for (int mi=0;mi<4;mi++){ acc_o[mi][0]=zero4; acc_o[mi][1]=zero4; acc_g[mi][0]=zero4; acc_g[mi][1]=zero4; }

  #pragma unroll
  for (int kk=0;kk<4;kk++){
    bf16x8 a[4];
    #pragma unroll
    for (int mi=0;mi<4;mi++)
      a[mi] = *(const bf16x8*)&zn[mi*16 + lr][kk*32 + lg*8];
    #pragma unroll
    for (int n=0;n<2;n++){
      int o = w*32 + n*16 + lr;
      bf16x8 b = *(const bf16x8*)&wts[5*16384 + o*128 + kk*32 + lg*8];
      #pragma unroll
      for (int mi=0;mi<4;mi++)
        acc_o[mi][n] = __builtin_amdgcn_mfma_f32_16x16x32_bf16(a[mi], b, acc_o[mi][n], 0,0,0);
    }
  }
  #pragma unroll
  for (int kk=0;kk<4;kk++){
    bf16x8 a[4];
    #pragma unroll
    for (int mi=0;mi<4;mi++)
      a[mi] = *(const bf16x8*)&zL[mi*16 + lr][kk*32 + lg*8];
    #pragma unroll
    for (int n=0;n<2;n++){
      int o = w*32 + n*16 + lr;
      bf16x8 b = *(const bf16x8*)&wts[4*16384 + o*128 + kk*32 + lg*8];
      #pragma unroll
      for (int mi=0;mi<4;mi++)
        acc_g[mi][n] = __builtin_amdgcn_mfma_f32_16x16x32_bf16(a[mi], b, acc_g[mi][n], 0,0,0);
    }
  }

  #pragma unroll
  for (int n=0;n<2;n++){
    int o = w*32 + n*16 + lr;
    float bgv = b_og[o];
    #pragma unroll
    for (int mi=0;mi<4;mi++){
      #pragma unroll
      for (int g2=0;g2<4;g2++){
        int r = mi*16 + lg*4 + g2;
        float val = acc_o[mi][n][g2] * sigm(acc_g[mi][n][g2] + bgv) * mask_s[r];
        out[(size_t)(row0 + r)*CH + o] = val;
      }
    }
  }
}

// --------------------------- launcher ------------------------------------
extern "C" void kernel_launch(void* const* d_in, const int* in_sizes, int n_in,
                              void* d_out, int out_size, void* d_ws, size_t ws_size,
                              hipStream_t stream)
{
  const float* z       = (const float*)d_in[0];
  const float* pmask   = (const float*)d_in[1];
  const float* lnw     = (const float*)d_in[2];
  const float* lnb     = (const float*)d_in[3];
  const float* W_left  = (const float*)d_in[4];
  const float* W_right = (const float*)d_in[5];
  const float* W_lgate = (const float*)d_in[6];
  const float* b_lgate = (const float*)d_in[7];
  const float* W_rgate = (const float*)d_in[8];
  const float* b_rgate = (const float*)d_in[9];
  const float* onw     = (const float*)d_in[10];
  const float* onb     = (const float*)d_in[11];
  const float* W_out   = (const float*)d_in[12];
  const float* W_ogate = (const float*)d_in[13];
  const float* b_ogate = (const float*)d_in[14];

  const size_t SLOT = 67108864;   // 64 MiB
  uint8_t* ws = (uint8_t*)d_ws;
  u16* left_t  = (u16*)(ws);
  u16* right_t = (u16*)(ws + SLOT);
  u16* znS     = (u16*)(ws + 2*SLOT);

  const bool fused = (ws_size >= 4*SLOT + 196608);
  u16* wts   = (u16*)(ws + (fused ? 4*SLOT : 3*SLOT));
  u16* upd16 = fused ? (u16*)(ws + 3*SLOT) : (u16*)d_out;

  k0_cvt<<<96, 256, 0, stream>>>(W_left, W_lgate, W_right, W_rgate, W_ogate, W_out, wts);
  k1ab_proj<<<2048, 256, 0, stream>>>(z, pmask, lnw, lnb, b_lgate, b_rgate, wts,
                                      znS, left_t, right_t);
  k2_einsum<<<dim3(8,8,128), 256, 0, stream>>>(left_t, right_t, upd16);

  if (fused){
    k3bf_out<<<4096, 256, 0, stream>>>(upd16, znS, pmask, onw, onb, b_ogate, wts,
                                       (float*)d_out);
  } else {
    k3a_ln<<<dim3(512,4), 256, 0, stream>>>(upd16, onw, onb, left_t /*znu*/);
    k3b_out<<<4096, 256, 0, stream>>>(left_t /*znu*/, znS, pmask, b_ogate, wts,
                                      (float*)d_out);
  }
}

// Round 12
// 296.453 us; speedup vs baseline: 1.4143x; 1.0178x over previous
//
#include <hip/hip_runtime.h>
#include <stdint.h>

#define NSEQ 512
#define CH   128
#define NN   (NSEQ*NSEQ)   // 262144

typedef unsigned short u16;
typedef __attribute__((ext_vector_type(8))) short bf16x8;  // 8 bf16 = 4 VGPRs
typedef __attribute__((ext_vector_type(4))) float f32x4;

__device__ __forceinline__ u16 f2bf(float x){          // RNE
  uint32_t u = __float_as_uint(x);
  u += 0x7fffu + ((u >> 16) & 1u);
  return (u16)(u >> 16);
}
__device__ __forceinline__ float bf2f(u16 h){
  return __uint_as_float(((uint32_t)h) << 16);
}
__device__ __forceinline__ uint32_t cvtpk(float lo, float hi){  // bf16(lo)|bf16(hi)<<16
  uint32_t r;
  asm volatile("v_cvt_pk_bf16_f32 %0, %1, %2" : "=v"(r) : "v"(lo), "v"(hi));
  return r;
}
__device__ __forceinline__ float sigm(float x){
  return __builtin_amdgcn_rcpf(1.0f + __expf(-x));
}
__device__ __forceinline__ void gll16(const void* g, void* l){  // 16B global->LDS DMA
  __builtin_amdgcn_global_load_lds((const __attribute__((address_space(1))) void*)g,
                                   (__attribute__((address_space(3))) void*)l, 16, 0, 0);
}

// left/right tensor layout: [i (512)][kblk (8)][c (128)][kin (64)] u16
// offset = i*65536 + kblk*8192 + c*64 + kin   (flat row n = i*512 + kblk*64 + kin)

// ------------- k0: cast 6 weight matrices fp32 -> bf16 -------------
// slot order: 0=W_left 1=W_lgate 2=W_right 3=W_rgate 4=W_ogate 5=W_out
__global__ void k0_cvt(const float* __restrict__ w0, const float* __restrict__ w1,
                       const float* __restrict__ w2, const float* __restrict__ w3,
                       const float* __restrict__ w4, const float* __restrict__ w5,
                       u16* __restrict__ out)
{
  int mat = blockIdx.x >> 4;
  int blk = blockIdx.x & 15;
  const float* src = (mat==0)?w0:(mat==1)?w1:(mat==2)?w2:(mat==3)?w3:(mat==4)?w4:w5;
  int idx = (blk*256 + (int)threadIdx.x) * 4;
  float4 v = *(const float4*)(src + idx);
  uint2 pk;
  pk.x = cvtpk(v.x, v.y);
  pk.y = cvtpk(v.z, v.w);
  *(uint2*)(out + mat*16384 + idx) = pk;
}

// ------------- k1ab: FUSED LN(z) + 2 gated projections, 128 rows/block ----
// z loads are LANE-CONTIGUOUS (1KB/instr, ideal coalescing): thread t, step e
// holds cols (t&31)*4..+3 of row e*8+(t>>5); row stats via 32-lane shfl_xor.
__global__ __launch_bounds__(256) void k1ab_proj(
    const float* __restrict__ z, const float* __restrict__ pmask,
    const float* __restrict__ lnw, const float* __restrict__ lnb,
    const float* __restrict__ b_lg, const float* __restrict__ b_rg,
    const u16* __restrict__ wts, u16* __restrict__ znS,
    u16* __restrict__ left_t, u16* __restrict__ right_t)
{
  __shared__ __align__(16) u16 zn[2][64][136];  // 34 KB
  __shared__ __align__(16) u16 stg[4][2048];    // 16 KB (per-wave stage)
  __shared__ float lnw_s[128], lnb_s[128], mask_s[128];
  const int t = threadIdx.x;
  const int row0 = blockIdx.x * 128;

  if (t < 32)      ((float4*)lnw_s)[t]     = ((const float4*)lnw)[t];
  else if (t < 64) ((float4*)lnb_s)[t-32]  = ((const float4*)lnb)[t-32];
  else if (t < 96) ((float4*)mask_s)[t-64] = ((const float4*)(pmask + row0))[t-64];

  // lane-contiguous z loads: tile0 = float4 idx e*256+t, tile1 = +2048
  const float4* zt = (const float4*)(z + (size_t)row0 * CH);
  float4 v0[8], v1[8];
  #pragma unroll
  for (int e=0;e<8;e++) v0[e] = zt[e*256 + t];
  #pragma unroll
  for (int e=0;e<8;e++) v1[e] = zt[2048 + e*256 + t];
  __syncthreads();   // lnw_s/lnb_s/mask_s visible

  const int rsub = t >> 5;          // row sub-index within step
  const int c4   = (t & 31) * 4;    // this thread's 4 channels

  // ----- LN tile 0: per step e, row = e*8+rsub; stats over 32-lane half -----
  #pragma unroll
  for (int e=0;e<8;e++){
    float4 vv = v0[e];
    float s  = vv.x + vv.y + vv.z + vv.w;
    float sq = vv.x*vv.x + vv.y*vv.y + vv.z*vv.z + vv.w*vv.w;
    s += __shfl_xor(s,1);  sq += __shfl_xor(sq,1);
    s += __shfl_xor(s,2);  sq += __shfl_xor(sq,2);
    s += __shfl_xor(s,4);  sq += __shfl_xor(sq,4);
    s += __shfl_xor(s,8);  sq += __shfl_xor(sq,8);
    s += __shfl_xor(s,16); sq += __shfl_xor(sq,16);
    float mu = s * (1.f/128.f);
    float rstd = __builtin_amdgcn_rsqf(sq * (1.f/128.f) - mu*mu + 1e-5f);
    float y0 = (vv.x - mu)*rstd*lnw_s[c4+0] + lnb_s[c4+0];
    float y1 = (vv.y - mu)*rstd*lnw_s[c4+1] + lnb_s[c4+1];
    float y2 = (vv.z - mu)*rstd*lnw_s[c4+2] + lnb_s[c4+2];
    float y3 = (vv.w - mu)*rstd*lnw_s[c4+3] + lnb_s[c4+3];
    uint2 pk = make_uint2(cvtpk(y0,y1), cvtpk(y2,y3));
    ((uint2*)(znS + (size_t)row0*CH))[e*256 + t] = pk;   // coalesced 8B/lane
    int row = e*8 + rsub;
    *(uint2*)&zn[0][row][c4] = pk;
  }
  // ----- LN tile 1 -----
  #pragma unroll
  for (int e=0;e<8;e++){
    float4 vv = v1[e];
    float s  = vv.x + vv.y + vv.z + vv.w;
    float sq = vv.x*vv.x + vv.y*vv.y + vv.z*vv.z + vv.w*vv.w;
    s += __shfl_xor(s,1);  sq += __shfl_xor(sq,1);
    s += __shfl_xor(s,2);  sq += __shfl_xor(sq,2);
    s += __shfl_xor(s,4);  sq += __shfl_xor(sq,4);
    s += __shfl_xor(s,8);  sq += __shfl_xor(sq,8);
    s += __shfl_xor(s,16); sq += __shfl_xor(sq,16);
    float mu = s * (1.f/128.f);
    float rstd = __builtin_amdgcn_rsqf(sq * (1.f/128.f) - mu*mu + 1e-5f);
    float y0 = (vv.x - mu)*rstd*lnw_s[c4+0] + lnb_s[c4+0];
    float y1 = (vv.y - mu)*rstd*lnw_s[c4+1] + lnb_s[c4+1];
    float y2 = (vv.z - mu)*rstd*lnw_s[c4+2] + lnb_s[c4+2];
    float y3 = (vv.w - mu)*rstd*lnw_s[c4+3] + lnb_s[c4+3];
    uint2 pk = make_uint2(cvtpk(y0,y1), cvtpk(y2,y3));
    ((uint2*)(znS + (size_t)(row0+64)*CH))[e*256 + t] = pk;
    int row = e*8 + rsub;
    *(uint2*)&zn[1][row][c4] = pk;
  }
  __syncthreads();   // zn ready

  const int lane = t & 63;
  const int w = t >> 6;
  const int lr = lane & 15;
  const int lg = lane >> 4;
  const int ow = w*32;
  const f32x4 zero4 = {0.f,0.f,0.f,0.f};

  #pragma unroll
  for (int tt=0; tt<2; tt++){
    const int r0t = row0 + tt*64;
    const size_t tile_off = (size_t)(r0t >> 9)*65536 + (size_t)((r0t >> 6) & 7)*8192;
    const float* msk = mask_s + tt*64;

    bf16x8 wl[8], wg[8];
    #pragma unroll
    for (int kk=0;kk<4;kk++)
      #pragma unroll
      for (int n=0;n<2;n++){
        int o = ow + n*16 + lr;
        wl[kk*2+n] = *(const bf16x8*)&wts[0*16384 + o*128 + kk*32 + lg*8];
        wg[kk*2+n] = *(const bf16x8*)&wts[1*16384 + o*128 + kk*32 + lg*8];
      }

    f32x4 acc1[4][2], acc2[4][2];
    #pragma unroll
    for (int mi=0;mi<4;mi++){ acc1[mi][0]=zero4; acc1[mi][1]=zero4; acc2[mi][0]=zero4; acc2[mi][1]=zero4; }
    #pragma unroll
    for (int kk=0;kk<4;kk++){
      bf16x8 a[4];
      #pragma unroll
      for (int mi=0;mi<4;mi++)
        a[mi] = *(const bf16x8*)&zn[tt][mi*16 + lr][kk*32 + lg*8];
      #pragma unroll
      for (int n=0;n<2;n++)
        #pragma unroll
        for (int mi=0;mi<4;mi++){
          acc1[mi][n] = __builtin_amdgcn_mfma_f32_16x16x32_bf16(a[mi], wl[kk*2+n], acc1[mi][n], 0,0,0);
          acc2[mi][n] = __builtin_amdgcn_mfma_f32_16x16x32_bf16(a[mi], wg[kk*2+n], acc2[mi][n], 0,0,0);
        }
    }
    bf16x8 wl2[8], wg2[8];
    #pragma unroll
    for (int kk=0;kk<4;kk++)
      #pragma unroll
      for (int n=0;n<2;n++){
        int o = ow + n*16 + lr;
        wl2[kk*2+n] = *(const bf16x8*)&wts[2*16384 + o*128 + kk*32 + lg*8];
        wg2[kk*2+n] = *(const bf16x8*)&wts[3*16384 + o*128 + kk*32 + lg*8];
      }

    #pragma unroll
    for (int n=0;n<2;n++){
      int ol = n*16 + lr;
      float bgv = b_lg[ow + ol];
      #pragma unroll
      for (int mi=0;mi<4;mi++){
        int r0 = mi*16 + lg*4;
        float u0 = acc1[mi][n][0] * sigm(acc2[mi][n][0] + bgv) * msk[r0+0];
        float u1 = acc1[mi][n][1] * sigm(acc2[mi][n][1] + bgv) * msk[r0+1];
        float u2 = acc1[mi][n][2] * sigm(acc2[mi][n][2] + bgv) * msk[r0+2];
        float u3 = acc1[mi][n][3] * sigm(acc2[mi][n][3] + bgv) * msk[r0+3];
        int chunk = (mi*2 + (lg>>1)) ^ (ol & 7);
        *(uint2*)&stg[w][ol*64 + (chunk<<3) + (lg&1)*4] = make_uint2(cvtpk(u0,u1), cvtpk(u2,u3));
      }
    }
    {
      int ol = lane >> 1, rh = lane & 1;
      uint4 pf[4];
      #pragma unroll
      for (int qq=0;qq<4;qq++){
        int m = (rh*4 + qq) ^ (ol & 7);
        pf[qq] = *(const uint4*)&stg[w][ol*64 + (m<<3)];
      }
      uint4* dst = (uint4*)(left_t + tile_off + (ow + ol)*64 + rh*32);
      #pragma unroll
      for (int qq=0;qq<4;qq++) dst[qq] = pf[qq];
    }

    #pragma unroll
    for (int mi=0;mi<4;mi++){ acc1[mi][0]=zero4; acc1[mi][1]=zero4; acc2[mi][0]=zero4; acc2[mi][1]=zero4; }
    #pragma unroll
    for (int kk=0;kk<4;kk++){
      bf16x8 a[4];
      #pragma unroll
      for (int mi=0;mi<4;mi++)
        a[mi] = *(const bf16x8*)&zn[tt][mi*16 + lr][kk*32 + lg*8];
      #pragma unroll
      for (int n=0;n<2;n++)
        #pragma unroll
        for (int mi=0;mi<4;mi++){
          acc1[mi][n] = __builtin_amdgcn_mfma_f32_16x16x32_bf16(a[mi], wl2[kk*2+n], acc1[mi][n], 0,0,0);
          acc2[mi][n] = __builtin_amdgcn_mfma_f32_16x16x32_bf16(a[mi], wg2[kk*2+n], acc2[mi][n], 0,0,0);
        }
    }
    #pragma unroll
    for (int n=0;n<2;n++){
      int ol = n*16 + lr;
      float bgv = b_rg[ow + ol];
      #pragma unroll
      for (int mi=0;mi<4;mi++){
        int r0 = mi*16 + lg*4;
        float u0 = acc1[mi][n][0] * sigm(acc2[mi][n][0] + bgv) * msk[r0+0];
        float u1 = acc1[mi][n][1] * sigm(acc2[mi][n][1] + bgv) * msk[r0+1];
        float u2 = acc1[mi][n][2] * sigm(acc2[mi][n][2] + bgv) * msk[r0+2];
        float u3 = acc1[mi][n][3] * sigm(acc2[mi][n][3] + bgv) * msk[r0+3];
        int chunk = (mi*2 + (lg>>1)) ^ (ol & 7);
        *(uint2*)&stg[w][ol*64 + (chunk<<3) + (lg&1)*4] = make_uint2(cvtpk(u0,u1), cvtpk(u2,u3));
      }
    }
    {
      int ol = lane >> 1, rh = lane & 1;
      uint4 pf[4];
      #pragma unroll
      for (int qq=0;qq<4;qq++){
        int m = (rh*4 + qq) ^ (ol & 7);
        pf[qq] = *(const uint4*)&stg[w][ol*64 + (m<<3)];
      }
      uint4* dst = (uint4*)(right_t + tile_off + (ow + ol)*64 + rh*32);
      #pragma unroll
      for (int qq=0;qq<4;qq++) dst[qq] = pf[qq];
    }
  }
}

// ------------- k2: per-channel 64x64x512 GEMM, gll staging + XCD swizzle --
__global__ __launch_bounds__(256) void k2_einsum(
    const u16* __restrict__ left_t, const u16* __restrict__ right_t,
    u16* __restrict__ upd16)
{
  __shared__ __align__(16) u16 lds_raw[16384];  // L bufs @0,4096 | R bufs @8192,12288
  const int t = threadIdx.x;
  const int lane = t & 63, w = t >> 6;
  const int wi = w >> 1, wj = w & 1;
  const int lr = lane & 15, lg = lane >> 4;

  // XCD-aware bijective swizzle (nwg = 8192, 8192 % 8 == 0)
  const int lin = (int)(blockIdx.x + (blockIdx.y << 3) + (blockIdx.z << 6));
  const int logical = ((lin & 7) << 10) + (lin >> 3);
  const int c  = logical >> 6;
  const int tl = logical & 63;
  const int i0 = (tl & 7) * 64, j0 = (tl >> 3) * 64;

  const int srow = t >> 3;   // 0..31
  const int ssl  = t & 7;

  f32x4 acc[2][2];
  const f32x4 zero4 = {0.f,0.f,0.f,0.f};
  acc[0][0]=zero4; acc[0][1]=zero4; acc[1][0]=zero4; acc[1][1]=zero4;

  auto stage = [&](int buf, int kt){
    #pragma unroll
    for (int q=0;q<2;q++){
      int row = q*32 + srow;
      int gs  = ssl ^ (row & 7);
      size_t gofs = (size_t)kt*8192 + (size_t)c*64 + gs*8;
      const u16* gl = &left_t [(size_t)(i0+row)*65536 + gofs];
      const u16* gr = &right_t[(size_t)(j0+row)*65536 + gofs];
      u16* dl = lds_raw +        buf*4096 + q*2048 + w*512 + lane*8;  // linear in lane
      u16* dr = lds_raw + 8192 + buf*4096 + q*2048 + w*512 + lane*8;
      gll16(gl, dl);
      gll16(gr, dr);
    }
  };

  stage(0, 0);
  __syncthreads();

  for (int kt=0; kt<8; kt++){
    const int buf = kt & 1;
    if (kt < 7) stage(buf^1, kt+1);
    #pragma unroll
    for (int kk=0;kk<2;kk++){
      bf16x8 af[2], bfr[2];
      #pragma unroll
      for (int mi=0;mi<2;mi++){
        int row = wi*32 + mi*16 + lr;
        af[mi] = *(const bf16x8*)&lds_raw[buf*4096 + row*64 + (((kk*4+lg) ^ (row&7)))*8];
      }
      #pragma unroll
      for (int nj=0;nj<2;nj++){
        int row = wj*32 + nj*16 + lr;
        bfr[nj] = *(const bf16x8*)&lds_raw[8192 + buf*4096 + row*64 + (((kk*4+lg) ^ (row&7)))*8];
      }
      #pragma unroll
      for (int mi=0;mi<2;mi++)
        #pragma unroll
        for (int nj=0;nj<2;nj++)
          acc[mi][nj] = __builtin_amdgcn_mfma_f32_16x16x32_bf16(af[mi], bfr[nj], acc[mi][nj], 0,0,0);
    }
    __syncthreads();
  }

  const float scale = 0.044194173824159216f;   // 1/sqrt(512)
  u16* st = lds_raw;
  #pragma unroll
  for (int mi=0;mi<2;mi++){
    #pragma unroll
    for (int nj=0;nj<2;nj++){
      int cj = wj*32 + nj*16 + lr;
      #pragma unroll
      for (int g2=0;g2<4;g2++){
        int ri = wi*32 + mi*16 + lg*4 + g2;
        st[ri*72 + cj] = f2bf(acc[mi][nj][g2] * scale);
      }
    }
  }
  __syncthreads();
  {
    int ri = t >> 2, q = t & 3;
    const uint4* src = (const uint4*)&st[ri*72 + q*16];
    uint4* dst = (uint4*)(upd16 + (size_t)c*NN + (size_t)(i0+ri)*NSEQ + j0 + q*16);
    dst[0] = src[0];
    dst[1] = src[1];
  }
}

// ------------- k3a: LN over c of upd16 [c][i*512+j] -> znu [row][c] bf16 --
__global__ __launch_bounds__(256) void k3a_ln(
    const u16* __restrict__ upd16, const float* __restrict__ onw,
    const float* __restrict__ onb, u16* __restrict__ znu)
{
  __shared__ float u[128*129];
  __shared__ float onw_s[128], onb_s[128];
  const int t = threadIdx.x;
  const int i = blockIdx.x;
  const int j0 = blockIdx.y * 128;

  if (t < 32)      ((float4*)onw_s)[t]    = ((const float4*)onw)[t];
  else if (t < 64) ((float4*)onb_s)[t-32] = ((const float4*)onb)[t-32];

  {
    int cr = t >> 1, h = t & 1;
    const uint4* src = (const uint4*)(upd16 + (size_t)cr*NN + (size_t)i*NSEQ + j0 + h*64);
    float* dst = &u[cr*129 + h*64];
    #pragma unroll
    for (int e=0;e<8;e++){
      uint4 v = src[e];
      const u16* hp = (const u16*)&v;
      #pragma unroll
      for (int p=0;p<8;p++) dst[e*8+p] = bf2f(hp[p]);
    }
  }
  __syncthreads();

  int j = t >> 1, h = t & 1;
  float s = 0.f, sq = 0.f;
  #pragma unroll
  for (int e=0;e<64;e++){
    float v = u[(h*64+e)*129 + j];
    s += v; sq += v*v;
  }
  s += __shfl_xor(s,1); sq += __shfl_xor(sq,1);
  float mu = s * (1.f/128.f);
  float rstd = __builtin_amdgcn_rsqf(sq * (1.f/128.f) - mu*mu + 1e-5f);

  uint32_t pk[32];
  #pragma unroll
  for (int e=0;e<64;e+=2){
    int c0 = h*64 + e;
    float v0 = (u[c0*129 + j]     - mu)*rstd*onw_s[c0]   + onb_s[c0];
    float v1 = (u[(c0+1)*129 + j] - mu)*rstd*onw_s[c0+1] + onb_s[c0+1];
    pk[e>>1] = cvtpk(v0, v1);
  }
  uint4* dst = (uint4*)(znu + ((size_t)i*NSEQ + j0 + j)*CH + h*64);
  #pragma unroll
  for (int e=0;e<8;e++) dst[e] = make_uint4(pk[e*4], pk[e*4+1], pk[e*4+2], pk[e*4+3]);
}

// ------------- k3b: out = (LN'd-update @ W_out^T) * sigm(zn@W_og^T+b) * mask
__global__ __launch_bounds__(256) void k3b_out(
    const u16* __restrict__ znu, const u16* __restrict__ znS,
    const float* __restrict__ pmask, const float* __restrict__ b_og,
    const u16* __restrict__ wts, float* __restrict__ out)
{
  __shared__ __align__(16) u16 uL[64][136];
  __shared__ __align__(16) u16 zL[64][136];
  __shared__ float mask_s[64];
  const int t = threadIdx.x;
  const int row0 = blockIdx.x * 64;

  #pragma unroll
  for (int k=0;k<4;k++){
    uint4 vu = *(const uint4*)(znu + (size_t)row0*CH + k*2048 + t*8);
    uint4 vz = *(const uint4*)(znS + (size_t)row0*CH + k*2048 + t*8);
    int r = k*16 + (t>>4), g = t & 15;
    *(uint4*)&uL[r][g*8] = vu;
    *(uint4*)&zL[r][g*8] = vz;
  }
  if (t < 16) ((float4*)mask_s)[t] = ((const float4*)(pmask + row0))[t];
  __syncthreads();

  const int lane = t & 63, w = t >> 6;
  const int lr = lane & 15, lg = lane >> 4;

  f32x4 acc_o[4][2], acc_g[4][2];
  const f32x4 zero4 = {0.f,0.f,0.f,0.f};
  #pragma unroll
  for (int mi=0;mi<4;mi++){ acc_o[mi][0]=zero4; acc_o[mi][1]=zero4; acc_g[mi][0]=zero4; acc_g[mi][1]=zero4; }

  #pragma unroll
  for (int kk=0;kk<4;kk++){
    bf16x8 a[4];
    #pragma unroll
    for (int mi=0;mi<4;mi++)
      a[mi] = *(const bf16x8*)&uL[mi*16 + lr][kk*32 + lg*8];
    #pragma unroll
    for (int n=0;n<2;n++){
      int o = w*32 + n*16 + lr;
      bf16x8 b = *(const bf16x8*)&wts[5*16384 + o*128 + kk*32 + lg*8];
      #pragma unroll
      for (int mi=0;mi<4;mi++)
        acc_o[mi][n] = __builtin_amdgcn_mfma_f32_16x16x32_bf16(a[mi], b, acc_o[mi][n], 0,0,0);
    }
  }
  #pragma unroll
  for (int kk=0;kk<4;kk++){
    bf16x8 a[4];
    #pragma unroll
    for (int mi=0;mi<4;mi++)
      a[mi] = *(const bf16x8*)&zL[mi*16 + lr][kk*32 + lg*8];
    #pragma unroll
    for (int n=0;n<2;n++){
      int o = w*32 + n*16 + lr;
      bf16x8 b = *(const bf16x8*)&wts[4*16384 + o*128 + kk*32 + lg*8];
      #pragma unroll
      for (int mi=0;mi<4;mi++)
        acc_g[mi][n] = __builtin_amdgcn_mfma_f32_16x16x32_bf16(a[mi], b, acc_g[mi][n], 0,0,0);
    }
  }

  #pragma unroll
  for (int n=0;n<2;n++){
    int o = w*32 + n*16 + lr;
    float bgv = b_og[o];
    #pragma unroll
    for (int mi=0;mi<4;mi++){
      #pragma unroll
      for (int g2=0;g2<4;g2++){
        int r = mi*16 + lg*4 + g2;
        float val = acc_o[mi][n][g2] * sigm(acc_g[mi][n][g2] + bgv) * mask_s[r];
        out[(size_t)(row0 + r)*CH + o] = val;
      }
    }
  }
}

// ------------- k3bf: FUSED LN(update) + dual GEMM + gate + store ----------
__global__ __launch_bounds__(256) void k3bf_out(
    const u16* __restrict__ upd16, const u16* __restrict__ znS,
    const float* __restrict__ pmask, const float* __restrict__ onw,
    const float* __restrict__ onb, const float* __restrict__ b_og,
    const u16* __restrict__ wts, float* __restrict__ out)
{
  __shared__ __align__(16) u16 zn[64][136];   // LN'd update (GEMM1 A operand)
  __shared__ __align__(16) u16 zL[64][136];   // znS tile   (GEMM2 A operand)
  __shared__ float ps[4][64], pq[4][64];
  __shared__ float st2[64][2];
  __shared__ float onw_s[128], onb_s[128], mask_s[64];

  const int t = threadIdx.x;
  const int row0 = blockIdx.x * 64;
  const int j  = t & 63;
  const int h2 = t >> 6;

  uint4 vz[4];
  #pragma unroll
  for (int k=0;k<4;k++) vz[k] = *(const uint4*)(znS + (size_t)row0*CH + k*2048 + t*8);

  float v[32];
  #pragma unroll
  for (int e=0;e<32;e++){
    int c = h2*32 + e;
    v[e] = bf2f(upd16[(size_t)c*NN + row0 + j]);
  }

  if (t < 32)      ((float4*)onw_s)[t]     = ((const float4*)onw)[t];
  else if (t < 64) ((float4*)onb_s)[t-32]  = ((const float4*)onb)[t-32];
  else if (t < 80) ((float4*)mask_s)[t-64] = ((const float4*)(pmask + row0))[t-64];

  #pragma unroll
  for (int k=0;k<4;k++){
    int r = k*16 + (t>>4), g = t & 15;
    *(uint4*)&zL[r][g*8] = vz[k];
  }

  {
    float s = 0.f, sq = 0.f;
    #pragma unroll
    for (int e=0;e<32;e++){ s += v[e]; sq += v[e]*v[e]; }
    ps[h2][j] = s; pq[h2][j] = sq;
  }
  __syncthreads();
  if (t < 64){
    float s  = ps[0][t]+ps[1][t]+ps[2][t]+ps[3][t];
    float sq = pq[0][t]+pq[1][t]+pq[2][t]+pq[3][t];
    float mu = s * (1.f/128.f);
    float rstd = __builtin_amdgcn_rsqf(sq * (1.f/128.f) - mu*mu + 1e-5f);
    st2[t][0] = mu; st2[t][1] = rstd;
  }
  __syncthreads();

  {
    float mu = st2[j][0], rstd = st2[j][1];
    #pragma unroll
    for (int q=0;q<4;q++){
      uint32_t pk[4];
      #pragma unroll
      for (int p=0;p<4;p++){
        int e = q*8 + p*2;
        int c = h2*32 + e;
        float y0 = (v[e]   - mu)*rstd*onw_s[c]   + onb_s[c];
        float y1 = (v[e+1] - mu)*rstd*onw_s[c+1] + onb_s[c+1];
        pk[p] = cvtpk(y0, y1);
      }
      *(uint4*)&zn[j][h2*32 + q*8] = make_uint4(pk[0],pk[1],pk[2],pk[3]);
    }
  }
  __syncthreads();

  const int lane = t & 63, w = t >> 6;
  const int lr = lane & 15, lg = lane >> 4;

  f32x4 acc_o[4][2], acc_g[4][2];
  const f32x4 zero4 = {0.f,0.f,0.f,0.f};
  #pragma unroll
  for (int mi=0;mi<4;mi++){ acc_o[mi][0]=zero4; acc_o[mi][1]=zero4; acc_g[mi][0]=zero4; acc_g[mi][1]=zero4; }

  #pragma unroll
  for (int kk=0;kk<4;kk++){
    bf16x8 a[4];
    #pragma unroll
    for (int mi=0;mi<4;mi++)
      a[mi] = *(const bf16x8*)&zn[mi*16 + lr][kk*32 + lg*8];
    #pragma unroll
    for (int n=0;n<2;n++){
      int o = w*32 + n*16 + lr;
      bf16x8 b = *(const bf16x8*)&wts[5*16384 + o*128 + kk*32 + lg*8];
      #pragma unroll
      for (int mi=0;mi<4;mi++)
        acc_o[mi][n] = __builtin_amdgcn_mfma_f32_16x16x32_bf16(a[mi], b, acc_o[mi][n], 0,0,0);
    }
  }
  #pragma unroll
  for (int kk=0;kk<4;kk++){
    bf16x8 a[4];
    #pragma unroll
    for (int mi=0;mi<4;mi++)
      a[mi] = *(const bf16x8*)&zL[mi*16 + lr][kk*32 + lg*8];
    #pragma unroll
    for (int n=0;n<2;n++){
      int o = w*32 + n*16 + lr;
      bf16x8 b = *(const bf16x8*)&wts[4*16384 + o*128 + kk*32 + lg*8];
      #pragma unroll
      for (int mi=0;mi<4;mi++)
        acc_g[mi][n] = __builtin_amdgcn_mfma_f32_16x16x32_bf16(a[mi], b, acc_g[mi][n], 0,0,0);
    }
  }

  #pragma unroll
  for (int n=0;n<2;n++){
    int o = w*32 + n*16 + lr;
    float bgv = b_og[o];
    #pragma unroll
    for (int mi=0;mi<4;mi++){
      #pragma unroll
      for (int g2=0;g2<4;g2++){
        int r = mi*16 + lg*4 + g2;
        float val = acc_o[mi][n][g2] * sigm(acc_g[mi][n][g2] + bgv) * mask_s[r];
        out[(size_t)(row0 + r)*CH + o] = val;
      }
    }
  }
}

// --------------------------- launcher ------------------------------------
extern "C" void kernel_launch(void* const* d_in, const int* in_sizes, int n_in,
                              void* d_out, int out_size, void* d_ws, size_t ws_size,
                              hipStream_t stream)
{
  const float* z       = (const float*)d_in[0];
  const float* pmask   = (const float*)d_in[1];
  const float* lnw     = (const float*)d_in[2];
  const float* lnb     = (const float*)d_in[3];
  const float* W_left  = (const float*)d_in[4];
  const float* W_right = (const float*)d_in[5];
  const float* W_lgate = (const float*)d_in[6];
  const float* b_lgate = (const float*)d_in[7];
  const float* W_rgate = (const float*)d_in[8];
  const float* b_rgate = (const float*)d_in[9];
  const float* onw     = (const float*)d_in[10];
  const float* onb     = (const float*)d_in[11];
  const float* W_out   = (const float*)d_in[12];
  const float* W_ogate = (const float*)d_in[13];
  const float* b_ogate = (const float*)d_in[14];

  const size_t SLOT = 67108864;   // 64 MiB
  uint8_t* ws = (uint8_t*)d_ws;
  u16* left_t  = (u16*)(ws);
  u16* right_t = (u16*)(ws + SLOT);
  u16* znS     = (u16*)(ws + 2*SLOT);

  const bool fused = (ws_size >= 4*SLOT + 196608);
  u16* wts   = (u16*)(ws + (fused ? 4*SLOT : 3*SLOT));
  u16* upd16 = fused ? (u16*)(ws + 3*SLOT) : (u16*)d_out;

  k0_cvt<<<96, 256, 0, stream>>>(W_left, W_lgate, W_right, W_rgate, W_ogate, W_out, wts);
  k1ab_proj<<<2048, 256, 0, stream>>>(z, pmask, lnw, lnb, b_lgate, b_rgate, wts,
                                      znS, left_t, right_t);
  k2_einsum<<<dim3(8,8,128), 256, 0, stream>>>(left_t, right_t, upd16);

  if (fused){
    k3bf_out<<<4096, 256, 0, stream>>>(upd16, znS, pmask, onw, onb, b_ogate, wts,
                                       (float*)d_out);
  } else {
    k3a_ln<<<dim3(512,4), 256, 0, stream>>>(upd16, onw, onb, left_t /*znu*/);
    k3b_out<<<4096, 256, 0, stream>>>(left_t /*znu*/, znS, pmask, b_ogate, wts,
                                      (float*)d_out);
  }
}

// Round 13
// 294.563 us; speedup vs baseline: 1.4234x; 1.0064x over previous
//
#include <hip/hip_runtime.h>
#include <stdint.h>

#define NSEQ 512
#define CH   128
#define NN   (NSEQ*NSEQ)   // 262144

typedef unsigned short u16;
typedef __attribute__((ext_vector_type(8))) short bf16x8;  // 8 bf16 = 4 VGPRs
typedef __attribute__((ext_vector_type(4))) float f32x4;

__device__ __forceinline__ u16 f2bf(float x){          // RNE
  uint32_t u = __float_as_uint(x);
  u += 0x7fffu + ((u >> 16) & 1u);
  return (u16)(u >> 16);
}
__device__ __forceinline__ float bf2f(u16 h){
  return __uint_as_float(((uint32_t)h) << 16);
}
__device__ __forceinline__ uint32_t cvtpk(float lo, float hi){  // bf16(lo)|bf16(hi)<<16
  uint32_t r;
  asm volatile("v_cvt_pk_bf16_f32 %0, %1, %2" : "=v"(r) : "v"(lo), "v"(hi));
  return r;
}
__device__ __forceinline__ float sigm(float x){
  return __builtin_amdgcn_rcpf(1.0f + __expf(-x));
}
__device__ __forceinline__ void gll16(const void* g, void* l){  // 16B global->LDS DMA
  __builtin_amdgcn_global_load_lds((const __attribute__((address_space(1))) void*)g,
                                   (__attribute__((address_space(3))) void*)l, 16, 0, 0);
}

// left/right tensor layout: [i (512)][kblk (8)][c (128)][kin (64)] u16
// offset = i*65536 + kblk*8192 + c*64 + kin   (flat row n = i*512 + kblk*64 + kin)

// ------------- k0: cast 6 weight matrices fp32 -> bf16 -------------
// slot order: 0=W_left 1=W_lgate 2=W_right 3=W_rgate 4=W_ogate 5=W_out
__global__ void k0_cvt(const float* __restrict__ w0, const float* __restrict__ w1,
                       const float* __restrict__ w2, const float* __restrict__ w3,
                       const float* __restrict__ w4, const float* __restrict__ w5,
                       u16* __restrict__ out)
{
  int mat = blockIdx.x >> 4;
  int blk = blockIdx.x & 15;
  const float* src = (mat==0)?w0:(mat==1)?w1:(mat==2)?w2:(mat==3)?w3:(mat==4)?w4:w5;
  int idx = (blk*256 + (int)threadIdx.x) * 4;
  float4 v = *(const float4*)(src + idx);
  uint2 pk;
  pk.x = cvtpk(v.x, v.y);
  pk.y = cvtpk(v.z, v.w);
  *(uint2*)(out + mat*16384 + idx) = pk;
}

// ------------- k1ab: FUSED LN(z) + 2 gated projections, 128 rows/block ----
__global__ __launch_bounds__(256) void k1ab_proj(
    const float* __restrict__ z, const float* __restrict__ pmask,
    const float* __restrict__ lnw, const float* __restrict__ lnb,
    const float* __restrict__ b_lg, const float* __restrict__ b_rg,
    const u16* __restrict__ wts, u16* __restrict__ znS,
    u16* __restrict__ left_t, u16* __restrict__ right_t)
{
  __shared__ __align__(16) u16 zn[2][64][136];  // 34 KB
  __shared__ __align__(16) u16 stg[4][2048];    // 16 KB (per-wave stage)
  __shared__ float lnw_s[128], lnb_s[128], mask_s[128];
  const int t = threadIdx.x;
  const int row0 = blockIdx.x * 128;

  if (t < 32)      ((float4*)lnw_s)[t]     = ((const float4*)lnw)[t];
  else if (t < 64) ((float4*)lnb_s)[t-32]  = ((const float4*)lnb)[t-32];
  else if (t < 96) ((float4*)mask_s)[t-64] = ((const float4*)(pmask + row0))[t-64];

  // lane-contiguous z loads: tile0 = float4 idx e*256+t, tile1 = +2048
  const float4* zt = (const float4*)(z + (size_t)row0 * CH);
  float4 v0[8], v1[8];
  #pragma unroll
  for (int e=0;e<8;e++) v0[e] = zt[e*256 + t];
  #pragma unroll
  for (int e=0;e<8;e++) v1[e] = zt[2048 + e*256 + t];
  __syncthreads();   // lnw_s/lnb_s/mask_s visible

  const int rsub = t >> 5;          // row sub-index within step
  const int c4   = (t & 31) * 4;    // this thread's 4 channels

  // ----- LN tile 0: per step e, row = e*8+rsub; stats over 32-lane half -----
  #pragma unroll
  for (int e=0;e<8;e++){
    float4 vv = v0[e];
    float s  = vv.x + vv.y + vv.z + vv.w;
    float sq = vv.x*vv.x + vv.y*vv.y + vv.z*vv.z + vv.w*vv.w;
    s += __shfl_xor(s,1);  sq += __shfl_xor(sq,1);
    s += __shfl_xor(s,2);  sq += __shfl_xor(sq,2);
    s += __shfl_xor(s,4);  sq += __shfl_xor(sq,4);
    s += __shfl_xor(s,8);  sq += __shfl_xor(sq,8);
    s += __shfl_xor(s,16); sq += __shfl_xor(sq,16);
    float mu = s * (1.f/128.f);
    float rstd = __builtin_amdgcn_rsqf(sq * (1.f/128.f) - mu*mu + 1e-5f);
    float y0 = (vv.x - mu)*rstd*lnw_s[c4+0] + lnb_s[c4+0];
    float y1 = (vv.y - mu)*rstd*lnw_s[c4+1] + lnb_s[c4+1];
    float y2 = (vv.z - mu)*rstd*lnw_s[c4+2] + lnb_s[c4+2];
    float y3 = (vv.w - mu)*rstd*lnw_s[c4+3] + lnb_s[c4+3];
    uint2 pk = make_uint2(cvtpk(y0,y1), cvtpk(y2,y3));
    ((uint2*)(znS + (size_t)row0*CH))[e*256 + t] = pk;   // coalesced 8B/lane
    int row = e*8 + rsub;
    *(uint2*)&zn[0][row][c4] = pk;
  }
  // ----- LN tile 1 -----
  #pragma unroll
  for (int e=0;e<8;e++){
    float4 vv = v1[e];
    float s  = vv.x + vv.y + vv.z + vv.w;
    float sq = vv.x*vv.x + vv.y*vv.y + vv.z*vv.z + vv.w*vv.w;
    s += __shfl_xor(s,1);  sq += __shfl_xor(sq,1);
    s += __shfl_xor(s,2);  sq += __shfl_xor(sq,2);
    s += __shfl_xor(s,4);  sq += __shfl_xor(sq,4);
    s += __shfl_xor(s,8);  sq += __shfl_xor(sq,8);
    s += __shfl_xor(s,16); sq += __shfl_xor(sq,16);
    float mu = s * (1.f/128.f);
    float rstd = __builtin_amdgcn_rsqf(sq * (1.f/128.f) - mu*mu + 1e-5f);
    float y0 = (vv.x - mu)*rstd*lnw_s[c4+0] + lnb_s[c4+0];
    float y1 = (vv.y - mu)*rstd*lnw_s[c4+1] + lnb_s[c4+1];
    float y2 = (vv.z - mu)*rstd*lnw_s[c4+2] + lnb_s[c4+2];
    float y3 = (vv.w - mu)*rstd*lnw_s[c4+3] + lnb_s[c4+3];
    uint2 pk = make_uint2(cvtpk(y0,y1), cvtpk(y2,y3));
    ((uint2*)(znS + (size_t)(row0+64)*CH))[e*256 + t] = pk;
    int row = e*8 + rsub;
    *(uint2*)&zn[1][row][c4] = pk;
  }
  __syncthreads();   // zn ready

  const int lane = t & 63;
  const int w = t >> 6;
  const int lr = lane & 15;
  const int lg = lane >> 4;
  const int ow = w*32;
  const f32x4 zero4 = {0.f,0.f,0.f,0.f};

  #pragma unroll
  for (int tt=0; tt<2; tt++){
    const int r0t = row0 + tt*64;
    const size_t tile_off = (size_t)(r0t >> 9)*65536 + (size_t)((r0t >> 6) & 7)*8192;
    const float* msk = mask_s + tt*64;

    bf16x8 wl[8], wg[8];
    #pragma unroll
    for (int kk=0;kk<4;kk++)
      #pragma unroll
      for (int n=0;n<2;n++){
        int o = ow + n*16 + lr;
        wl[kk*2+n] = *(const bf16x8*)&wts[0*16384 + o*128 + kk*32 + lg*8];
        wg[kk*2+n] = *(const bf16x8*)&wts[1*16384 + o*128 + kk*32 + lg*8];
      }

    f32x4 acc1[4][2], acc2[4][2];
    #pragma unroll
    for (int mi=0;mi<4;mi++){ acc1[mi][0]=zero4; acc1[mi][1]=zero4; acc2[mi][0]=zero4; acc2[mi][1]=zero4; }
    #pragma unroll
    for (int kk=0;kk<4;kk++){
      bf16x8 a[4];
      #pragma unroll
      for (int mi=0;mi<4;mi++)
        a[mi] = *(const bf16x8*)&zn[tt][mi*16 + lr][kk*32 + lg*8];
      #pragma unroll
      for (int n=0;n<2;n++)
        #pragma unroll
        for (int mi=0;mi<4;mi++){
          acc1[mi][n] = __builtin_amdgcn_mfma_f32_16x16x32_bf16(a[mi], wl[kk*2+n], acc1[mi][n], 0,0,0);
          acc2[mi][n] = __builtin_amdgcn_mfma_f32_16x16x32_bf16(a[mi], wg[kk*2+n], acc2[mi][n], 0,0,0);
        }
    }
    bf16x8 wl2[8], wg2[8];
    #pragma unroll
    for (int kk=0;kk<4;kk++)
      #pragma unroll
      for (int n=0;n<2;n++){
        int o = ow + n*16 + lr;
        wl2[kk*2+n] = *(const bf16x8*)&wts[2*16384 + o*128 + kk*32 + lg*8];
        wg2[kk*2+n] = *(const bf16x8*)&wts[3*16384 + o*128 + kk*32 + lg*8];
      }

    #pragma unroll
    for (int n=0;n<2;n++){
      int ol = n*16 + lr;
      float bgv = b_lg[ow + ol];
      #pragma unroll
      for (int mi=0;mi<4;mi++){
        int r0 = mi*16 + lg*4;
        float u0 = acc1[mi][n][0] * sigm(acc2[mi][n][0] + bgv) * msk[r0+0];
        float u1 = acc1[mi][n][1] * sigm(acc2[mi][n][1] + bgv) * msk[r0+1];
        float u2 = acc1[mi][n][2] * sigm(acc2[mi][n][2] + bgv) * msk[r0+2];
        float u3 = acc1[mi][n][3] * sigm(acc2[mi][n][3] + bgv) * msk[r0+3];
        int chunk = (mi*2 + (lg>>1)) ^ (ol & 7);
        *(uint2*)&stg[w][ol*64 + (chunk<<3) + (lg&1)*4] = make_uint2(cvtpk(u0,u1), cvtpk(u2,u3));
      }
    }
    {
      int ol = lane >> 1, rh = lane & 1;
      uint4 pf[4];
      #pragma unroll
      for (int qq=0;qq<4;qq++){
        int m = (rh*4 + qq) ^ (ol & 7);
        pf[qq] = *(const uint4*)&stg[w][ol*64 + (m<<3)];
      }
      uint4* dst = (uint4*)(left_t + tile_off + (ow + ol)*64 + rh*32);
      #pragma unroll
      for (int qq=0;qq<4;qq++) dst[qq] = pf[qq];
    }

    #pragma unroll
    for (int mi=0;mi<4;mi++){ acc1[mi][0]=zero4; acc1[mi][1]=zero4; acc2[mi][0]=zero4; acc2[mi][1]=zero4; }
    #pragma unroll
    for (int kk=0;kk<4;kk++){
      bf16x8 a[4];
      #pragma unroll
      for (int mi=0;mi<4;mi++)
        a[mi] = *(const bf16x8*)&zn[tt][mi*16 + lr][kk*32 + lg*8];
      #pragma unroll
      for (int n=0;n<2;n++)
        #pragma unroll
        for (int mi=0;mi<4;mi++){
          acc1[mi][n] = __builtin_amdgcn_mfma_f32_16x16x32_bf16(a[mi], wl2[kk*2+n], acc1[mi][n], 0,0,0);
          acc2[mi][n] = __builtin_amdgcn_mfma_f32_16x16x32_bf16(a[mi], wg2[kk*2+n], acc2[mi][n], 0,0,0);
        }
    }
    #pragma unroll
    for (int n=0;n<2;n++){
      int ol = n*16 + lr;
      float bgv = b_rg[ow + ol];
      #pragma unroll
      for (int mi=0;mi<4;mi++){
        int r0 = mi*16 + lg*4;
        float u0 = acc1[mi][n][0] * sigm(acc2[mi][n][0] + bgv) * msk[r0+0];
        float u1 = acc1[mi][n][1] * sigm(acc2[mi][n][1] + bgv) * msk[r0+1];
        float u2 = acc1[mi][n][2] * sigm(acc2[mi][n][2] + bgv) * msk[r0+2];
        float u3 = acc1[mi][n][3] * sigm(acc2[mi][n][3] + bgv) * msk[r0+3];
        int chunk = (mi*2 + (lg>>1)) ^ (ol & 7);
        *(uint2*)&stg[w][ol*64 + (chunk<<3) + (lg&1)*4] = make_uint2(cvtpk(u0,u1), cvtpk(u2,u3));
      }
    }
    {
      int ol = lane >> 1, rh = lane & 1;
      uint4 pf[4];
      #pragma unroll
      for (int qq=0;qq<4;qq++){
        int m = (rh*4 + qq) ^ (ol & 7);
        pf[qq] = *(const uint4*)&stg[w][ol*64 + (m<<3)];
      }
      uint4* dst = (uint4*)(right_t + tile_off + (ow + ol)*64 + rh*32);
      #pragma unroll
      for (int qq=0;qq<4;qq++) dst[qq] = pf[qq];
    }
  }
}

// ------------- k2: per-channel 128x128x512 GEMM, BK=32, gll + XCD swizzle -
// 32 KB LDS (same as 64^2 version): A dbuf [2][128][32] @0, B @8192 (u16).
// L2 traffic halves vs 64^2 (4MB/c), 16 MFMA per barrier (was 8).
// Bank swizzle: slot' = slot ^ ((row ^ row>>2) & 3) -> 2-way max (free).
// gll16: linear LDS dest (chunk d = q*256+t), inverse-swizzled GLOBAL source.
__global__ __launch_bounds__(256) void k2_einsum(
    const u16* __restrict__ left_t, const u16* __restrict__ right_t,
    u16* __restrict__ upd16)
{
  __shared__ __align__(16) u16 lds_raw[16384];  // 32 KB
  const int t = threadIdx.x;
  const int lane = t & 63, w = t >> 6;
  const int wi = w >> 1, wj = w & 1;            // wave quadrant: 64x64 out
  const int lr = lane & 15, lg = lane >> 4;

  // XCD-aware bijective swizzle (nwg = 2048, 2048 % 8 == 0; 256/XCD chunk)
  const int lin = (int)(blockIdx.x + (blockIdx.y << 2) + (blockIdx.z << 4));
  const int logical = ((lin & 7) << 8) + (lin >> 3);
  const int c  = logical >> 4;                  // 16 tiles per channel
  const int tl = logical & 15;
  const int i0 = (tl & 3) * 128, j0 = (tl >> 2) * 128;

  f32x4 acc[4][4];
  const f32x4 zero4 = {0.f,0.f,0.f,0.f};
  #pragma unroll
  for (int mi=0;mi<4;mi++)
    #pragma unroll
    for (int nj=0;nj<4;nj++) acc[mi][nj] = zero4;

  // stage k-step kt (32 k's): chunk d=(row=d>>2, sl=d&3); 2 chunks/thr/tensor
  auto stage = [&](int buf, int kt){
    size_t kb = (size_t)(kt >> 1)*8192 + (size_t)c*64 + (size_t)((kt & 1)*32);
    #pragma unroll
    for (int q=0;q<2;q++){
      int d   = q*256 + t;
      int row = d >> 2, sl = d & 3;
      int gs  = sl ^ ((row ^ (row >> 2)) & 3);
      const u16* gl = &left_t [(size_t)(i0+row)*65536 + kb + gs*8];
      const u16* gr = &right_t[(size_t)(j0+row)*65536 + kb + gs*8];
      gll16(gl, lds_raw +        buf*4096 + d*8);   // dest linear in lane
      gll16(gr, lds_raw + 8192 + buf*4096 + d*8);
    }
  };

  stage(0, 0);
  __syncthreads();

  for (int kt=0; kt<16; kt++){
    const int buf = kt & 1;
    if (kt < 15) stage(buf^1, kt+1);
    bf16x8 af[4], bfr[4];
    #pragma unroll
    for (int mi=0;mi<4;mi++){
      int row = wi*64 + mi*16 + lr;
      int sw  = (row ^ (row >> 2)) & 3;
      af[mi] = *(const bf16x8*)&lds_raw[buf*4096 + row*32 + ((lg ^ sw)*8)];
    }
    #pragma unroll
    for (int nj=0;nj<4;nj++){
      int row = wj*64 + nj*16 + lr;
      int sw  = (row ^ (row >> 2)) & 3;
      bfr[nj] = *(const bf16x8*)&lds_raw[8192 + buf*4096 + row*32 + ((lg ^ sw)*8)];
    }
    #pragma unroll
    for (int mi=0;mi<4;mi++)
      #pragma unroll
      for (int nj=0;nj<4;nj++)
        acc[mi][nj] = __builtin_amdgcn_mfma_f32_16x16x32_bf16(af[mi], bfr[nj], acc[mi][nj], 0,0,0);
    __syncthreads();
  }

  // epilogue: two 64-row half-passes through st[64][136] (17.4 KB)
  const float scale = 0.044194173824159216f;   // 1/sqrt(512)
  u16* st = lds_raw;
  #pragma unroll
  for (int half=0; half<2; half++){
    if (wi == half){
      #pragma unroll
      for (int mi=0;mi<4;mi++){
        #pragma unroll
        for (int nj=0;nj<4;nj++){
          int cj = wj*64 + nj*16 + lr;
          #pragma unroll
          for (int g2=0;g2<4;g2++){
            int rl = mi*16 + lg*4 + g2;     // 0..63 within half
            st[rl*136 + cj] = f2bf(acc[mi][nj][g2] * scale);
          }
        }
      }
    }
    __syncthreads();
    {
      int rl = t >> 2, qq = t & 3;
      const uint4* src = (const uint4*)&st[rl*136 + qq*32];
      uint4* dst = (uint4*)(upd16 + (size_t)c*NN
                            + (size_t)(i0 + half*64 + rl)*NSEQ + j0 + qq*32);
      dst[0] = src[0]; dst[1] = src[1]; dst[2] = src[2]; dst[3] = src[3];
    }
    __syncthreads();
  }
}

// ------------- k3a: LN over c of upd16 [c][i*512+j] -> znu [row][c] bf16 --
__global__ __launch_bounds__(256) void k3a_ln(
    const u16* __restrict__ upd16, const float* __restrict__ onw,
    const float* __restrict__ onb, u16* __restrict__ znu)
{
  __shared__ float u[128*129];
  __shared__ float onw_s[128], onb_s[128];
  const int t = threadIdx.x;
  const int i = blockIdx.x;
  const int j0 = blockIdx.y * 128;

  if (t < 32)      ((float4*)onw_s)[t]    = ((const float4*)onw)[t];
  else if (t < 64) ((float4*)onb_s)[t-32] = ((const float4*)onb)[t-32];

  {
    int cr = t >> 1, h = t & 1;
    const uint4* src = (const uint4*)(upd16 + (size_t)cr*NN + (size_t)i*NSEQ + j0 + h*64);
    float* dst = &u[cr*129 + h*64];
    #pragma unroll
    for (int e=0;e<8;e++){
      uint4 v = src[e];
      const u16* hp = (const u16*)&v;
      #pragma unroll
      for (int p=0;p<8;p++) dst[e*8+p] = bf2f(hp[p]);
    }
  }
  __syncthreads();

  int j = t >> 1, h = t & 1;
  float s = 0.f, sq = 0.f;
  #pragma unroll
  for (int e=0;e<64;e++){
    float v = u[(h*64+e)*129 + j];
    s += v; sq += v*v;
  }
  s += __shfl_xor(s,1); sq += __shfl_xor(sq,1);
  float mu = s * (1.f/128.f);
  float rstd = __builtin_amdgcn_rsqf(sq * (1.f/128.f) - mu*mu + 1e-5f);

  uint32_t pk[32];
  #pragma unroll
  for (int e=0;e<64;e+=2){
    int c0 = h*64 + e;
    float v0 = (u[c0*129 + j]     - mu)*rstd*onw_s[c0]   + onb_s[c0];
    float v1 = (u[(c0+1)*129 + j] - mu)*rstd*onw_s[c0+1] + onb_s[c0+1];
    pk[e>>1] = cvtpk(v0, v1);
  }
  uint4* dst = (uint4*)(znu + ((size_t)i*NSEQ + j0 + j)*CH + h*64);
  #pragma unroll
  for (int e=0;e<8;e++) dst[e] = make_uint4(pk[e*4], pk[e*4+1], pk[e*4+2], pk[e*4+3]);
}

// ------------- k3b: out = (LN'd-update @ W_out^T) * sigm(zn@W_og^T+b) * mask
__global__ __launch_bounds__(256) void k3b_out(
    const u16* __restrict__ znu, const u16* __restrict__ znS,
    const float* __restrict__ pmask, const float* __restrict__ b_og,
    const u16* __restrict__ wts, float* __restrict__ out)
{
  __shared__ __align__(16) u16 uL[64][136];
  __shared__ __align__(16) u16 zL[64][136];
  __shared__ float mask_s[64];
  const int t = threadIdx.x;
  const int row0 = blockIdx.x * 64;

  #pragma unroll
  for (int k=0;k<4;k++){
    uint4 vu = *(const uint4*)(znu + (size_t)row0*CH + k*2048 + t*8);
    uint4 vz = *(const uint4*)(znS + (size_t)row0*CH + k*2048 + t*8);
    int r = k*16 + (t>>4), g = t & 15;
    *(uint4*)&uL[r][g*8] = vu;
    *(uint4*)&zL[r][g*8] = vz;
  }
  if (t < 16) ((float4*)mask_s)[t] = ((const float4*)(pmask + row0))[t];
  __syncthreads();

  const int lane = t & 63, w = t >> 6;
  const int lr = lane & 15, lg = lane >> 4;

  f32x4 acc_o[4][2], acc_g[4][2];
  const f32x4 zero4 = {0.f,0.f,0.f,0.f};
  #pragma unroll
  for (int mi=0;mi<4;mi++){ acc_o[mi][0]=zero4; acc_o[mi][1]=zero4; acc_g[mi][0]=zero4; acc_g[mi][1]=zero4; }

  #pragma unroll
  for (int kk=0;kk<4;kk++){
    bf16x8 a[4];
    #pragma unroll
    for (int mi=0;mi<4;mi++)
      a[mi] = *(const bf16x8*)&uL[mi*16 + lr][kk*32 + lg*8];
    #pragma unroll
    for (int n=0;n<2;n++){
      int o = w*32 + n*16 + lr;
      bf16x8 b = *(const bf16x8*)&wts[5*16384 + o*128 + kk*32 + lg*8];
      #pragma unroll
      for (int mi=0;mi<4;mi++)
        acc_o[mi][n] = __builtin_amdgcn_mfma_f32_16x16x32_bf16(a[mi], b, acc_o[mi][n], 0,0,0);
    }
  }
  #pragma unroll
  for (int kk=0;kk<4;kk++){
    bf16x8 a[4];
    #pragma unroll
    for (int mi=0;mi<4;mi++)
      a[mi] = *(const bf16x8*)&zL[mi*16 + lr][kk*32 + lg*8];
    #pragma unroll
    for (int n=0;n<2;n++){
      int o = w*32 + n*16 + lr;
      bf16x8 b = *(const bf16x8*)&wts[4*16384 + o*128 + kk*32 + lg*8];
      #pragma unroll
      for (int mi=0;mi<4;mi++)
        acc_g[mi][n] = __builtin_amdgcn_mfma_f32_16x16x32_bf16(a[mi], b, acc_g[mi][n], 0,0,0);
    }
  }

  #pragma unroll
  for (int n=0;n<2;n++){
    int o = w*32 + n*16 + lr;
    float bgv = b_og[o];
    #pragma unroll
    for (int mi=0;mi<4;mi++){
      #pragma unroll
      for (int g2=0;g2<4;g2++){
        int r = mi*16 + lg*4 + g2;
        float val = acc_o[mi][n][g2] * sigm(acc_g[mi][n][g2] + bgv) * mask_s[r];
        out[(size_t)(row0 + r)*CH + o] = val;
      }
    }
  }
}

// ------------- k3bf: FUSED LN(update) + dual GEMM + gate + store ----------
__global__ __launch_bounds__(256) void k3bf_out(
    const u16* __restrict__ upd16, const u16* __restrict__ znS,
    const float* __restrict__ pmask, const float* __restrict__ onw,
    const float* __restrict__ onb, const float* __restrict__ b_og,
    const u16* __restrict__ wts, float* __restrict__ out)
{
  __shared__ __align__(16) u16 zn[64][136];   // LN'd update (GEMM1 A operand)
  __shared__ __align__(16) u16 zL[64][136];   // znS tile   (GEMM2 A operand)
  __shared__ float ps[4][64], pq[4][64];
  __shared__ float st2[64][2];
  __shared__ float onw_s[128], onb_s[128], mask_s[64];

  const int t = threadIdx.x;
  const int row0 = blockIdx.x * 64;
  const int j  = t & 63;
  const int h2 = t >> 6;

  uint4 vz[4];
  #pragma unroll
  for (int k=0;k<4;k++) vz[k] = *(const uint4*)(znS + (size_t)row0*CH + k*2048 + t*8);

  float v[32];
  #pragma unroll
  for (int e=0;e<32;e++){
    int c = h2*32 + e;
    v[e] = bf2f(upd16[(size_t)c*NN + row0 + j]);
  }

  if (t < 32)      ((float4*)onw_s)[t]     = ((const float4*)onw)[t];
  else if (t < 64) ((float4*)onb_s)[t-32]  = ((const float4*)onb)[t-32];
  else if (t < 80) ((float4*)mask_s)[t-64] = ((const float4*)(pmask + row0))[t-64];

  #pragma unroll
  for (int k=0;k<4;k++){
    int r = k*16 + (t>>4), g = t & 15;
    *(uint4*)&zL[r][g*8] = vz[k];
  }

  {
    float s = 0.f, sq = 0.f;
    #pragma unroll
    for (int e=0;e<32;e++){ s += v[e]; sq += v[e]*v[e]; }
    ps[h2][j] = s; pq[h2][j] = sq;
  }
  __syncthreads();
  if (t < 64){
    float s  = ps[0][t]+ps[1][t]+ps[2][t]+ps[3][t];
    float sq = pq[0][t]+pq[1][t]+pq[2][t]+pq[3][t];
    float mu = s * (1.f/128.f);
    float rstd = __builtin_amdgcn_rsqf(sq * (1.f/128.f) - mu*mu + 1e-5f);
    st2[t][0] = mu; st2[t][1] = rstd;
  }
  __syncthreads();

  {
    float mu = st2[j][0], rstd = st2[j][1];
    #pragma unroll
    for (int q=0;q<4;q++){
      uint32_t pk[4];
      #pragma unroll
      for (int p=0;p<4;p++){
        int e = q*8 + p*2;
        int c = h2*32 + e;
        float y0 = (v[e]   - mu)*rstd*onw_s[c]   + onb_s[c];
        float y1 = (v[e+1] - mu)*rstd*onw_s[c+1] + onb_s[c+1];
        pk[p] = cvtpk(y0, y1);
      }
      *(uint4*)&zn[j][h2*32 + q*8] = make_uint4(pk[0],pk[1],pk[2],pk[3]);
    }
  }
  __syncthreads();

  const int lane = t & 63, w = t >> 6;
  const int lr = lane & 15, lg = lane >> 4;

  f32x4 acc_o[4][2], acc_g[4][2];
  const f32x4 zero4 = {0.f,0.f,0.f,0.f};
  #pragma unroll
  for (int mi=0;mi<4;mi++){ acc_o[mi][0]=zero4; acc_o[mi][1]=zero4; acc_g[mi][0]=zero4; acc_g[mi][1]=zero4; }

  #pragma unroll
  for (int kk=0;kk<4;kk++){
    bf16x8 a[4];
    #pragma unroll
    for (int mi=0;mi<4;mi++)
      a[mi] = *(const bf16x8*)&zn[mi*16 + lr][kk*32 + lg*8];
    #pragma unroll
    for (int n=0;n<2;n++){
      int o = w*32 + n*16 + lr;
      bf16x8 b = *(const bf16x8*)&wts[5*16384 + o*128 + kk*32 + lg*8];
      #pragma unroll
      for (int mi=0;mi<4;mi++)
        acc_o[mi][n] = __builtin_amdgcn_mfma_f32_16x16x32_bf16(a[mi], b, acc_o[mi][n], 0,0,0);
    }
  }
  #pragma unroll
  for (int kk=0;kk<4;kk++){
    bf16x8 a[4];
    #pragma unroll
    for (int mi=0;mi<4;mi++)
      a[mi] = *(const bf16x8*)&zL[mi*16 + lr][kk*32 + lg*8];
    #pragma unroll
    for (int n=0;n<2;n++){
      int o = w*32 + n*16 + lr;
      bf16x8 b = *(const bf16x8*)&wts[4*16384 + o*128 + kk*32 + lg*8];
      #pragma unroll
      for (int mi=0;mi<4;mi++)
        acc_g[mi][n] = __builtin_amdgcn_mfma_f32_16x16x32_bf16(a[mi], b, acc_g[mi][n], 0,0,0);
    }
  }

  #pragma unroll
  for (int n=0;n<2;n++){
    int o = w*32 + n*16 + lr;
    float bgv = b_og[o];
    #pragma unroll
    for (int mi=0;mi<4;mi++){
      #pragma unroll
      for (int g2=0;g2<4;g2++){
        int r = mi*16 + lg*4 + g2;
        float val = acc_o[mi][n][g2] * sigm(acc_g[mi][n][g2] + bgv) * mask_s[r];
        out[(size_t)(row0 + r)*CH + o] = val;
      }
    }
  }
}

// --------------------------- launcher ------------------------------------
extern "C" void kernel_launch(void* const* d_in, const int* in_sizes, int n_in,
                              void* d_out, int out_size, void* d_ws, size_t ws_size,
                              hipStream_t stream)
{
  const float* z       = (const float*)d_in[0];
  const float* pmask   = (const float*)d_in[1];
  const float* lnw     = (const float*)d_in[2];
  const float* lnb     = (const float*)d_in[3];
  const float* W_left  = (const float*)d_in[4];
  const float* W_right = (const float*)d_in[5];
  const float* W_lgate = (const float*)d_in[6];
  const float* b_lgate = (const float*)d_in[7];
  const float* W_rgate = (const float*)d_in[8];
  const float* b_rgate = (const float*)d_in[9];
  const float* onw     = (const float*)d_in[10];
  const float* onb     = (const float*)d_in[11];
  const float* W_out   = (const float*)d_in[12];
  const float* W_ogate = (const float*)d_in[13];
  const float* b_ogate = (const float*)d_in[14];

  const size_t SLOT = 67108864;   // 64 MiB
  uint8_t* ws = (uint8_t*)d_ws;
  u16* left_t  = (u16*)(ws);
  u16* right_t = (u16*)(ws + SLOT);
  u16* znS     = (u16*)(ws + 2*SLOT);

  const bool fused = (ws_size >= 4*SLOT + 196608);
  u16* wts   = (u16*)(ws + (fused ? 4*SLOT : 3*SLOT));
  u16* upd16 = fused ? (u16*)(ws + 3*SLOT) : (u16*)d_out;

  k0_cvt<<<96, 256, 0, stream>>>(W_left, W_lgate, W_right, W_rgate, W_ogate, W_out, wts);
  k1ab_proj<<<2048, 256, 0, stream>>>(z, pmask, lnw, lnb, b_lgate, b_rgate, wts,
                                      znS, left_t, right_t);
  k2_einsum<<<dim3(4,4,128), 256, 0, stream>>>(left_t, right_t, upd16);

  if (fused){
    k3bf_out<<<4096, 256, 0, stream>>>(upd16, znS, pmask, onw, onb, b_ogate, wts,
                                       (float*)d_out);
  } else {
    k3a_ln<<<dim3(512,4), 256, 0, stream>>>(upd16, onw, onb, left_t /*znu*/);
    k3b_out<<<4096, 256, 0, stream>>>(left_t /*znu*/, znS, pmask, b_ogate, wts,
                                      (float*)d_out);
  }
}